// Round 3
// baseline (1159.702 us; speedup 1.0000x reference)
//
#include <hip/hip_runtime.h>
#include <math.h>

#define NXCD 8

// ================= XCD-partitioned histogram =================
// Persistent blocks drain per-range chunk queues; a block prefers the queue
// matching its own XCD (csr/deg range then stays in ONE L2 -> stores/atomics
// merge locally), then steals so completion never depends on XCD mapping.
__global__ __launch_bounds__(256) void k_hist_xcd(
    const int* __restrict__ dst, int* __restrict__ deg,
    int* __restrict__ queues, int E, int N, int nchunks, int chunk_edges) {
    unsigned xcc;
    asm volatile("s_getreg_b32 %0, hwreg(HW_REG_XCC_ID)" : "=s"(xcc));
    int myq = (int)(xcc & (NXCD - 1));
    __shared__ int s_c;
    for (int qi = 0; qi < NXCD; ++qi) {
        int q = (myq + qi) & (NXCD - 1);
        int lo = (int)(((long long)q * N) / NXCD);
        int hi = (int)(((long long)(q + 1) * N) / NXCD);
        for (;;) {
            __syncthreads();
            if (threadIdx.x == 0) s_c = atomicAdd(&queues[q], 1);
            __syncthreads();
            int c = s_c;
            if (c >= nchunks) break;
            int base = c * chunk_edges;
            int end = min(base + chunk_edges, E);
            for (int i = base + (int)threadIdx.x; i < end; i += 256) {
                int d = dst[i];
                if (d >= lo && d < hi) atomicAdd(&deg[d], 1);
            }
        }
    }
}

// ================= XCD-partitioned CSR fill =================
__global__ __launch_bounds__(256) void k_fill_xcd(
    const int* __restrict__ src, const int* __restrict__ dst,
    int* __restrict__ cursor, int* __restrict__ csr,
    int* __restrict__ queues, int E, int N, int nchunks, int chunk_edges) {
    unsigned xcc;
    asm volatile("s_getreg_b32 %0, hwreg(HW_REG_XCC_ID)" : "=s"(xcc));
    int myq = (int)(xcc & (NXCD - 1));
    __shared__ int s_c;
    for (int qi = 0; qi < NXCD; ++qi) {
        int q = (myq + qi) & (NXCD - 1);
        int lo = (int)(((long long)q * N) / NXCD);
        int hi = (int)(((long long)(q + 1) * N) / NXCD);
        for (;;) {
            __syncthreads();
            if (threadIdx.x == 0) s_c = atomicAdd(&queues[q], 1);
            __syncthreads();
            int c = s_c;
            if (c >= nchunks) break;
            int base = c * chunk_edges;
            int end = min(base + chunk_edges, E);
            for (int i = base + (int)threadIdx.x; i < end; i += 256) {
                int d = dst[i];
                if (d >= lo && d < hi) {
                    int pos = atomicAdd(&cursor[d], 1);
                    csr[pos] = src[i];
                }
            }
        }
    }
}

__global__ __launch_bounds__(256) void k_blocksum(const int* __restrict__ deg,
                                                  int* __restrict__ partials, int n) {
    __shared__ int s[256];
    int i = blockIdx.x * 256 + threadIdx.x;
    s[threadIdx.x] = (i < n) ? deg[i] : 0;
    __syncthreads();
    for (int off = 128; off > 0; off >>= 1) {
        if (threadIdx.x < off) s[threadIdx.x] += s[threadIdx.x + off];
        __syncthreads();
    }
    if (threadIdx.x == 0) partials[blockIdx.x] = s[0];
}

__global__ __launch_bounds__(1024) void k_scan_partials(int* partials, int nb) {
    __shared__ int s[1024];
    int carry = 0;
    for (int base = 0; base < nb; base += 1024) {
        int i = base + (int)threadIdx.x;
        int v = (i < nb) ? partials[i] : 0;
        s[threadIdx.x] = v;
        __syncthreads();
        for (int off = 1; off < 1024; off <<= 1) {
            int t = (threadIdx.x >= (unsigned)off) ? s[threadIdx.x - off] : 0;
            __syncthreads();
            s[threadIdx.x] += t;
            __syncthreads();
        }
        if (i < nb) partials[i] = s[threadIdx.x] + carry;
        int total = s[1023];
        __syncthreads();
        carry += total;
    }
}

__global__ __launch_bounds__(256) void k_rowptr(const int* __restrict__ deg,
                                                const int* __restrict__ psum,
                                                int* __restrict__ row_ptr,
                                                int* __restrict__ cursor,
                                                float* __restrict__ inv_deg,
                                                int n, int E_) {
    __shared__ int s[256];
    int blk = blockIdx.x;
    int i = blk * 256 + (int)threadIdx.x;
    int d = (i < n) ? deg[i] : 0;
    s[threadIdx.x] = d;
    __syncthreads();
    for (int off = 1; off < 256; off <<= 1) {
        int t = (threadIdx.x >= (unsigned)off) ? s[threadIdx.x - off] : 0;
        __syncthreads();
        s[threadIdx.x] += t;
        __syncthreads();
    }
    int excl = s[threadIdx.x] - d;
    int offset = (blk == 0) ? 0 : psum[blk - 1];
    if (i < n) {
        int rp = offset + excl;
        row_ptr[i] = rp;
        cursor[i] = rp;
        inv_deg[i] = d > 0 ? 1.0f / (float)d : 0.0f;
    }
    if (i == 0) row_ptr[n] = E_;
}

// ============== mean aggregation: gather via CSR ==============
__global__ __launch_bounds__(256) void k_gather(const float* __restrict__ h,
                                                const int* __restrict__ csr,
                                                const int* __restrict__ row_ptr,
                                                const float* __restrict__ inv_deg,
                                                float* __restrict__ out, int n) {
    int wave = (blockIdx.x * 256 + (int)threadIdx.x) >> 6;
    if (wave >= n) return;
    int lane = threadIdx.x & 63;
    int start = row_ptr[wave], end = row_ptr[wave + 1];
    float acc = 0.0f;
    for (int base = start; base < end; base += 64) {
        int j = base + lane;
        int idx = (j < end) ? csr[j] : 0;
        int cnt = min(64, end - base);
        int k = 0;
        for (; k + 4 <= cnt; k += 4) {
            int s0 = __shfl(idx, k + 0, 64);
            int s1 = __shfl(idx, k + 1, 64);
            int s2 = __shfl(idx, k + 2, 64);
            int s3 = __shfl(idx, k + 3, 64);
            float v0 = h[(size_t)s0 * 64 + lane];
            float v1 = h[(size_t)s1 * 64 + lane];
            float v2 = h[(size_t)s2 * 64 + lane];
            float v3 = h[(size_t)s3 * 64 + lane];
            acc += v0; acc += v1; acc += v2; acc += v3;
        }
        for (; k < cnt; ++k) {
            int s = __shfl(idx, k, 64);
            acc += h[(size_t)s * 64 + lane];
        }
    }
    out[(size_t)wave * 64 + lane] = acc * inv_deg[wave];
}

// ---- fused node matmul: out[N,64] = act([A0(xscale)|A1] @ [W0;W1] + bias) ----
template <int K0, int K1, bool RELU>
__global__ __launch_bounds__(256) void node_mm(
    const float* __restrict__ A0, const float* __restrict__ scale0,
    const float* __restrict__ A1, const float* __restrict__ W0,
    const float* __restrict__ W1, const float* __restrict__ bias,
    float* __restrict__ out, int n) {
    constexpr int K = K0 + K1;
    constexpr int KV = K / 4;
    __shared__ float sA[64 * K];
    __shared__ float sW[K * 64];
    const int tid = threadIdx.x;
    const int row0 = blockIdx.x * 64;

    for (int i = tid; i < K0 * 16; i += 256)
        ((float4*)sW)[i] = ((const float4*)W0)[i];
    if (K1 > 0) {
        for (int i = tid; i < K1 * 16; i += 256)
            ((float4*)sW)[K0 * 16 + i] = ((const float4*)W1)[i];
    }

    for (int idx = tid; idx < 64 * KV; idx += 256) {
        int r = idx / KV, kc = idx % KV;
        int k = kc * 4;
        int grow = row0 + r;
        float4 v = make_float4(0.f, 0.f, 0.f, 0.f);
        if (grow < n) {
            if (k < K0) {
                v = *(const float4*)&A0[(size_t)grow * K0 + k];
                if (scale0) {
                    float sc = scale0[grow];
                    v.x *= sc; v.y *= sc; v.z *= sc; v.w *= sc;
                }
            } else {
                v = *(const float4*)&A1[(size_t)grow * K1 + (k - K0)];
            }
        }
        int kcs = kc ^ ((r >> 2) & 3);
        *(float4*)&sA[r * K + kcs * 4] = v;
    }
    __syncthreads();

    const int tc = tid & 15;
    const int tr = tid >> 4;
    const int sw = tr & 3;
    float4 acc[4];
#pragma unroll
    for (int rr = 0; rr < 4; ++rr) acc[rr] = make_float4(0.f, 0.f, 0.f, 0.f);

#pragma unroll 4
    for (int kc = 0; kc < KV; ++kc) {
        int ks = (kc ^ sw) * 4;
        float4 a[4], w[4];
#pragma unroll
        for (int rr = 0; rr < 4; ++rr)
            a[rr] = *(const float4*)&sA[(tr * 4 + rr) * K + ks];
#pragma unroll
        for (int kk = 0; kk < 4; ++kk)
            w[kk] = *(const float4*)&sW[(kc * 4 + kk) * 64 + tc * 4];
#pragma unroll
        for (int kk = 0; kk < 4; ++kk) {
#pragma unroll
            for (int rr = 0; rr < 4; ++rr) {
                float av = (&a[rr].x)[kk];
                acc[rr].x = fmaf(av, w[kk].x, acc[rr].x);
                acc[rr].y = fmaf(av, w[kk].y, acc[rr].y);
                acc[rr].z = fmaf(av, w[kk].z, acc[rr].z);
                acc[rr].w = fmaf(av, w[kk].w, acc[rr].w);
            }
        }
    }

    float4 b4 = make_float4(0.f, 0.f, 0.f, 0.f);
    if (bias) b4 = *(const float4*)&bias[tc * 4];
#pragma unroll
    for (int rr = 0; rr < 4; ++rr) {
        int r = row0 + tr * 4 + rr;
        if (r < n) {
            float4 v = acc[rr];
            v.x += b4.x; v.y += b4.y; v.z += b4.z; v.w += b4.w;
            if (RELU) {
                v.x = fmaxf(v.x, 0.f); v.y = fmaxf(v.y, 0.f);
                v.z = fmaxf(v.z, 0.f); v.w = fmaxf(v.w, 0.f);
            }
            *(float4*)&out[(size_t)r * 64 + tc * 4] = v;
        }
    }
}

// ---- edge scorer: out[e] = tanh( relu(P[s]+Q[d]) . w2 + b2 ) ----
__global__ __launch_bounds__(256) void k_score(
    const float* __restrict__ P, const float* __restrict__ Q,
    const int* __restrict__ msrc, const int* __restrict__ mdst,
    const float* __restrict__ w2, const float* __restrict__ b2,
    float* __restrict__ out, int M) {
    int gid = blockIdx.x * 256 + threadIdx.x;
    int e = gid >> 4;
    if (e >= M) return;
    int l = gid & 15;
    int s = msrc[e], d = mdst[e];
    float4 p = *(const float4*)&P[(size_t)s * 64 + l * 4];
    float4 q = *(const float4*)&Q[(size_t)d * 64 + l * 4];
    float4 w = *(const float4*)&w2[l * 4];
    float ux = fmaxf(p.x + q.x, 0.f);
    float uy = fmaxf(p.y + q.y, 0.f);
    float uz = fmaxf(p.z + q.z, 0.f);
    float uw = fmaxf(p.w + q.w, 0.f);
    float partial = ux * w.x + uy * w.y + uz * w.z + uw * w.w;
#pragma unroll
    for (int m = 1; m < 16; m <<= 1) partial += __shfl_xor(partial, m, 16);
    if (l == 0) out[e] = tanhf(partial + b2[0]);
}

extern "C" void kernel_launch(void* const* d_in, const int* in_sizes, int n_in,
                              void* d_out, int out_size, void* d_ws, size_t ws_size,
                              hipStream_t stream) {
    const float* x      = (const float*)d_in[0];
    const int*   ei     = (const int*)d_in[1];
    const int*   mei    = (const int*)d_in[2];
    const float* lin1_w = (const float*)d_in[3];
    const float* lin1_b = (const float*)d_in[4];
    const float* lin2_w = (const float*)d_in[5];
    const float* lin2_b = (const float*)d_in[6];
    const float* c1_wl  = (const float*)d_in[7];
    const float* c1_bl  = (const float*)d_in[8];
    const float* c1_wr  = (const float*)d_in[9];
    const float* c2_wl  = (const float*)d_in[10];
    const float* c2_bl  = (const float*)d_in[11];
    const float* c2_wr  = (const float*)d_in[12];
    const float* mlp_w1 = (const float*)d_in[13];
    const float* mlp_b1 = (const float*)d_in[14];
    const float* mlp_w2 = (const float*)d_in[15];
    const float* mlp_b2 = (const float*)d_in[16];

    const int N = in_sizes[0] / 128;
    const int E = in_sizes[1] / 2;
    const int M = in_sizes[2] / 2;
    const int* src  = ei;
    const int* dstE = ei + E;
    const int* msrc = mei;
    const int* mdst = mei + M;

    const size_t N64 = (size_t)N * 64;
    float* bufA    = (float*)d_ws;              // N*64
    float* bufB    = bufA + N64;                // N*64
    float* bufC    = bufB + N64;                // N*64
    float* inv_deg = bufC + N64;                // N
    int*   deg_i   = (int*)(inv_deg + N);       // N
    int*   queues  = deg_i + N;                 // 16 (hist: 0..7, fill: 8..15)
    int*   row_ptr = queues + 16;               // N+1
    int*   cursor  = row_ptr + (N + 1);         // N
    int*   partials= cursor + N;                // nb
    const int nb   = (N + 255) / 256;
    int*   csr     = partials + ((nb + 63) & ~63); // E
    float* outf = (float*)d_out;

    const int nbN = (N + 63) / 64;
    const int nbM = (int)(((long long)M * 16 + 255) / 256);
    const int nbG = (int)(((long long)N * 64 + 255) / 256);

    const int chunk_edges = 2048;
    const int nchunks = (E + chunk_edges - 1) / chunk_edges;

    // ---- CSR build (once; both SAGE layers share edge_index) ----
    hipMemsetAsync(deg_i, 0, ((size_t)N + 16) * 4, stream);  // deg + queues
    k_hist_xcd<<<1024, 256, 0, stream>>>(dstE, deg_i, queues, E, N,
                                         nchunks, chunk_edges);
    k_blocksum<<<nb, 256, 0, stream>>>(deg_i, partials, N);
    k_scan_partials<<<1, 1024, 0, stream>>>(partials, nb);
    k_rowptr<<<nb, 256, 0, stream>>>(deg_i, partials, row_ptr, cursor, inv_deg, N, E);
    k_fill_xcd<<<1024, 256, 0, stream>>>(src, dstE, cursor, csr, queues + NXCD,
                                         E, N, nchunks, chunk_edges);

    // h1 = relu(x @ lin1_w + b)          -> A
    node_mm<128, 0, true><<<nbN, 256, 0, stream>>>(
        x, nullptr, nullptr, lin1_w, nullptr, lin1_b, bufA, N);

    // sage1: agg = mean gather -> B; h2 = relu(agg @ wl + bl + h1 @ wr) -> C
    k_gather<<<nbG, 256, 0, stream>>>(bufA, csr, row_ptr, inv_deg, bufB, N);
    node_mm<64, 64, true><<<nbN, 256, 0, stream>>>(
        bufB, nullptr, bufA, c1_wl, c1_wr, c1_bl, bufC, N);

    // h3 = relu(h2 @ lin2_w + b)         -> A
    node_mm<64, 0, true><<<nbN, 256, 0, stream>>>(
        bufC, nullptr, nullptr, lin2_w, nullptr, lin2_b, bufA, N);

    // sage2 -> C
    k_gather<<<nbG, 256, 0, stream>>>(bufA, csr, row_ptr, inv_deg, bufB, N);
    node_mm<64, 64, true><<<nbN, 256, 0, stream>>>(
        bufB, nullptr, bufA, c2_wl, c2_wr, c2_bl, bufC, N);

    // P = h4 @ W1[:64] + b1 -> A ; Q = h4 @ W1[64:] -> B
    node_mm<64, 0, false><<<nbN, 256, 0, stream>>>(
        bufC, nullptr, nullptr, mlp_w1, nullptr, mlp_b1, bufA, N);
    node_mm<64, 0, false><<<nbN, 256, 0, stream>>>(
        bufC, nullptr, nullptr, mlp_w1 + 64 * 64, nullptr, nullptr, bufB, N);

    // edge scoring
    k_score<<<nbM, 256, 0, stream>>>(bufA, bufB, msrc, mdst, mlp_w2, mlp_b2,
                                     outf, M);
}

// Round 4
// 719.072 us; speedup vs baseline: 1.6128x; 1.6128x over previous
//
#include <hip/hip_runtime.h>
#include <math.h>

#define MAXB 256   // max buckets (512 dst nodes each at shift=9, N<=131072)

// ========== Phase A: per-bucket edge counts ==========
__global__ __launch_bounds__(256) void k_bcount(const int* __restrict__ dst,
                                                int* __restrict__ bucket_cnt,
                                                int E, int shift) {
    __shared__ int h[MAXB];
    for (int i = threadIdx.x; i < MAXB; i += 256) h[i] = 0;
    __syncthreads();
    int stride = gridDim.x * 256;
    for (int i = blockIdx.x * 256 + threadIdx.x; i < E; i += stride)
        atomicAdd(&h[dst[i] >> shift], 1);
    __syncthreads();
    for (int i = threadIdx.x; i < MAXB; i += 256)
        if (h[i]) atomicAdd(&bucket_cnt[i], h[i]);
}

// ========== scan bucket counts -> bucket_off, bucket_cur ==========
__global__ __launch_bounds__(256) void k_bscan(const int* __restrict__ bucket_cnt,
                                               int* __restrict__ bucket_off,
                                               int* __restrict__ bucket_cur,
                                               int nbuckets) {
    __shared__ int s[MAXB];
    int t = threadIdx.x;
    int v = (t < nbuckets) ? bucket_cnt[t] : 0;
    s[t] = v;
    __syncthreads();
    for (int off = 1; off < MAXB; off <<= 1) {
        int u = (t >= off) ? s[t - off] : 0;
        __syncthreads();
        s[t] += u;
        __syncthreads();
    }
    int excl = s[t] - v;
    if (t < nbuckets) { bucket_off[t] = excl; bucket_cur[t] = excl; }
}

// ========== Phase B: partition edges into bucket runs (compacted writes) ====
#define PART_CH 16384
__global__ __launch_bounds__(256) void k_part(const int* __restrict__ src,
                                              const int* __restrict__ dst,
                                              int* __restrict__ bucket_cur,
                                              unsigned* __restrict__ bb,
                                              int E, int shift) {
    __shared__ int h[MAXB], base[MAXB];
    int b0 = blockIdx.x * PART_CH;
    int e1 = min(b0 + PART_CH, E);
    for (int i = threadIdx.x; i < MAXB; i += 256) h[i] = 0;
    __syncthreads();
    for (int i = b0 + threadIdx.x; i < e1; i += 256)
        atomicAdd(&h[dst[i] >> shift], 1);
    __syncthreads();
    for (int i = threadIdx.x; i < MAXB; i += 256) {
        base[i] = h[i] ? atomicAdd(&bucket_cur[i], h[i]) : 0;
        h[i] = 0;  // reuse as local cursor
    }
    __syncthreads();
    unsigned mask = (1u << shift) - 1u;
    for (int i = b0 + threadIdx.x; i < e1; i += 256) {
        int d = dst[i];
        int b = d >> shift;
        int r = atomicAdd(&h[b], 1);
        bb[base[b] + r] = ((unsigned)src[i] << shift) | ((unsigned)d & mask);
    }
}

// ========== Phase C: per-bucket deg/rowptr/csr fill, all counters in LDS ====
__global__ __launch_bounds__(512) void k_bfill(const unsigned* __restrict__ bb,
                                               const int* __restrict__ bucket_off,
                                               const int* __restrict__ bucket_cnt,
                                               int* __restrict__ row_ptr,
                                               int* __restrict__ cursor_unused,
                                               float* __restrict__ inv_deg,
                                               int* __restrict__ csr,
                                               int N, int E, int shift) {
    __shared__ int deg[512], cur[512], s[512];
    int b = blockIdx.x;
    int t = threadIdx.x;
    int lo = b << shift;
    int hi = min(N, (b + 1) << shift);
    int nn = hi - lo;
    int off = bucket_off[b];
    int cnt = bucket_cnt[b];
    unsigned mask = (1u << shift) - 1u;

    deg[t] = 0;
    __syncthreads();
    for (int i = off + t; i < off + cnt; i += 512)
        atomicAdd(&deg[bb[i] & mask], 1);
    __syncthreads();
    int d = deg[t];
    s[t] = d;
    __syncthreads();
    for (int o = 1; o < 512; o <<= 1) {
        int u = (t >= o) ? s[t - o] : 0;
        __syncthreads();
        s[t] += u;
        __syncthreads();
    }
    int excl = s[t] - d;
    cur[t] = excl;
    if (t < nn) {
        row_ptr[lo + t] = off + excl;
        inv_deg[lo + t] = d > 0 ? 1.0f / (float)d : 0.0f;
    }
    if (t == 0 && hi == N) row_ptr[N] = E;
    __syncthreads();
    for (int i = off + t; i < off + cnt; i += 512) {
        unsigned w = bb[i];
        int dl = (int)(w & mask);
        int pos = atomicAdd(&cur[dl], 1);
        csr[off + pos] = (int)(w >> shift);
    }
}

// ============== mean aggregation: gather via CSR ==============
__global__ __launch_bounds__(256) void k_gather(const float* __restrict__ h,
                                                const int* __restrict__ csr,
                                                const int* __restrict__ row_ptr,
                                                const float* __restrict__ inv_deg,
                                                float* __restrict__ out, int n) {
    int wave = (blockIdx.x * 256 + (int)threadIdx.x) >> 6;
    if (wave >= n) return;
    int lane = threadIdx.x & 63;
    int start = row_ptr[wave], end = row_ptr[wave + 1];
    float acc = 0.0f;
    for (int base = start; base < end; base += 64) {
        int j = base + lane;
        int idx = (j < end) ? csr[j] : 0;
        int cnt = min(64, end - base);
        int k = 0;
        for (; k + 4 <= cnt; k += 4) {
            int s0 = __shfl(idx, k + 0, 64);
            int s1 = __shfl(idx, k + 1, 64);
            int s2 = __shfl(idx, k + 2, 64);
            int s3 = __shfl(idx, k + 3, 64);
            float v0 = h[(size_t)s0 * 64 + lane];
            float v1 = h[(size_t)s1 * 64 + lane];
            float v2 = h[(size_t)s2 * 64 + lane];
            float v3 = h[(size_t)s3 * 64 + lane];
            acc += v0; acc += v1; acc += v2; acc += v3;
        }
        for (; k < cnt; ++k) {
            int s = __shfl(idx, k, 64);
            acc += h[(size_t)s * 64 + lane];
        }
    }
    out[(size_t)wave * 64 + lane] = acc * inv_deg[wave];
}

// ---- fused node matmul: out[N,64] = act([A0(xscale)|A1] @ [W0;W1] + bias) ----
template <int K0, int K1, bool RELU>
__global__ __launch_bounds__(256) void node_mm(
    const float* __restrict__ A0, const float* __restrict__ scale0,
    const float* __restrict__ A1, const float* __restrict__ W0,
    const float* __restrict__ W1, const float* __restrict__ bias,
    float* __restrict__ out, int n) {
    constexpr int K = K0 + K1;
    constexpr int KV = K / 4;
    __shared__ float sA[64 * K];
    __shared__ float sW[K * 64];
    const int tid = threadIdx.x;
    const int row0 = blockIdx.x * 64;

    for (int i = tid; i < K0 * 16; i += 256)
        ((float4*)sW)[i] = ((const float4*)W0)[i];
    if (K1 > 0) {
        for (int i = tid; i < K1 * 16; i += 256)
            ((float4*)sW)[K0 * 16 + i] = ((const float4*)W1)[i];
    }

    for (int idx = tid; idx < 64 * KV; idx += 256) {
        int r = idx / KV, kc = idx % KV;
        int k = kc * 4;
        int grow = row0 + r;
        float4 v = make_float4(0.f, 0.f, 0.f, 0.f);
        if (grow < n) {
            if (k < K0) {
                v = *(const float4*)&A0[(size_t)grow * K0 + k];
                if (scale0) {
                    float sc = scale0[grow];
                    v.x *= sc; v.y *= sc; v.z *= sc; v.w *= sc;
                }
            } else {
                v = *(const float4*)&A1[(size_t)grow * K1 + (k - K0)];
            }
        }
        int kcs = kc ^ ((r >> 2) & 3);
        *(float4*)&sA[r * K + kcs * 4] = v;
    }
    __syncthreads();

    const int tc = tid & 15;
    const int tr = tid >> 4;
    const int sw = tr & 3;
    float4 acc[4];
#pragma unroll
    for (int rr = 0; rr < 4; ++rr) acc[rr] = make_float4(0.f, 0.f, 0.f, 0.f);

#pragma unroll 4
    for (int kc = 0; kc < KV; ++kc) {
        int ks = (kc ^ sw) * 4;
        float4 a[4], w[4];
#pragma unroll
        for (int rr = 0; rr < 4; ++rr)
            a[rr] = *(const float4*)&sA[(tr * 4 + rr) * K + ks];
#pragma unroll
        for (int kk = 0; kk < 4; ++kk)
            w[kk] = *(const float4*)&sW[(kc * 4 + kk) * 64 + tc * 4];
#pragma unroll
        for (int kk = 0; kk < 4; ++kk) {
#pragma unroll
            for (int rr = 0; rr < 4; ++rr) {
                float av = (&a[rr].x)[kk];
                acc[rr].x = fmaf(av, w[kk].x, acc[rr].x);
                acc[rr].y = fmaf(av, w[kk].y, acc[rr].y);
                acc[rr].z = fmaf(av, w[kk].z, acc[rr].z);
                acc[rr].w = fmaf(av, w[kk].w, acc[rr].w);
            }
        }
    }

    float4 b4 = make_float4(0.f, 0.f, 0.f, 0.f);
    if (bias) b4 = *(const float4*)&bias[tc * 4];
#pragma unroll
    for (int rr = 0; rr < 4; ++rr) {
        int r = row0 + tr * 4 + rr;
        if (r < n) {
            float4 v = acc[rr];
            v.x += b4.x; v.y += b4.y; v.z += b4.z; v.w += b4.w;
            if (RELU) {
                v.x = fmaxf(v.x, 0.f); v.y = fmaxf(v.y, 0.f);
                v.z = fmaxf(v.z, 0.f); v.w = fmaxf(v.w, 0.f);
            }
            *(float4*)&out[(size_t)r * 64 + tc * 4] = v;
        }
    }
}

// ---- edge scorer: out[e] = tanh( relu(P[s]+Q[d]) . w2 + b2 ) ----
__global__ __launch_bounds__(256) void k_score(
    const float* __restrict__ P, const float* __restrict__ Q,
    const int* __restrict__ msrc, const int* __restrict__ mdst,
    const float* __restrict__ w2, const float* __restrict__ b2,
    float* __restrict__ out, int M) {
    int gid = blockIdx.x * 256 + threadIdx.x;
    int e = gid >> 4;
    if (e >= M) return;
    int l = gid & 15;
    int s = msrc[e], d = mdst[e];
    float4 p = *(const float4*)&P[(size_t)s * 64 + l * 4];
    float4 q = *(const float4*)&Q[(size_t)d * 64 + l * 4];
    float4 w = *(const float4*)&w2[l * 4];
    float ux = fmaxf(p.x + q.x, 0.f);
    float uy = fmaxf(p.y + q.y, 0.f);
    float uz = fmaxf(p.z + q.z, 0.f);
    float uw = fmaxf(p.w + q.w, 0.f);
    float partial = ux * w.x + uy * w.y + uz * w.z + uw * w.w;
#pragma unroll
    for (int m = 1; m < 16; m <<= 1) partial += __shfl_xor(partial, m, 16);
    if (l == 0) out[e] = tanhf(partial + b2[0]);
}

extern "C" void kernel_launch(void* const* d_in, const int* in_sizes, int n_in,
                              void* d_out, int out_size, void* d_ws, size_t ws_size,
                              hipStream_t stream) {
    const float* x      = (const float*)d_in[0];
    const int*   ei     = (const int*)d_in[1];
    const int*   mei    = (const int*)d_in[2];
    const float* lin1_w = (const float*)d_in[3];
    const float* lin1_b = (const float*)d_in[4];
    const float* lin2_w = (const float*)d_in[5];
    const float* lin2_b = (const float*)d_in[6];
    const float* c1_wl  = (const float*)d_in[7];
    const float* c1_bl  = (const float*)d_in[8];
    const float* c1_wr  = (const float*)d_in[9];
    const float* c2_wl  = (const float*)d_in[10];
    const float* c2_bl  = (const float*)d_in[11];
    const float* c2_wr  = (const float*)d_in[12];
    const float* mlp_w1 = (const float*)d_in[13];
    const float* mlp_b1 = (const float*)d_in[14];
    const float* mlp_w2 = (const float*)d_in[15];
    const float* mlp_b2 = (const float*)d_in[16];

    const int N = in_sizes[0] / 128;
    const int E = in_sizes[1] / 2;
    const int M = in_sizes[2] / 2;
    const int* src  = ei;
    const int* dstE = ei + E;
    const int* msrc = mei;
    const int* mdst = mei + M;

    // bucket shift: 512 nodes/bucket, <=256 buckets
    int shift = 9;
    while ((((N - 1) >> shift) + 1) > MAXB) ++shift;
    const int nbuckets = ((N - 1) >> shift) + 1;

    const size_t N64 = (size_t)N * 64;
    float* bufA    = (float*)d_ws;              // N*64
    float* bufB    = bufA + N64;                // N*64 (aliased by bb pre-gather)
    float* bufC    = bufB + N64;                // N*64
    float* inv_deg = bufC + N64;                // N
    int*   row_ptr = (int*)(inv_deg + N);       // N+1
    int*   bcnt    = row_ptr + (N + 1);         // MAXB
    int*   boff    = bcnt + MAXB;               // MAXB
    int*   bcur    = boff + MAXB;               // MAXB
    int*   csr     = bcur + MAXB;               // E
    unsigned* bb   = (unsigned*)bufB;           // E (dead before first k_gather)
    float* outf = (float*)d_out;

    const int nbN = (N + 63) / 64;
    const int nbM = (int)(((long long)M * 16 + 255) / 256);
    const int nbG = (int)(((long long)N * 64 + 255) / 256);
    const int nbP = (E + PART_CH - 1) / PART_CH;

    // ---- CSR build: count -> scan -> partition -> per-bucket fill ----
    hipMemsetAsync(bcnt, 0, MAXB * sizeof(int), stream);
    k_bcount<<<512, 256, 0, stream>>>(dstE, bcnt, E, shift);
    k_bscan<<<1, MAXB, 0, stream>>>(bcnt, boff, bcur, nbuckets);
    k_part<<<nbP, 256, 0, stream>>>(src, dstE, bcur, bb, E, shift);
    k_bfill<<<nbuckets, 512, 0, stream>>>(bb, boff, bcnt, row_ptr, nullptr,
                                          inv_deg, csr, N, E, shift);

    // h1 = relu(x @ lin1_w + b)          -> A
    node_mm<128, 0, true><<<nbN, 256, 0, stream>>>(
        x, nullptr, nullptr, lin1_w, nullptr, lin1_b, bufA, N);

    // sage1: agg = mean gather -> B; h2 = relu(agg @ wl + bl + h1 @ wr) -> C
    k_gather<<<nbG, 256, 0, stream>>>(bufA, csr, row_ptr, inv_deg, bufB, N);
    node_mm<64, 64, true><<<nbN, 256, 0, stream>>>(
        bufB, nullptr, bufA, c1_wl, c1_wr, c1_bl, bufC, N);

    // h3 = relu(h2 @ lin2_w + b)         -> A
    node_mm<64, 0, true><<<nbN, 256, 0, stream>>>(
        bufC, nullptr, nullptr, lin2_w, nullptr, lin2_b, bufA, N);

    // sage2 -> C
    k_gather<<<nbG, 256, 0, stream>>>(bufA, csr, row_ptr, inv_deg, bufB, N);
    node_mm<64, 64, true><<<nbN, 256, 0, stream>>>(
        bufB, nullptr, bufA, c2_wl, c2_wr, c2_bl, bufC, N);

    // P = h4 @ W1[:64] + b1 -> A ; Q = h4 @ W1[64:] -> B
    node_mm<64, 0, false><<<nbN, 256, 0, stream>>>(
        bufC, nullptr, nullptr, mlp_w1, nullptr, mlp_b1, bufA, N);
    node_mm<64, 0, false><<<nbN, 256, 0, stream>>>(
        bufC, nullptr, nullptr, mlp_w1 + 64 * 64, nullptr, nullptr, bufB, N);

    // edge scoring
    k_score<<<nbM, 256, 0, stream>>>(bufA, bufB, msrc, mdst, mlp_w2, mlp_b2,
                                     outf, M);
}

// Round 5
// 594.800 us; speedup vs baseline: 1.9497x; 1.2089x over previous
//
#include <hip/hip_runtime.h>
#include <math.h>

#define MAXB 256   // max buckets (512 dst nodes each at shift=9, N<=131072)

// ---- bf16 helpers (RNE) ----
static __device__ __forceinline__ unsigned short f2bf(float f) {
    unsigned u = __float_as_uint(f);
    u += 0x7fffu + ((u >> 16) & 1u);
    return (unsigned short)(u >> 16);
}
static __device__ __forceinline__ float bf2f(unsigned short s) {
    return __uint_as_float((unsigned)s << 16);
}

// ========== Phase A: per-bucket edge counts ==========
__global__ __launch_bounds__(256) void k_bcount(const int* __restrict__ dst,
                                                int* __restrict__ bucket_cnt,
                                                int E, int shift) {
    __shared__ int h[MAXB];
    for (int i = threadIdx.x; i < MAXB; i += 256) h[i] = 0;
    __syncthreads();
    int stride = gridDim.x * 256;
    for (int i = blockIdx.x * 256 + threadIdx.x; i < E; i += stride)
        atomicAdd(&h[dst[i] >> shift], 1);
    __syncthreads();
    for (int i = threadIdx.x; i < MAXB; i += 256)
        if (h[i]) atomicAdd(&bucket_cnt[i], h[i]);
}

// ========== scan bucket counts -> bucket_off, bucket_cur ==========
__global__ __launch_bounds__(256) void k_bscan(const int* __restrict__ bucket_cnt,
                                               int* __restrict__ bucket_off,
                                               int* __restrict__ bucket_cur,
                                               int nbuckets) {
    __shared__ int s[MAXB];
    int t = threadIdx.x;
    int v = (t < nbuckets) ? bucket_cnt[t] : 0;
    s[t] = v;
    __syncthreads();
    for (int off = 1; off < MAXB; off <<= 1) {
        int u = (t >= off) ? s[t - off] : 0;
        __syncthreads();
        s[t] += u;
        __syncthreads();
    }
    int excl = s[t] - v;
    if (t < nbuckets) { bucket_off[t] = excl; bucket_cur[t] = excl; }
}

// ========== Phase B: partition edges into bucket runs (compacted writes) ====
#define PART_CH 16384
__global__ __launch_bounds__(256) void k_part(const int* __restrict__ src,
                                              const int* __restrict__ dst,
                                              int* __restrict__ bucket_cur,
                                              unsigned* __restrict__ bb,
                                              int E, int shift) {
    __shared__ int h[MAXB], base[MAXB];
    int b0 = blockIdx.x * PART_CH;
    int e1 = min(b0 + PART_CH, E);
    for (int i = threadIdx.x; i < MAXB; i += 256) h[i] = 0;
    __syncthreads();
    for (int i = b0 + threadIdx.x; i < e1; i += 256)
        atomicAdd(&h[dst[i] >> shift], 1);
    __syncthreads();
    for (int i = threadIdx.x; i < MAXB; i += 256) {
        base[i] = h[i] ? atomicAdd(&bucket_cur[i], h[i]) : 0;
        h[i] = 0;  // reuse as local cursor
    }
    __syncthreads();
    unsigned mask = (1u << shift) - 1u;
    for (int i = b0 + threadIdx.x; i < e1; i += 256) {
        int d = dst[i];
        int b = d >> shift;
        int r = atomicAdd(&h[b], 1);
        bb[base[b] + r] = ((unsigned)src[i] << shift) | ((unsigned)d & mask);
    }
}

// ========== Phase C: per-bucket deg/rowptr/csr fill, all counters in LDS ====
__global__ __launch_bounds__(512) void k_bfill(const unsigned* __restrict__ bb,
                                               const int* __restrict__ bucket_off,
                                               const int* __restrict__ bucket_cnt,
                                               int* __restrict__ row_ptr,
                                               float* __restrict__ inv_deg,
                                               int* __restrict__ csr,
                                               int N, int E, int shift) {
    __shared__ int deg[512], cur[512], s[512];
    int b = blockIdx.x;
    int t = threadIdx.x;
    int lo = b << shift;
    int hi = min(N, (b + 1) << shift);
    int nn = hi - lo;
    int off = bucket_off[b];
    int cnt = bucket_cnt[b];
    unsigned mask = (1u << shift) - 1u;

    deg[t] = 0;
    __syncthreads();
    for (int i = off + t; i < off + cnt; i += 512)
        atomicAdd(&deg[bb[i] & mask], 1);
    __syncthreads();
    int d = deg[t];
    s[t] = d;
    __syncthreads();
    for (int o = 1; o < 512; o <<= 1) {
        int u = (t >= o) ? s[t - o] : 0;
        __syncthreads();
        s[t] += u;
        __syncthreads();
    }
    int excl = s[t] - d;
    cur[t] = excl;
    if (t < nn) {
        row_ptr[lo + t] = off + excl;
        inv_deg[lo + t] = d > 0 ? 1.0f / (float)d : 0.0f;
    }
    if (t == 0 && hi == N) row_ptr[N] = E;
    __syncthreads();
    for (int i = off + t; i < off + cnt; i += 512) {
        unsigned w = bb[i];
        int dl = (int)(w & mask);
        int pos = atomicAdd(&cur[dl], 1);
        csr[off + pos] = (int)(w >> shift);
    }
}

// ====== mean aggregation, bf16 rows, 4 rows in flight per wave ======
// wave = node; lane = slot g (4) x channel-chunk sub (16, 4 ch each).
// Clamped addresses + mask-fma (no branches) so loads batch for MLP.
__global__ __launch_bounds__(256) void k_gather_bf(
    const unsigned short* __restrict__ hbf, const int* __restrict__ csr,
    const int* __restrict__ row_ptr, const float* __restrict__ inv_deg,
    float* __restrict__ out, int n) {
    int wave = (blockIdx.x * 256 + (int)threadIdx.x) >> 6;
    if (wave >= n) return;
    int lane = threadIdx.x & 63;
    int g = lane >> 4, sub = lane & 15;
    int start = row_ptr[wave], end = row_ptr[wave + 1];
    float4 acc = make_float4(0.f, 0.f, 0.f, 0.f);
    for (int base = start; base < end; base += 16) {
        int j0 = base + g;
        int j1 = j0 + 4, j2 = j0 + 8, j3 = j0 + 12;
        int last = end - 1;
        int s0 = csr[min(j0, last)];
        int s1 = csr[min(j1, last)];
        int s2 = csr[min(j2, last)];
        int s3 = csr[min(j3, last)];
        ushort4 u0 = *(const ushort4*)&hbf[(size_t)s0 * 64 + sub * 4];
        ushort4 u1 = *(const ushort4*)&hbf[(size_t)s1 * 64 + sub * 4];
        ushort4 u2 = *(const ushort4*)&hbf[(size_t)s2 * 64 + sub * 4];
        ushort4 u3 = *(const ushort4*)&hbf[(size_t)s3 * 64 + sub * 4];
        float m0 = (j0 < end) ? 1.f : 0.f;
        float m1 = (j1 < end) ? 1.f : 0.f;
        float m2 = (j2 < end) ? 1.f : 0.f;
        float m3 = (j3 < end) ? 1.f : 0.f;
        acc.x = fmaf(m0, bf2f(u0.x), acc.x);
        acc.y = fmaf(m0, bf2f(u0.y), acc.y);
        acc.z = fmaf(m0, bf2f(u0.z), acc.z);
        acc.w = fmaf(m0, bf2f(u0.w), acc.w);
        acc.x = fmaf(m1, bf2f(u1.x), acc.x);
        acc.y = fmaf(m1, bf2f(u1.y), acc.y);
        acc.z = fmaf(m1, bf2f(u1.z), acc.z);
        acc.w = fmaf(m1, bf2f(u1.w), acc.w);
        acc.x = fmaf(m2, bf2f(u2.x), acc.x);
        acc.y = fmaf(m2, bf2f(u2.y), acc.y);
        acc.z = fmaf(m2, bf2f(u2.z), acc.z);
        acc.w = fmaf(m2, bf2f(u2.w), acc.w);
        acc.x = fmaf(m3, bf2f(u3.x), acc.x);
        acc.y = fmaf(m3, bf2f(u3.y), acc.y);
        acc.z = fmaf(m3, bf2f(u3.z), acc.z);
        acc.w = fmaf(m3, bf2f(u3.w), acc.w);
    }
    // fold the 4 slots
    acc.x += __shfl_xor(acc.x, 16, 64);
    acc.y += __shfl_xor(acc.y, 16, 64);
    acc.z += __shfl_xor(acc.z, 16, 64);
    acc.w += __shfl_xor(acc.w, 16, 64);
    acc.x += __shfl_xor(acc.x, 32, 64);
    acc.y += __shfl_xor(acc.y, 32, 64);
    acc.z += __shfl_xor(acc.z, 32, 64);
    acc.w += __shfl_xor(acc.w, 32, 64);
    if (g == 0) {
        float idv = inv_deg[wave];
        float4 r = make_float4(acc.x * idv, acc.y * idv, acc.z * idv, acc.w * idv);
        *(float4*)&out[(size_t)wave * 64 + sub * 4] = r;
    }
}

// ---- fused node matmul: out[N,64] = act([A0|A1] @ [W0;W1] + bias) ----
// optional fp32 out and/or bf16 out_bf
template <int K0, int K1, bool RELU>
__global__ __launch_bounds__(256) void node_mm(
    const float* __restrict__ A0, const float* __restrict__ A1,
    const float* __restrict__ W0, const float* __restrict__ W1,
    const float* __restrict__ bias, float* __restrict__ out,
    unsigned short* __restrict__ out_bf, int n) {
    constexpr int K = K0 + K1;
    constexpr int KV = K / 4;
    __shared__ float sA[64 * K];
    __shared__ float sW[K * 64];
    const int tid = threadIdx.x;
    const int row0 = blockIdx.x * 64;

    for (int i = tid; i < K0 * 16; i += 256)
        ((float4*)sW)[i] = ((const float4*)W0)[i];
    if (K1 > 0) {
        for (int i = tid; i < K1 * 16; i += 256)
            ((float4*)sW)[K0 * 16 + i] = ((const float4*)W1)[i];
    }

    for (int idx = tid; idx < 64 * KV; idx += 256) {
        int r = idx / KV, kc = idx % KV;
        int k = kc * 4;
        int grow = row0 + r;
        float4 v = make_float4(0.f, 0.f, 0.f, 0.f);
        if (grow < n) {
            if (k < K0) {
                v = *(const float4*)&A0[(size_t)grow * K0 + k];
            } else {
                v = *(const float4*)&A1[(size_t)grow * K1 + (k - K0)];
            }
        }
        int kcs = kc ^ ((r >> 2) & 3);
        *(float4*)&sA[r * K + kcs * 4] = v;
    }
    __syncthreads();

    const int tc = tid & 15;
    const int tr = tid >> 4;
    const int sw = tr & 3;
    float4 acc[4];
#pragma unroll
    for (int rr = 0; rr < 4; ++rr) acc[rr] = make_float4(0.f, 0.f, 0.f, 0.f);

#pragma unroll 4
    for (int kc = 0; kc < KV; ++kc) {
        int ks = (kc ^ sw) * 4;
        float4 a[4], w[4];
#pragma unroll
        for (int rr = 0; rr < 4; ++rr)
            a[rr] = *(const float4*)&sA[(tr * 4 + rr) * K + ks];
#pragma unroll
        for (int kk = 0; kk < 4; ++kk)
            w[kk] = *(const float4*)&sW[(kc * 4 + kk) * 64 + tc * 4];
#pragma unroll
        for (int kk = 0; kk < 4; ++kk) {
#pragma unroll
            for (int rr = 0; rr < 4; ++rr) {
                float av = (&a[rr].x)[kk];
                acc[rr].x = fmaf(av, w[kk].x, acc[rr].x);
                acc[rr].y = fmaf(av, w[kk].y, acc[rr].y);
                acc[rr].z = fmaf(av, w[kk].z, acc[rr].z);
                acc[rr].w = fmaf(av, w[kk].w, acc[rr].w);
            }
        }
    }

    float4 b4 = make_float4(0.f, 0.f, 0.f, 0.f);
    if (bias) b4 = *(const float4*)&bias[tc * 4];
#pragma unroll
    for (int rr = 0; rr < 4; ++rr) {
        int r = row0 + tr * 4 + rr;
        if (r < n) {
            float4 v = acc[rr];
            v.x += b4.x; v.y += b4.y; v.z += b4.z; v.w += b4.w;
            if (RELU) {
                v.x = fmaxf(v.x, 0.f); v.y = fmaxf(v.y, 0.f);
                v.z = fmaxf(v.z, 0.f); v.w = fmaxf(v.w, 0.f);
            }
            if (out) *(float4*)&out[(size_t)r * 64 + tc * 4] = v;
            if (out_bf) {
                ushort4 ub;
                ub.x = f2bf(v.x); ub.y = f2bf(v.y);
                ub.z = f2bf(v.z); ub.w = f2bf(v.w);
                *(ushort4*)&out_bf[(size_t)r * 64 + tc * 4] = ub;
            }
        }
    }
}

// ---- edge scorer: out[e] = tanh( relu(P[s]+Q[d]) . w2 + b2 ), bf16 P/Q ----
__global__ __launch_bounds__(256) void k_score_bf(
    const unsigned short* __restrict__ P, const unsigned short* __restrict__ Q,
    const int* __restrict__ msrc, const int* __restrict__ mdst,
    const float* __restrict__ w2, const float* __restrict__ b2,
    float* __restrict__ out, int M) {
    int gid = blockIdx.x * 256 + threadIdx.x;
    int e = gid >> 4;
    if (e >= M) return;
    int l = gid & 15;
    int s = msrc[e], d = mdst[e];
    ushort4 up = *(const ushort4*)&P[(size_t)s * 64 + l * 4];
    ushort4 uq = *(const ushort4*)&Q[(size_t)d * 64 + l * 4];
    float4 w = *(const float4*)&w2[l * 4];
    float ux = fmaxf(bf2f(up.x) + bf2f(uq.x), 0.f);
    float uy = fmaxf(bf2f(up.y) + bf2f(uq.y), 0.f);
    float uz = fmaxf(bf2f(up.z) + bf2f(uq.z), 0.f);
    float uw = fmaxf(bf2f(up.w) + bf2f(uq.w), 0.f);
    float partial = ux * w.x + uy * w.y + uz * w.z + uw * w.w;
#pragma unroll
    for (int m = 1; m < 16; m <<= 1) partial += __shfl_xor(partial, m, 16);
    if (l == 0) out[e] = tanhf(partial + b2[0]);
}

extern "C" void kernel_launch(void* const* d_in, const int* in_sizes, int n_in,
                              void* d_out, int out_size, void* d_ws, size_t ws_size,
                              hipStream_t stream) {
    const float* x      = (const float*)d_in[0];
    const int*   ei     = (const int*)d_in[1];
    const int*   mei    = (const int*)d_in[2];
    const float* lin1_w = (const float*)d_in[3];
    const float* lin1_b = (const float*)d_in[4];
    const float* lin2_w = (const float*)d_in[5];
    const float* lin2_b = (const float*)d_in[6];
    const float* c1_wl  = (const float*)d_in[7];
    const float* c1_bl  = (const float*)d_in[8];
    const float* c1_wr  = (const float*)d_in[9];
    const float* c2_wl  = (const float*)d_in[10];
    const float* c2_bl  = (const float*)d_in[11];
    const float* c2_wr  = (const float*)d_in[12];
    const float* mlp_w1 = (const float*)d_in[13];
    const float* mlp_b1 = (const float*)d_in[14];
    const float* mlp_w2 = (const float*)d_in[15];
    const float* mlp_b2 = (const float*)d_in[16];

    const int N = in_sizes[0] / 128;
    const int E = in_sizes[1] / 2;
    const int M = in_sizes[2] / 2;
    const int* src  = ei;
    const int* dstE = ei + E;
    const int* msrc = mei;
    const int* mdst = mei + M;

    // bucket shift: 512 nodes/bucket, <=256 buckets
    int shift = 9;
    while ((((N - 1) >> shift) + 1) > MAXB) ++shift;
    const int nbuckets = ((N - 1) >> shift) + 1;

    const size_t N64 = (size_t)N * 64;
    float* bufA    = (float*)d_ws;              // N*64 f32
    float* bufB    = bufA + N64;                // N*64 f32 (aliased by bb / Qbf)
    float* bufC    = bufB + N64;                // N*64 f32
    unsigned short* Hbf = (unsigned short*)(bufC + N64);   // N*64 bf16
    float* inv_deg = (float*)(Hbf + N64);       // N
    int*   row_ptr = (int*)(inv_deg + N);       // N+1
    int*   bcnt    = row_ptr + (N + 1);         // MAXB
    int*   boff    = bcnt + MAXB;               // MAXB
    int*   bcur    = boff + MAXB;               // MAXB
    int*   csr     = bcur + MAXB;               // E
    unsigned* bb   = (unsigned*)bufB;           // E (dead before first gather)
    unsigned short* Pbf = (unsigned short*)bufA; // N*64 bf16 (A dead after sage2)
    unsigned short* Qbf = (unsigned short*)bufB; // N*64 bf16 (B dead after sage2)
    float* outf = (float*)d_out;

    const int nbN = (N + 63) / 64;
    const int nbM = (int)(((long long)M * 16 + 255) / 256);
    const int nbG = (int)(((long long)N * 64 + 255) / 256);
    const int nbP = (E + PART_CH - 1) / PART_CH;

    // ---- CSR build: count -> scan -> partition -> per-bucket fill ----
    hipMemsetAsync(bcnt, 0, MAXB * sizeof(int), stream);
    k_bcount<<<512, 256, 0, stream>>>(dstE, bcnt, E, shift);
    k_bscan<<<1, MAXB, 0, stream>>>(bcnt, boff, bcur, nbuckets);
    k_part<<<nbP, 256, 0, stream>>>(src, dstE, bcur, bb, E, shift);
    k_bfill<<<nbuckets, 512, 0, stream>>>(bb, boff, bcnt, row_ptr,
                                          inv_deg, csr, N, E, shift);

    // h1 = relu(x @ lin1_w + b)          -> A (f32) + Hbf (bf16)
    node_mm<128, 0, true><<<nbN, 256, 0, stream>>>(
        x, nullptr, lin1_w, nullptr, lin1_b, bufA, Hbf, N);

    // sage1: agg = mean gather (bf16 in) -> B; h2 = relu([B|A]@[wl;wr]+bl) -> C
    k_gather_bf<<<nbG, 256, 0, stream>>>(Hbf, csr, row_ptr, inv_deg, bufB, N);
    node_mm<64, 64, true><<<nbN, 256, 0, stream>>>(
        bufB, bufA, c1_wl, c1_wr, c1_bl, bufC, nullptr, N);

    // h3 = relu(h2 @ lin2_w + b)         -> A (f32) + Hbf (bf16)
    node_mm<64, 0, true><<<nbN, 256, 0, stream>>>(
        bufC, nullptr, lin2_w, nullptr, lin2_b, bufA, Hbf, N);

    // sage2 -> C (h4)
    k_gather_bf<<<nbG, 256, 0, stream>>>(Hbf, csr, row_ptr, inv_deg, bufB, N);
    node_mm<64, 64, true><<<nbN, 256, 0, stream>>>(
        bufB, bufA, c2_wl, c2_wr, c2_bl, bufC, nullptr, N);

    // P = h4 @ W1[:64] + b1 -> Pbf ; Q = h4 @ W1[64:] -> Qbf   (bf16 only)
    node_mm<64, 0, false><<<nbN, 256, 0, stream>>>(
        bufC, nullptr, mlp_w1, nullptr, mlp_b1, nullptr, Pbf, N);
    node_mm<64, 0, false><<<nbN, 256, 0, stream>>>(
        bufC, nullptr, mlp_w1 + 64 * 64, nullptr, nullptr, nullptr, Qbf, N);

    // edge scoring
    k_score_bf<<<nbM, 256, 0, stream>>>(Pbf, Qbf, msrc, mdst, mlp_w2, mlp_b2,
                                        outf, M);
}

// Round 6
// 564.228 us; speedup vs baseline: 2.0554x; 1.0542x over previous
//
#include <hip/hip_runtime.h>
#include <math.h>

#define MAXB 512   // max buckets (256 dst nodes each at shift=8, N<=131072)

// ---- bf16 helpers (RNE) ----
static __device__ __forceinline__ unsigned short f2bf(float f) {
    unsigned u = __float_as_uint(f);
    u += 0x7fffu + ((u >> 16) & 1u);
    return (unsigned short)(u >> 16);
}
static __device__ __forceinline__ float bf2f(unsigned short s) {
    return __uint_as_float((unsigned)s << 16);
}

// ========== Phase A: per-bucket edge counts ==========
__global__ __launch_bounds__(256) void k_bcount(const int* __restrict__ dst,
                                                int* __restrict__ bucket_cnt,
                                                int E, int shift) {
    __shared__ int h[MAXB];
    for (int i = threadIdx.x; i < MAXB; i += 256) h[i] = 0;
    __syncthreads();
    int stride = gridDim.x * 256;
    for (int i = blockIdx.x * 256 + threadIdx.x; i < E; i += stride)
        atomicAdd(&h[dst[i] >> shift], 1);
    __syncthreads();
    for (int i = threadIdx.x; i < MAXB; i += 256)
        if (h[i]) atomicAdd(&bucket_cnt[i], h[i]);
}

// ========== scan bucket counts -> bucket_off, bucket_cur ==========
__global__ __launch_bounds__(MAXB) void k_bscan(const int* __restrict__ bucket_cnt,
                                                int* __restrict__ bucket_off,
                                                int* __restrict__ bucket_cur,
                                                int nbuckets) {
    __shared__ int s[MAXB];
    int t = threadIdx.x;
    int v = (t < nbuckets) ? bucket_cnt[t] : 0;
    s[t] = v;
    __syncthreads();
    for (int off = 1; off < MAXB; off <<= 1) {
        int u = (t >= off) ? s[t - off] : 0;
        __syncthreads();
        s[t] += u;
        __syncthreads();
    }
    int excl = s[t] - v;
    if (t < nbuckets) { bucket_off[t] = excl; bucket_cur[t] = excl; }
}

// ========== Phase B: partition edges into bucket runs (compacted writes) ====
// 1024 threads/block, 8192-edge chunks: 391 blocks x 16 waves ~76% occupancy.
#define PART_CH 8192
#define PART_BS 1024
__global__ __launch_bounds__(PART_BS) void k_part(const int* __restrict__ src,
                                                  const int* __restrict__ dst,
                                                  int* __restrict__ bucket_cur,
                                                  unsigned* __restrict__ bb,
                                                  int E, int shift) {
    __shared__ int h[MAXB], base[MAXB];
    int b0 = blockIdx.x * PART_CH;
    int e1 = min(b0 + PART_CH, E);
    for (int i = threadIdx.x; i < MAXB; i += PART_BS) h[i] = 0;
    __syncthreads();
    for (int i = b0 + threadIdx.x; i < e1; i += PART_BS)
        atomicAdd(&h[dst[i] >> shift], 1);
    __syncthreads();
    for (int i = threadIdx.x; i < MAXB; i += PART_BS) {
        base[i] = h[i] ? atomicAdd(&bucket_cur[i], h[i]) : 0;
        h[i] = 0;  // reuse as local cursor
    }
    __syncthreads();
    unsigned mask = (1u << shift) - 1u;
    for (int i = b0 + threadIdx.x; i < e1; i += PART_BS) {
        int d = dst[i];
        int b = d >> shift;
        int r = atomicAdd(&h[b], 1);
        bb[base[b] + r] = ((unsigned)src[i] << shift) | ((unsigned)d & mask);
    }
}

// ========== Phase C: per-bucket deg/rowptr/csr fill, all counters in LDS ====
// (bucket size <= 512 nodes; works for shift=8's 256-node buckets too)
__global__ __launch_bounds__(512) void k_bfill(const unsigned* __restrict__ bb,
                                               const int* __restrict__ bucket_off,
                                               const int* __restrict__ bucket_cnt,
                                               int* __restrict__ row_ptr,
                                               float* __restrict__ inv_deg,
                                               int* __restrict__ csr,
                                               int N, int E, int shift) {
    __shared__ int deg[512], cur[512], s[512];
    int b = blockIdx.x;
    int t = threadIdx.x;
    int lo = b << shift;
    int hi = min(N, (b + 1) << shift);
    int nn = hi - lo;
    int off = bucket_off[b];
    int cnt = bucket_cnt[b];
    unsigned mask = (1u << shift) - 1u;

    deg[t] = 0;
    __syncthreads();
    for (int i = off + t; i < off + cnt; i += 512)
        atomicAdd(&deg[bb[i] & mask], 1);
    __syncthreads();
    int d = deg[t];
    s[t] = d;
    __syncthreads();
    for (int o = 1; o < 512; o <<= 1) {
        int u = (t >= o) ? s[t - o] : 0;
        __syncthreads();
        s[t] += u;
        __syncthreads();
    }
    int excl = s[t] - d;
    cur[t] = excl;
    if (t < nn) {
        row_ptr[lo + t] = off + excl;
        inv_deg[lo + t] = d > 0 ? 1.0f / (float)d : 0.0f;
    }
    if (t == 0 && hi == N) row_ptr[N] = E;
    __syncthreads();
    for (int i = off + t; i < off + cnt; i += 512) {
        unsigned w = bb[i];
        int dl = (int)(w & mask);
        int pos = atomicAdd(&cur[dl], 1);
        csr[off + pos] = (int)(w >> shift);
    }
}

// ====== mean aggregation, bf16 rows, 4 rows in flight per wave ======
__global__ __launch_bounds__(256) void k_gather_bf(
    const unsigned short* __restrict__ hbf, const int* __restrict__ csr,
    const int* __restrict__ row_ptr, const float* __restrict__ inv_deg,
    float* __restrict__ out, int n) {
    int wave = (blockIdx.x * 256 + (int)threadIdx.x) >> 6;
    if (wave >= n) return;
    int lane = threadIdx.x & 63;
    int g = lane >> 4, sub = lane & 15;
    int start = row_ptr[wave], end = row_ptr[wave + 1];
    float4 acc = make_float4(0.f, 0.f, 0.f, 0.f);
    for (int base = start; base < end; base += 16) {
        int j0 = base + g;
        int j1 = j0 + 4, j2 = j0 + 8, j3 = j0 + 12;
        int last = end - 1;
        int s0 = csr[min(j0, last)];
        int s1 = csr[min(j1, last)];
        int s2 = csr[min(j2, last)];
        int s3 = csr[min(j3, last)];
        ushort4 u0 = *(const ushort4*)&hbf[(size_t)s0 * 64 + sub * 4];
        ushort4 u1 = *(const ushort4*)&hbf[(size_t)s1 * 64 + sub * 4];
        ushort4 u2 = *(const ushort4*)&hbf[(size_t)s2 * 64 + sub * 4];
        ushort4 u3 = *(const ushort4*)&hbf[(size_t)s3 * 64 + sub * 4];
        float m0 = (j0 < end) ? 1.f : 0.f;
        float m1 = (j1 < end) ? 1.f : 0.f;
        float m2 = (j2 < end) ? 1.f : 0.f;
        float m3 = (j3 < end) ? 1.f : 0.f;
        acc.x = fmaf(m0, bf2f(u0.x), acc.x);
        acc.y = fmaf(m0, bf2f(u0.y), acc.y);
        acc.z = fmaf(m0, bf2f(u0.z), acc.z);
        acc.w = fmaf(m0, bf2f(u0.w), acc.w);
        acc.x = fmaf(m1, bf2f(u1.x), acc.x);
        acc.y = fmaf(m1, bf2f(u1.y), acc.y);
        acc.z = fmaf(m1, bf2f(u1.z), acc.z);
        acc.w = fmaf(m1, bf2f(u1.w), acc.w);
        acc.x = fmaf(m2, bf2f(u2.x), acc.x);
        acc.y = fmaf(m2, bf2f(u2.y), acc.y);
        acc.z = fmaf(m2, bf2f(u2.z), acc.z);
        acc.w = fmaf(m2, bf2f(u2.w), acc.w);
        acc.x = fmaf(m3, bf2f(u3.x), acc.x);
        acc.y = fmaf(m3, bf2f(u3.y), acc.y);
        acc.z = fmaf(m3, bf2f(u3.z), acc.z);
        acc.w = fmaf(m3, bf2f(u3.w), acc.w);
    }
    acc.x += __shfl_xor(acc.x, 16, 64);
    acc.y += __shfl_xor(acc.y, 16, 64);
    acc.z += __shfl_xor(acc.z, 16, 64);
    acc.w += __shfl_xor(acc.w, 16, 64);
    acc.x += __shfl_xor(acc.x, 32, 64);
    acc.y += __shfl_xor(acc.y, 32, 64);
    acc.z += __shfl_xor(acc.z, 32, 64);
    acc.w += __shfl_xor(acc.w, 32, 64);
    if (g == 0) {
        float idv = inv_deg[wave];
        float4 r = make_float4(acc.x * idv, acc.y * idv, acc.z * idv, acc.w * idv);
        *(float4*)&out[(size_t)wave * 64 + sub * 4] = r;
    }
}

// ---- fused node matmul: out[N,64] = act([A0|A1] @ [W0;W1] + bias) ----
template <int K0, int K1, bool RELU>
__global__ __launch_bounds__(256) void node_mm(
    const float* __restrict__ A0, const float* __restrict__ A1,
    const float* __restrict__ W0, const float* __restrict__ W1,
    const float* __restrict__ bias, float* __restrict__ out,
    unsigned short* __restrict__ out_bf, int n) {
    constexpr int K = K0 + K1;
    constexpr int KV = K / 4;
    __shared__ float sA[64 * K];
    __shared__ float sW[K * 64];
    const int tid = threadIdx.x;
    const int row0 = blockIdx.x * 64;

    for (int i = tid; i < K0 * 16; i += 256)
        ((float4*)sW)[i] = ((const float4*)W0)[i];
    if (K1 > 0) {
        for (int i = tid; i < K1 * 16; i += 256)
            ((float4*)sW)[K0 * 16 + i] = ((const float4*)W1)[i];
    }

    for (int idx = tid; idx < 64 * KV; idx += 256) {
        int r = idx / KV, kc = idx % KV;
        int k = kc * 4;
        int grow = row0 + r;
        float4 v = make_float4(0.f, 0.f, 0.f, 0.f);
        if (grow < n) {
            if (k < K0) {
                v = *(const float4*)&A0[(size_t)grow * K0 + k];
            } else {
                v = *(const float4*)&A1[(size_t)grow * K1 + (k - K0)];
            }
        }
        int kcs = kc ^ ((r >> 2) & 3);
        *(float4*)&sA[r * K + kcs * 4] = v;
    }
    __syncthreads();

    const int tc = tid & 15;
    const int tr = tid >> 4;
    const int sw = tr & 3;
    float4 acc[4];
#pragma unroll
    for (int rr = 0; rr < 4; ++rr) acc[rr] = make_float4(0.f, 0.f, 0.f, 0.f);

#pragma unroll 4
    for (int kc = 0; kc < KV; ++kc) {
        int ks = (kc ^ sw) * 4;
        float4 a[4], w[4];
#pragma unroll
        for (int rr = 0; rr < 4; ++rr)
            a[rr] = *(const float4*)&sA[(tr * 4 + rr) * K + ks];
#pragma unroll
        for (int kk = 0; kk < 4; ++kk)
            w[kk] = *(const float4*)&sW[(kc * 4 + kk) * 64 + tc * 4];
#pragma unroll
        for (int kk = 0; kk < 4; ++kk) {
#pragma unroll
            for (int rr = 0; rr < 4; ++rr) {
                float av = (&a[rr].x)[kk];
                acc[rr].x = fmaf(av, w[kk].x, acc[rr].x);
                acc[rr].y = fmaf(av, w[kk].y, acc[rr].y);
                acc[rr].z = fmaf(av, w[kk].z, acc[rr].z);
                acc[rr].w = fmaf(av, w[kk].w, acc[rr].w);
            }
        }
    }

    float4 b4 = make_float4(0.f, 0.f, 0.f, 0.f);
    if (bias) b4 = *(const float4*)&bias[tc * 4];
#pragma unroll
    for (int rr = 0; rr < 4; ++rr) {
        int r = row0 + tr * 4 + rr;
        if (r < n) {
            float4 v = acc[rr];
            v.x += b4.x; v.y += b4.y; v.z += b4.z; v.w += b4.w;
            if (RELU) {
                v.x = fmaxf(v.x, 0.f); v.y = fmaxf(v.y, 0.f);
                v.z = fmaxf(v.z, 0.f); v.w = fmaxf(v.w, 0.f);
            }
            if (out) *(float4*)&out[(size_t)r * 64 + tc * 4] = v;
            if (out_bf) {
                ushort4 ub;
                ub.x = f2bf(v.x); ub.y = f2bf(v.y);
                ub.z = f2bf(v.z); ub.w = f2bf(v.w);
                *(ushort4*)&out_bf[(size_t)r * 64 + tc * 4] = ub;
            }
        }
    }
}

// ---- edge scorer: out[e] = tanh( relu(P[s]+Q[d]) . w2 + b2 ), bf16 P/Q ----
__global__ __launch_bounds__(256) void k_score_bf(
    const unsigned short* __restrict__ P, const unsigned short* __restrict__ Q,
    const int* __restrict__ msrc, const int* __restrict__ mdst,
    const float* __restrict__ w2, const float* __restrict__ b2,
    float* __restrict__ out, int M) {
    int gid = blockIdx.x * 256 + threadIdx.x;
    int e = gid >> 4;
    if (e >= M) return;
    int l = gid & 15;
    int s = msrc[e], d = mdst[e];
    ushort4 up = *(const ushort4*)&P[(size_t)s * 64 + l * 4];
    ushort4 uq = *(const ushort4*)&Q[(size_t)d * 64 + l * 4];
    float4 w = *(const float4*)&w2[l * 4];
    float ux = fmaxf(bf2f(up.x) + bf2f(uq.x), 0.f);
    float uy = fmaxf(bf2f(up.y) + bf2f(uq.y), 0.f);
    float uz = fmaxf(bf2f(up.z) + bf2f(uq.z), 0.f);
    float uw = fmaxf(bf2f(up.w) + bf2f(uq.w), 0.f);
    float partial = ux * w.x + uy * w.y + uz * w.z + uw * w.w;
#pragma unroll
    for (int m = 1; m < 16; m <<= 1) partial += __shfl_xor(partial, m, 16);
    if (l == 0) out[e] = tanhf(partial + b2[0]);
}

extern "C" void kernel_launch(void* const* d_in, const int* in_sizes, int n_in,
                              void* d_out, int out_size, void* d_ws, size_t ws_size,
                              hipStream_t stream) {
    const float* x      = (const float*)d_in[0];
    const int*   ei     = (const int*)d_in[1];
    const int*   mei    = (const int*)d_in[2];
    const float* lin1_w = (const float*)d_in[3];
    const float* lin1_b = (const float*)d_in[4];
    const float* lin2_w = (const float*)d_in[5];
    const float* lin2_b = (const float*)d_in[6];
    const float* c1_wl  = (const float*)d_in[7];
    const float* c1_bl  = (const float*)d_in[8];
    const float* c1_wr  = (const float*)d_in[9];
    const float* c2_wl  = (const float*)d_in[10];
    const float* c2_bl  = (const float*)d_in[11];
    const float* c2_wr  = (const float*)d_in[12];
    const float* mlp_w1 = (const float*)d_in[13];
    const float* mlp_b1 = (const float*)d_in[14];
    const float* mlp_w2 = (const float*)d_in[15];
    const float* mlp_b2 = (const float*)d_in[16];

    const int N = in_sizes[0] / 128;
    const int E = in_sizes[1] / 2;
    const int M = in_sizes[2] / 2;
    const int* src  = ei;
    const int* dstE = ei + E;
    const int* msrc = mei;
    const int* mdst = mei + M;

    // bucket shift: 256 nodes/bucket, <=512 buckets
    int shift = 8;
    while ((((N - 1) >> shift) + 1) > MAXB) ++shift;
    const int nbuckets = ((N - 1) >> shift) + 1;

    const size_t N64 = (size_t)N * 64;
    float* bufA    = (float*)d_ws;              // N*64 f32
    float* bufB    = bufA + N64;                // N*64 f32 (aliased by bb / Qbf)
    float* bufC    = bufB + N64;                // N*64 f32
    unsigned short* Hbf = (unsigned short*)(bufC + N64);   // N*64 bf16
    float* inv_deg = (float*)(Hbf + N64);       // N
    int*   row_ptr = (int*)(inv_deg + N);       // N+1
    int*   bcnt    = row_ptr + (N + 1);         // MAXB
    int*   boff    = bcnt + MAXB;               // MAXB
    int*   bcur    = boff + MAXB;               // MAXB
    int*   csr     = bcur + MAXB;               // E
    unsigned* bb   = (unsigned*)bufB;           // E (dead before first gather)
    unsigned short* Pbf = (unsigned short*)bufA; // N*64 bf16 (A dead after sage2)
    unsigned short* Qbf = (unsigned short*)bufB; // N*64 bf16 (B dead after sage2)
    float* outf = (float*)d_out;

    const int nbN = (N + 63) / 64;
    const int nbM = (int)(((long long)M * 16 + 255) / 256);
    const int nbG = (int)(((long long)N * 64 + 255) / 256);
    const int nbP = (E + PART_CH - 1) / PART_CH;

    // ---- CSR build: count -> scan -> partition -> per-bucket fill ----
    hipMemsetAsync(bcnt, 0, MAXB * sizeof(int), stream);
    k_bcount<<<512, 256, 0, stream>>>(dstE, bcnt, E, shift);
    k_bscan<<<1, MAXB, 0, stream>>>(bcnt, boff, bcur, nbuckets);
    k_part<<<nbP, PART_BS, 0, stream>>>(src, dstE, bcur, bb, E, shift);
    k_bfill<<<nbuckets, 512, 0, stream>>>(bb, boff, bcnt, row_ptr,
                                          inv_deg, csr, N, E, shift);

    // h1 = relu(x @ lin1_w + b)          -> A (f32) + Hbf (bf16)
    node_mm<128, 0, true><<<nbN, 256, 0, stream>>>(
        x, nullptr, lin1_w, nullptr, lin1_b, bufA, Hbf, N);

    // sage1: agg = mean gather (bf16 in) -> B; h2 = relu([B|A]@[wl;wr]+bl) -> C
    k_gather_bf<<<nbG, 256, 0, stream>>>(Hbf, csr, row_ptr, inv_deg, bufB, N);
    node_mm<64, 64, true><<<nbN, 256, 0, stream>>>(
        bufB, bufA, c1_wl, c1_wr, c1_bl, bufC, nullptr, N);

    // h3 = relu(h2 @ lin2_w + b)         -> A (f32) + Hbf (bf16)
    node_mm<64, 0, true><<<nbN, 256, 0, stream>>>(
        bufC, nullptr, lin2_w, nullptr, lin2_b, bufA, Hbf, N);

    // sage2 -> C (h4)
    k_gather_bf<<<nbG, 256, 0, stream>>>(Hbf, csr, row_ptr, inv_deg, bufB, N);
    node_mm<64, 64, true><<<nbN, 256, 0, stream>>>(
        bufB, bufA, c2_wl, c2_wr, c2_bl, bufC, nullptr, N);

    // P = h4 @ W1[:64] + b1 -> Pbf ; Q = h4 @ W1[64:] -> Qbf   (bf16 only)
    node_mm<64, 0, false><<<nbN, 256, 0, stream>>>(
        bufC, nullptr, mlp_w1, nullptr, mlp_b1, nullptr, Pbf, N);
    node_mm<64, 0, false><<<nbN, 256, 0, stream>>>(
        bufC, nullptr, mlp_w1 + 64 * 64, nullptr, nullptr, nullptr, Qbf, N);

    // edge scoring
    k_score_bf<<<nbM, 256, 0, stream>>>(Pbf, Qbf, msrc, mdst, mlp_w2, mlp_b2,
                                        outf, M);
}

// Round 7
// 549.329 us; speedup vs baseline: 2.1111x; 1.0271x over previous
//
#include <hip/hip_runtime.h>
#include <math.h>

#define MAXB 512   // max buckets (256 dst nodes each at shift=8, N<=131072)

// ---- bf16 helpers (RNE) ----
static __device__ __forceinline__ unsigned short f2bf(float f) {
    unsigned u = __float_as_uint(f);
    u += 0x7fffu + ((u >> 16) & 1u);
    return (unsigned short)(u >> 16);
}
static __device__ __forceinline__ float bf2f(unsigned short s) {
    return __uint_as_float((unsigned)s << 16);
}

// ========== Phase A: per-bucket edge counts ==========
__global__ __launch_bounds__(256) void k_bcount(const int* __restrict__ dst,
                                                int* __restrict__ bucket_cnt,
                                                int E, int shift) {
    __shared__ int h[MAXB];
    for (int i = threadIdx.x; i < MAXB; i += 256) h[i] = 0;
    __syncthreads();
    int stride = gridDim.x * 256;
    for (int i = blockIdx.x * 256 + threadIdx.x; i < E; i += stride)
        atomicAdd(&h[dst[i] >> shift], 1);
    __syncthreads();
    for (int i = threadIdx.x; i < MAXB; i += 256)
        if (h[i]) atomicAdd(&bucket_cnt[i], h[i]);
}

// ========== scan bucket counts -> bucket_off, bucket_cur ==========
__global__ __launch_bounds__(MAXB) void k_bscan(const int* __restrict__ bucket_cnt,
                                                int* __restrict__ bucket_off,
                                                int* __restrict__ bucket_cur,
                                                int nbuckets) {
    __shared__ int s[MAXB];
    int t = threadIdx.x;
    int v = (t < nbuckets) ? bucket_cnt[t] : 0;
    s[t] = v;
    __syncthreads();
    for (int off = 1; off < MAXB; off <<= 1) {
        int u = (t >= off) ? s[t - off] : 0;
        __syncthreads();
        s[t] += u;
        __syncthreads();
    }
    int excl = s[t] - v;
    if (t < nbuckets) { bucket_off[t] = excl; bucket_cur[t] = excl; }
}

// ========== Phase B: partition edges into bucket runs ==========
#define PART_CH 8192
#define PART_BS 1024
__global__ __launch_bounds__(PART_BS) void k_part(const int* __restrict__ src,
                                                  const int* __restrict__ dst,
                                                  int* __restrict__ bucket_cur,
                                                  unsigned* __restrict__ bb,
                                                  int E, int shift) {
    __shared__ int h[MAXB], base[MAXB];
    int b0 = blockIdx.x * PART_CH;
    int e1 = min(b0 + PART_CH, E);
    for (int i = threadIdx.x; i < MAXB; i += PART_BS) h[i] = 0;
    __syncthreads();
    for (int i = b0 + threadIdx.x; i < e1; i += PART_BS)
        atomicAdd(&h[dst[i] >> shift], 1);
    __syncthreads();
    for (int i = threadIdx.x; i < MAXB; i += PART_BS) {
        base[i] = h[i] ? atomicAdd(&bucket_cur[i], h[i]) : 0;
        h[i] = 0;
    }
    __syncthreads();
    unsigned mask = (1u << shift) - 1u;
    for (int i = b0 + threadIdx.x; i < e1; i += PART_BS) {
        int d = dst[i];
        int b = d >> shift;
        int r = atomicAdd(&h[b], 1);
        bb[base[b] + r] = ((unsigned)src[i] << shift) | ((unsigned)d & mask);
    }
}

// ========== Phase C: per-bucket deg/rowptr/csr fill ==========
__global__ __launch_bounds__(512) void k_bfill(const unsigned* __restrict__ bb,
                                               const int* __restrict__ bucket_off,
                                               const int* __restrict__ bucket_cnt,
                                               int* __restrict__ row_ptr,
                                               float* __restrict__ inv_deg,
                                               int* __restrict__ csr,
                                               int N, int E, int shift) {
    __shared__ int deg[512], cur[512], s[512];
    int b = blockIdx.x;
    int t = threadIdx.x;
    int lo = b << shift;
    int hi = min(N, (b + 1) << shift);
    int nn = hi - lo;
    int off = bucket_off[b];
    int cnt = bucket_cnt[b];
    unsigned mask = (1u << shift) - 1u;

    deg[t] = 0;
    __syncthreads();
    for (int i = off + t; i < off + cnt; i += 512)
        atomicAdd(&deg[bb[i] & mask], 1);
    __syncthreads();
    int d = deg[t];
    s[t] = d;
    __syncthreads();
    for (int o = 1; o < 512; o <<= 1) {
        int u = (t >= o) ? s[t - o] : 0;
        __syncthreads();
        s[t] += u;
        __syncthreads();
    }
    int excl = s[t] - d;
    cur[t] = excl;
    if (t < nn) {
        row_ptr[lo + t] = off + excl;
        inv_deg[lo + t] = d > 0 ? 1.0f / (float)d : 0.0f;
    }
    if (t == 0 && hi == N) row_ptr[N] = E;
    __syncthreads();
    for (int i = off + t; i < off + cnt; i += 512) {
        unsigned w = bb[i];
        int dl = (int)(w & mask);
        int pos = atomicAdd(&cur[dl], 1);
        csr[off + pos] = (int)(w >> shift);
    }
}

// ====== mean aggregation, bf16 rows, 32 rows in flight per wave ======
__global__ __launch_bounds__(256) void k_gather_bf(
    const unsigned short* __restrict__ hbf, const int* __restrict__ csr,
    const int* __restrict__ row_ptr, const float* __restrict__ inv_deg,
    float* __restrict__ out, int n) {
    int wave = (blockIdx.x * 256 + (int)threadIdx.x) >> 6;
    if (wave >= n) return;
    int lane = threadIdx.x & 63;
    int g = lane >> 4, sub = lane & 15;
    int start = row_ptr[wave], end = row_ptr[wave + 1];
    float4 acc = make_float4(0.f, 0.f, 0.f, 0.f);
    for (int base = start; base < end; base += 32) {
        int last = end - 1;
        int jj[8], idx[8];
#pragma unroll
        for (int t = 0; t < 8; ++t) {
            jj[t] = base + g + 4 * t;
            idx[t] = csr[min(jj[t], last)];
        }
        ushort4 u[8];
#pragma unroll
        for (int t = 0; t < 8; ++t)
            u[t] = *(const ushort4*)(hbf + (((unsigned)idx[t] << 6) + ((unsigned)sub << 2)));
#pragma unroll
        for (int t = 0; t < 8; ++t) {
            float m = (jj[t] < end) ? 1.f : 0.f;
            acc.x = fmaf(m, bf2f(u[t].x), acc.x);
            acc.y = fmaf(m, bf2f(u[t].y), acc.y);
            acc.z = fmaf(m, bf2f(u[t].z), acc.z);
            acc.w = fmaf(m, bf2f(u[t].w), acc.w);
        }
    }
    acc.x += __shfl_xor(acc.x, 16, 64);
    acc.y += __shfl_xor(acc.y, 16, 64);
    acc.z += __shfl_xor(acc.z, 16, 64);
    acc.w += __shfl_xor(acc.w, 16, 64);
    acc.x += __shfl_xor(acc.x, 32, 64);
    acc.y += __shfl_xor(acc.y, 32, 64);
    acc.z += __shfl_xor(acc.z, 32, 64);
    acc.w += __shfl_xor(acc.w, 32, 64);
    if (g == 0) {
        float idv = inv_deg[wave];
        float4 r = make_float4(acc.x * idv, acc.y * idv, acc.z * idv, acc.w * idv);
        *(float4*)&out[(size_t)wave * 64 + sub * 4] = r;
    }
}

// ---- mm1: Hbf = relu(x @ lin1_w + b)  (K=128 f32 in, bf16 out only) ----
__global__ __launch_bounds__(256) void k_mm1(
    const float* __restrict__ A0, const float* __restrict__ W0,
    const float* __restrict__ bias, unsigned short* __restrict__ out_bf, int n) {
    constexpr int K = 128, KV = 32;
    __shared__ float sA[64 * K];
    __shared__ float sW[K * 64];
    const int tid = threadIdx.x;
    const int row0 = blockIdx.x * 64;

    for (int i = tid; i < K * 16; i += 256)
        ((float4*)sW)[i] = ((const float4*)W0)[i];
    for (int idx = tid; idx < 64 * KV; idx += 256) {
        int r = idx / KV, kc = idx % KV;
        int grow = row0 + r;
        float4 v = make_float4(0.f, 0.f, 0.f, 0.f);
        if (grow < n) v = *(const float4*)&A0[(size_t)grow * K + kc * 4];
        int kcs = kc ^ ((r >> 2) & 3);
        *(float4*)&sA[r * K + kcs * 4] = v;
    }
    __syncthreads();

    const int tc = tid & 15, tr = tid >> 4, sw = tr & 3;
    float4 acc[4];
#pragma unroll
    for (int rr = 0; rr < 4; ++rr) acc[rr] = make_float4(0.f, 0.f, 0.f, 0.f);
#pragma unroll 4
    for (int kc = 0; kc < KV; ++kc) {
        int ks = (kc ^ sw) * 4;
        float4 a[4], w[4];
#pragma unroll
        for (int rr = 0; rr < 4; ++rr) a[rr] = *(const float4*)&sA[(tr * 4 + rr) * K + ks];
#pragma unroll
        for (int kk = 0; kk < 4; ++kk) w[kk] = *(const float4*)&sW[(kc * 4 + kk) * 64 + tc * 4];
#pragma unroll
        for (int kk = 0; kk < 4; ++kk)
#pragma unroll
            for (int rr = 0; rr < 4; ++rr) {
                float av = (&a[rr].x)[kk];
                acc[rr].x = fmaf(av, w[kk].x, acc[rr].x);
                acc[rr].y = fmaf(av, w[kk].y, acc[rr].y);
                acc[rr].z = fmaf(av, w[kk].z, acc[rr].z);
                acc[rr].w = fmaf(av, w[kk].w, acc[rr].w);
            }
    }
    float4 b4 = *(const float4*)&bias[tc * 4];
#pragma unroll
    for (int rr = 0; rr < 4; ++rr) {
        int r = row0 + tr * 4 + rr;
        if (r < n) {
            float4 v = acc[rr];
            v.x = fmaxf(v.x + b4.x, 0.f); v.y = fmaxf(v.y + b4.y, 0.f);
            v.z = fmaxf(v.z + b4.z, 0.f); v.w = fmaxf(v.w + b4.w, 0.f);
            ushort4 ub = { f2bf(v.x), f2bf(v.y), f2bf(v.z), f2bf(v.w) };
            *(ushort4*)&out_bf[(size_t)r * 64 + tc * 4] = ub;
        }
    }
}

// ---- k_mm23: h3bf = relu( relu([agg|h1bf]@[wl;wr]+bl) @ lin2_w + lin2_b ) ----
// h2 tile never leaves LDS.
__global__ __launch_bounds__(256) void k_mm23(
    const float* __restrict__ A0, const unsigned short* __restrict__ A1bf,
    const float* __restrict__ W0, const float* __restrict__ W1,
    const float* __restrict__ bl, const float* __restrict__ W2,
    const float* __restrict__ b2, unsigned short* __restrict__ out_bf, int n) {
    constexpr int K = 128, KV = 32;
    __shared__ float sA[64 * K];
    __shared__ float sW[K * 64];
    const int tid = threadIdx.x;
    const int row0 = blockIdx.x * 64;

    for (int i = tid; i < 64 * 16; i += 256) ((float4*)sW)[i] = ((const float4*)W0)[i];
    for (int i = tid; i < 64 * 16; i += 256) ((float4*)sW)[64 * 16 + i] = ((const float4*)W1)[i];
    for (int idx = tid; idx < 64 * KV; idx += 256) {
        int r = idx / KV, kc = idx % KV;
        int grow = row0 + r;
        float4 v = make_float4(0.f, 0.f, 0.f, 0.f);
        if (grow < n) {
            if (kc < 16) {
                v = *(const float4*)&A0[(size_t)grow * 64 + kc * 4];
            } else {
                ushort4 u = *(const ushort4*)&A1bf[(size_t)grow * 64 + (kc - 16) * 4];
                v = make_float4(bf2f(u.x), bf2f(u.y), bf2f(u.z), bf2f(u.w));
            }
        }
        int kcs = kc ^ ((r >> 2) & 3);
        *(float4*)&sA[r * K + kcs * 4] = v;
    }
    __syncthreads();

    const int tc = tid & 15, tr = tid >> 4, sw = tr & 3;
    float4 acc[4];
#pragma unroll
    for (int rr = 0; rr < 4; ++rr) acc[rr] = make_float4(0.f, 0.f, 0.f, 0.f);
#pragma unroll 4
    for (int kc = 0; kc < KV; ++kc) {
        int ks = (kc ^ sw) * 4;
        float4 a[4], w[4];
#pragma unroll
        for (int rr = 0; rr < 4; ++rr) a[rr] = *(const float4*)&sA[(tr * 4 + rr) * K + ks];
#pragma unroll
        for (int kk = 0; kk < 4; ++kk) w[kk] = *(const float4*)&sW[(kc * 4 + kk) * 64 + tc * 4];
#pragma unroll
        for (int kk = 0; kk < 4; ++kk)
#pragma unroll
            for (int rr = 0; rr < 4; ++rr) {
                float av = (&a[rr].x)[kk];
                acc[rr].x = fmaf(av, w[kk].x, acc[rr].x);
                acc[rr].y = fmaf(av, w[kk].y, acc[rr].y);
                acc[rr].z = fmaf(av, w[kk].z, acc[rr].z);
                acc[rr].w = fmaf(av, w[kk].w, acc[rr].w);
            }
    }
    // h2 = relu(acc + bl) -> sA (K=64 swizzled layout); stage lin2_w -> sW
    float4 bl4 = *(const float4*)&bl[tc * 4];
    __syncthreads();
#pragma unroll
    for (int rr = 0; rr < 4; ++rr) {
        int r = tr * 4 + rr;
        float4 v = acc[rr];
        v.x = fmaxf(v.x + bl4.x, 0.f); v.y = fmaxf(v.y + bl4.y, 0.f);
        v.z = fmaxf(v.z + bl4.z, 0.f); v.w = fmaxf(v.w + bl4.w, 0.f);
        int kcs = tc ^ ((r >> 2) & 3);
        *(float4*)&sA[r * 64 + kcs * 4] = v;
    }
    for (int i = tid; i < 64 * 16; i += 256) ((float4*)sW)[i] = ((const float4*)W2)[i];
    __syncthreads();

    float4 acc2[4];
#pragma unroll
    for (int rr = 0; rr < 4; ++rr) acc2[rr] = make_float4(0.f, 0.f, 0.f, 0.f);
#pragma unroll 4
    for (int kc = 0; kc < 16; ++kc) {
        int ks = (kc ^ sw) * 4;
        float4 a[4], w[4];
#pragma unroll
        for (int rr = 0; rr < 4; ++rr) a[rr] = *(const float4*)&sA[(tr * 4 + rr) * 64 + ks];
#pragma unroll
        for (int kk = 0; kk < 4; ++kk) w[kk] = *(const float4*)&sW[(kc * 4 + kk) * 64 + tc * 4];
#pragma unroll
        for (int kk = 0; kk < 4; ++kk)
#pragma unroll
            for (int rr = 0; rr < 4; ++rr) {
                float av = (&a[rr].x)[kk];
                acc2[rr].x = fmaf(av, w[kk].x, acc2[rr].x);
                acc2[rr].y = fmaf(av, w[kk].y, acc2[rr].y);
                acc2[rr].z = fmaf(av, w[kk].z, acc2[rr].z);
                acc2[rr].w = fmaf(av, w[kk].w, acc2[rr].w);
            }
    }
    float4 b24 = *(const float4*)&b2[tc * 4];
#pragma unroll
    for (int rr = 0; rr < 4; ++rr) {
        int r = row0 + tr * 4 + rr;
        if (r < n) {
            float4 v = acc2[rr];
            v.x = fmaxf(v.x + b24.x, 0.f); v.y = fmaxf(v.y + b24.y, 0.f);
            v.z = fmaxf(v.z + b24.z, 0.f); v.w = fmaxf(v.w + b24.w, 0.f);
            ushort4 ub = { f2bf(v.x), f2bf(v.y), f2bf(v.z), f2bf(v.w) };
            *(ushort4*)&out_bf[(size_t)r * 64 + tc * 4] = ub;
        }
    }
}

// ---- k_mm456: h4 = relu([agg2|h3bf]@[wl;wr]+bl); P=h4@W1a+b1; Q=h4@W1b ----
__global__ __launch_bounds__(256) void k_mm456(
    const float* __restrict__ A0, const unsigned short* __restrict__ A1bf,
    const float* __restrict__ W0, const float* __restrict__ W1,
    const float* __restrict__ bl, const float* __restrict__ W1g,
    const float* __restrict__ b1, unsigned short* __restrict__ Pbf,
    unsigned short* __restrict__ Qbf, int n) {
    constexpr int K = 128, KV = 32;
    __shared__ float sA[64 * K];
    __shared__ float sW[K * 64];
    const int tid = threadIdx.x;
    const int row0 = blockIdx.x * 64;

    for (int i = tid; i < 64 * 16; i += 256) ((float4*)sW)[i] = ((const float4*)W0)[i];
    for (int i = tid; i < 64 * 16; i += 256) ((float4*)sW)[64 * 16 + i] = ((const float4*)W1)[i];
    for (int idx = tid; idx < 64 * KV; idx += 256) {
        int r = idx / KV, kc = idx % KV;
        int grow = row0 + r;
        float4 v = make_float4(0.f, 0.f, 0.f, 0.f);
        if (grow < n) {
            if (kc < 16) {
                v = *(const float4*)&A0[(size_t)grow * 64 + kc * 4];
            } else {
                ushort4 u = *(const ushort4*)&A1bf[(size_t)grow * 64 + (kc - 16) * 4];
                v = make_float4(bf2f(u.x), bf2f(u.y), bf2f(u.z), bf2f(u.w));
            }
        }
        int kcs = kc ^ ((r >> 2) & 3);
        *(float4*)&sA[r * K + kcs * 4] = v;
    }
    __syncthreads();

    const int tc = tid & 15, tr = tid >> 4, sw = tr & 3;
    float4 acc[4];
#pragma unroll
    for (int rr = 0; rr < 4; ++rr) acc[rr] = make_float4(0.f, 0.f, 0.f, 0.f);
#pragma unroll 4
    for (int kc = 0; kc < KV; ++kc) {
        int ks = (kc ^ sw) * 4;
        float4 a[4], w[4];
#pragma unroll
        for (int rr = 0; rr < 4; ++rr) a[rr] = *(const float4*)&sA[(tr * 4 + rr) * K + ks];
#pragma unroll
        for (int kk = 0; kk < 4; ++kk) w[kk] = *(const float4*)&sW[(kc * 4 + kk) * 64 + tc * 4];
#pragma unroll
        for (int kk = 0; kk < 4; ++kk)
#pragma unroll
            for (int rr = 0; rr < 4; ++rr) {
                float av = (&a[rr].x)[kk];
                acc[rr].x = fmaf(av, w[kk].x, acc[rr].x);
                acc[rr].y = fmaf(av, w[kk].y, acc[rr].y);
                acc[rr].z = fmaf(av, w[kk].z, acc[rr].z);
                acc[rr].w = fmaf(av, w[kk].w, acc[rr].w);
            }
    }
    // h4 = relu(acc + bl) -> sA (K=64 swizzled); stage mlp_w1 (128x64) -> sW
    float4 bl4 = *(const float4*)&bl[tc * 4];
    __syncthreads();
#pragma unroll
    for (int rr = 0; rr < 4; ++rr) {
        int r = tr * 4 + rr;
        float4 v = acc[rr];
        v.x = fmaxf(v.x + bl4.x, 0.f); v.y = fmaxf(v.y + bl4.y, 0.f);
        v.z = fmaxf(v.z + bl4.z, 0.f); v.w = fmaxf(v.w + bl4.w, 0.f);
        int kcs = tc ^ ((r >> 2) & 3);
        *(float4*)&sA[r * 64 + kcs * 4] = v;
    }
    for (int i = tid; i < 128 * 16; i += 256) ((float4*)sW)[i] = ((const float4*)W1g)[i];
    __syncthreads();

    float4 accP[4], accQ[4];
#pragma unroll
    for (int rr = 0; rr < 4; ++rr) {
        accP[rr] = make_float4(0.f, 0.f, 0.f, 0.f);
        accQ[rr] = make_float4(0.f, 0.f, 0.f, 0.f);
    }
#pragma unroll 2
    for (int kc = 0; kc < 16; ++kc) {
        int ks = (kc ^ sw) * 4;
        float4 a[4], wp[4], wq[4];
#pragma unroll
        for (int rr = 0; rr < 4; ++rr) a[rr] = *(const float4*)&sA[(tr * 4 + rr) * 64 + ks];
#pragma unroll
        for (int kk = 0; kk < 4; ++kk) {
            wp[kk] = *(const float4*)&sW[(kc * 4 + kk) * 64 + tc * 4];
            wq[kk] = *(const float4*)&sW[(64 + kc * 4 + kk) * 64 + tc * 4];
        }
#pragma unroll
        for (int kk = 0; kk < 4; ++kk)
#pragma unroll
            for (int rr = 0; rr < 4; ++rr) {
                float av = (&a[rr].x)[kk];
                accP[rr].x = fmaf(av, wp[kk].x, accP[rr].x);
                accP[rr].y = fmaf(av, wp[kk].y, accP[rr].y);
                accP[rr].z = fmaf(av, wp[kk].z, accP[rr].z);
                accP[rr].w = fmaf(av, wp[kk].w, accP[rr].w);
                accQ[rr].x = fmaf(av, wq[kk].x, accQ[rr].x);
                accQ[rr].y = fmaf(av, wq[kk].y, accQ[rr].y);
                accQ[rr].z = fmaf(av, wq[kk].z, accQ[rr].z);
                accQ[rr].w = fmaf(av, wq[kk].w, accQ[rr].w);
            }
    }
    float4 b14 = *(const float4*)&b1[tc * 4];
#pragma unroll
    for (int rr = 0; rr < 4; ++rr) {
        int r = row0 + tr * 4 + rr;
        if (r < n) {
            float4 p = accP[rr];
            p.x += b14.x; p.y += b14.y; p.z += b14.z; p.w += b14.w;
            ushort4 up = { f2bf(p.x), f2bf(p.y), f2bf(p.z), f2bf(p.w) };
            *(ushort4*)&Pbf[(size_t)r * 64 + tc * 4] = up;
            float4 q = accQ[rr];
            ushort4 uq = { f2bf(q.x), f2bf(q.y), f2bf(q.z), f2bf(q.w) };
            *(ushort4*)&Qbf[(size_t)r * 64 + tc * 4] = uq;
        }
    }
}

// ---- edge scorer: out[e] = tanh( relu(P[s]+Q[d]) . w2 + b2 ), bf16 P/Q ----
__global__ __launch_bounds__(256) void k_score_bf(
    const unsigned short* __restrict__ P, const unsigned short* __restrict__ Q,
    const int* __restrict__ msrc, const int* __restrict__ mdst,
    const float* __restrict__ w2, const float* __restrict__ b2,
    float* __restrict__ out, int M) {
    int gid = blockIdx.x * 256 + threadIdx.x;
    int e = gid >> 4;
    if (e >= M) return;
    int l = gid & 15;
    int s = msrc[e], d = mdst[e];
    ushort4 up = *(const ushort4*)(P + (((unsigned)s << 6) + ((unsigned)l << 2)));
    ushort4 uq = *(const ushort4*)(Q + (((unsigned)d << 6) + ((unsigned)l << 2)));
    float4 w = *(const float4*)&w2[l * 4];
    float ux = fmaxf(bf2f(up.x) + bf2f(uq.x), 0.f);
    float uy = fmaxf(bf2f(up.y) + bf2f(uq.y), 0.f);
    float uz = fmaxf(bf2f(up.z) + bf2f(uq.z), 0.f);
    float uw = fmaxf(bf2f(up.w) + bf2f(uq.w), 0.f);
    float partial = ux * w.x + uy * w.y + uz * w.z + uw * w.w;
#pragma unroll
    for (int m = 1; m < 16; m <<= 1) partial += __shfl_xor(partial, m, 16);
    if (l == 0) out[e] = tanhf(partial + b2[0]);
}

extern "C" void kernel_launch(void* const* d_in, const int* in_sizes, int n_in,
                              void* d_out, int out_size, void* d_ws, size_t ws_size,
                              hipStream_t stream) {
    const float* x      = (const float*)d_in[0];
    const int*   ei     = (const int*)d_in[1];
    const int*   mei    = (const int*)d_in[2];
    const float* lin1_w = (const float*)d_in[3];
    const float* lin1_b = (const float*)d_in[4];
    const float* lin2_w = (const float*)d_in[5];
    const float* lin2_b = (const float*)d_in[6];
    const float* c1_wl  = (const float*)d_in[7];
    const float* c1_bl  = (const float*)d_in[8];
    const float* c1_wr  = (const float*)d_in[9];
    const float* c2_wl  = (const float*)d_in[10];
    const float* c2_bl  = (const float*)d_in[11];
    const float* c2_wr  = (const float*)d_in[12];
    const float* mlp_w1 = (const float*)d_in[13];
    const float* mlp_b1 = (const float*)d_in[14];
    const float* mlp_w2 = (const float*)d_in[15];
    const float* mlp_b2 = (const float*)d_in[16];

    const int N = in_sizes[0] / 128;
    const int E = in_sizes[1] / 2;
    const int M = in_sizes[2] / 2;
    const int* src  = ei;
    const int* dstE = ei + E;
    const int* msrc = mei;
    const int* mdst = mei + M;

    int shift = 8;
    while ((((N - 1) >> shift) + 1) > MAXB) ++shift;
    const int nbuckets = ((N - 1) >> shift) + 1;

    const size_t N64 = (size_t)N * 64;
    float* bufA    = (float*)d_ws;              // N*64 f32 (unused by compute; bb could alias)
    float* bufB    = bufA + N64;                // N*64 f32: bb (pre-gather) then agg
    float* bufC    = bufB + N64;                // N*64 f32: Qbf aliases
    unsigned short* Hbf = (unsigned short*)(bufC + N64);   // N*64 bf16: h1bf/h3bf/Pbf
    float* inv_deg = (float*)(Hbf + N64);       // N
    int*   row_ptr = (int*)(inv_deg + N);       // N+1
    int*   bcnt    = row_ptr + (N + 1);         // MAXB
    int*   boff    = bcnt + MAXB;               // MAXB
    int*   bcur    = boff + MAXB;               // MAXB
    int*   csr     = bcur + MAXB;               // E
    unsigned* bb   = (unsigned*)bufB;           // E (dead before first gather)
    unsigned short* Pbf = Hbf;                  // h3bf dead after gather2 staging
    unsigned short* Qbf = (unsigned short*)bufC;
    float* outf = (float*)d_out;

    const int nbN = (N + 63) / 64;
    const int nbM = (int)(((long long)M * 16 + 255) / 256);
    const int nbG = (int)(((long long)N * 64 + 255) / 256);
    const int nbP = (E + PART_CH - 1) / PART_CH;

    // ---- CSR build ----
    hipMemsetAsync(bcnt, 0, MAXB * sizeof(int), stream);
    k_bcount<<<512, 256, 0, stream>>>(dstE, bcnt, E, shift);
    k_bscan<<<1, MAXB, 0, stream>>>(bcnt, boff, bcur, nbuckets);
    k_part<<<nbP, PART_BS, 0, stream>>>(src, dstE, bcur, bb, E, shift);
    k_bfill<<<nbuckets, 512, 0, stream>>>(bb, boff, bcnt, row_ptr,
                                          inv_deg, csr, N, E, shift);

    // h1bf = relu(x @ lin1_w + b)
    k_mm1<<<nbN, 256, 0, stream>>>(x, lin1_w, lin1_b, Hbf, N);

    // sage1 + lin2 fused: agg -> bufB; h3bf = relu(relu([agg|h1bf]@[wl;wr]+bl)@w2+b2)
    k_gather_bf<<<nbG, 256, 0, stream>>>(Hbf, csr, row_ptr, inv_deg, bufB, N);
    k_mm23<<<nbN, 256, 0, stream>>>(bufB, Hbf, c1_wl, c1_wr, c1_bl,
                                    lin2_w, lin2_b, Hbf, N);

    // sage2 + P/Q fused
    k_gather_bf<<<nbG, 256, 0, stream>>>(Hbf, csr, row_ptr, inv_deg, bufB, N);
    k_mm456<<<nbN, 256, 0, stream>>>(bufB, Hbf, c2_wl, c2_wr, c2_bl,
                                     mlp_w1, mlp_b1, Pbf, Qbf, N);

    // edge scoring
    k_score_bf<<<nbM, 256, 0, stream>>>(Pbf, Qbf, msrc, mdst, mlp_w2, mlp_b2,
                                        outf, M);
}

// Round 8
// 435.794 us; speedup vs baseline: 2.6611x; 1.2605x over previous
//
#include <hip/hip_runtime.h>
#include <math.h>

#define MAXB 512
#define PART_CH 8192
#define PART_BS 1024

typedef _Float16 f16;
typedef __attribute__((ext_vector_type(8))) _Float16 f16x8;
typedef __attribute__((ext_vector_type(4))) float f32x4;

static __device__ __forceinline__ float h2f(unsigned short s) {
    f16 h; *(unsigned short*)&h = s; return (float)h;
}
static __device__ __forceinline__ unsigned short f2h(float f) {
    f16 h = (f16)f; return *(unsigned short*)&h;
}

// ========== CSR build (unchanged from round 6) ==========
__global__ __launch_bounds__(256) void k_bcount(const int* __restrict__ dst,
                                                int* __restrict__ bucket_cnt,
                                                int E, int shift) {
    __shared__ int h[MAXB];
    for (int i = threadIdx.x; i < MAXB; i += 256) h[i] = 0;
    __syncthreads();
    int stride = gridDim.x * 256;
    for (int i = blockIdx.x * 256 + threadIdx.x; i < E; i += stride)
        atomicAdd(&h[dst[i] >> shift], 1);
    __syncthreads();
    for (int i = threadIdx.x; i < MAXB; i += 256)
        if (h[i]) atomicAdd(&bucket_cnt[i], h[i]);
}

__global__ __launch_bounds__(MAXB) void k_bscan(const int* __restrict__ bucket_cnt,
                                                int* __restrict__ bucket_off,
                                                int* __restrict__ bucket_cur,
                                                int nbuckets) {
    __shared__ int s[MAXB];
    int t = threadIdx.x;
    int v = (t < nbuckets) ? bucket_cnt[t] : 0;
    s[t] = v;
    __syncthreads();
    for (int off = 1; off < MAXB; off <<= 1) {
        int u = (t >= off) ? s[t - off] : 0;
        __syncthreads();
        s[t] += u;
        __syncthreads();
    }
    int excl = s[t] - v;
    if (t < nbuckets) { bucket_off[t] = excl; bucket_cur[t] = excl; }
}

__global__ __launch_bounds__(PART_BS) void k_part(const int* __restrict__ src,
                                                  const int* __restrict__ dst,
                                                  int* __restrict__ bucket_cur,
                                                  unsigned* __restrict__ bb,
                                                  int E, int shift) {
    __shared__ int h[MAXB], base[MAXB];
    int b0 = blockIdx.x * PART_CH;
    int e1 = min(b0 + PART_CH, E);
    for (int i = threadIdx.x; i < MAXB; i += PART_BS) h[i] = 0;
    __syncthreads();
    for (int i = b0 + threadIdx.x; i < e1; i += PART_BS)
        atomicAdd(&h[dst[i] >> shift], 1);
    __syncthreads();
    for (int i = threadIdx.x; i < MAXB; i += PART_BS) {
        base[i] = h[i] ? atomicAdd(&bucket_cur[i], h[i]) : 0;
        h[i] = 0;
    }
    __syncthreads();
    unsigned mask = (1u << shift) - 1u;
    for (int i = b0 + threadIdx.x; i < e1; i += PART_BS) {
        int d = dst[i];
        int b = d >> shift;
        int r = atomicAdd(&h[b], 1);
        bb[base[b] + r] = ((unsigned)src[i] << shift) | ((unsigned)d & mask);
    }
}

__global__ __launch_bounds__(512) void k_bfill(const unsigned* __restrict__ bb,
                                               const int* __restrict__ bucket_off,
                                               const int* __restrict__ bucket_cnt,
                                               int* __restrict__ row_ptr,
                                               float* __restrict__ inv_deg,
                                               int* __restrict__ csr,
                                               int N, int E, int shift) {
    __shared__ int deg[512], cur[512], s[512];
    int b = blockIdx.x;
    int t = threadIdx.x;
    int lo = b << shift;
    int hi = min(N, (b + 1) << shift);
    int nn = hi - lo;
    int off = bucket_off[b];
    int cnt = bucket_cnt[b];
    unsigned mask = (1u << shift) - 1u;

    deg[t] = 0;
    __syncthreads();
    for (int i = off + t; i < off + cnt; i += 512)
        atomicAdd(&deg[bb[i] & mask], 1);
    __syncthreads();
    int d = deg[t];
    s[t] = d;
    __syncthreads();
    for (int o = 1; o < 512; o <<= 1) {
        int u = (t >= o) ? s[t - o] : 0;
        __syncthreads();
        s[t] += u;
        __syncthreads();
    }
    int excl = s[t] - d;
    cur[t] = excl;
    if (t < nn) {
        row_ptr[lo + t] = off + excl;
        inv_deg[lo + t] = d > 0 ? 1.0f / (float)d : 0.0f;
    }
    if (t == 0 && hi == N) row_ptr[N] = E;
    __syncthreads();
    for (int i = off + t; i < off + cnt; i += 512) {
        unsigned w = bb[i];
        int dl = (int)(w & mask);
        int pos = atomicAdd(&cur[dl], 1);
        csr[off + pos] = (int)(w >> shift);
    }
}

// ========== weight prep: transpose+convert all weights to fp16 W^T[n][k] ====
// half offsets: Wt1 0 (64x128), Wc1 8192 (64x128), Wl2 16384 (64x64),
//               Wc2 20480 (64x128), Wp 28672 (64x64), Wq 32768 (64x64)
__global__ __launch_bounds__(256) void k_prep(
    const float* __restrict__ lin1_w, const float* __restrict__ c1_wl,
    const float* __restrict__ c1_wr, const float* __restrict__ lin2_w,
    const float* __restrict__ c2_wl, const float* __restrict__ c2_wr,
    const float* __restrict__ mlp_w1, unsigned short* __restrict__ Wt) {
    int i = blockIdx.x * 256 + threadIdx.x;
    for (; i < 36864; i += gridDim.x * 256) {
        float v;
        if (i < 8192)       { int j = i;         int n = j >> 7, k = j & 127; v = lin1_w[k * 64 + n]; }
        else if (i < 16384) { int j = i - 8192;  int n = j >> 7, k = j & 127;
                              v = (k < 64) ? c1_wl[k * 64 + n] : c1_wr[(k - 64) * 64 + n]; }
        else if (i < 20480) { int j = i - 16384; int n = j >> 6, k = j & 63;  v = lin2_w[k * 64 + n]; }
        else if (i < 28672) { int j = i - 20480; int n = j >> 7, k = j & 127;
                              v = (k < 64) ? c2_wl[k * 64 + n] : c2_wr[(k - 64) * 64 + n]; }
        else if (i < 32768) { int j = i - 28672; int n = j >> 6, k = j & 63;  v = mlp_w1[k * 64 + n]; }
        else                { int j = i - 32768; int n = j >> 6, k = j & 63;  v = mlp_w1[(k + 64) * 64 + n]; }
        Wt[i] = f2h(v);
    }
}

// ====== mean aggregation, fp16 rows, 32 rows in flight per wave ======
__global__ __launch_bounds__(256) void k_gather_h(
    const unsigned short* __restrict__ hh, const int* __restrict__ csr,
    const int* __restrict__ row_ptr, const float* __restrict__ inv_deg,
    unsigned short* __restrict__ out, int n) {
    int wave = (blockIdx.x * 256 + (int)threadIdx.x) >> 6;
    if (wave >= n) return;
    int lane = threadIdx.x & 63;
    int g = lane >> 4, sub = lane & 15;
    int start = row_ptr[wave], end = row_ptr[wave + 1];
    float4 acc = make_float4(0.f, 0.f, 0.f, 0.f);
    for (int base = start; base < end; base += 32) {
        int last = end - 1;
        int jj[8], idx[8];
#pragma unroll
        for (int t = 0; t < 8; ++t) {
            jj[t] = base + g + 4 * t;
            idx[t] = csr[min(jj[t], last)];
        }
        ushort4 u[8];
#pragma unroll
        for (int t = 0; t < 8; ++t)
            u[t] = *(const ushort4*)(hh + (((unsigned)idx[t] << 6) + ((unsigned)sub << 2)));
#pragma unroll
        for (int t = 0; t < 8; ++t) {
            float m = (jj[t] < end) ? 1.f : 0.f;
            acc.x = fmaf(m, h2f(u[t].x), acc.x);
            acc.y = fmaf(m, h2f(u[t].y), acc.y);
            acc.z = fmaf(m, h2f(u[t].z), acc.z);
            acc.w = fmaf(m, h2f(u[t].w), acc.w);
        }
    }
    acc.x += __shfl_xor(acc.x, 16, 64);
    acc.y += __shfl_xor(acc.y, 16, 64);
    acc.z += __shfl_xor(acc.z, 16, 64);
    acc.w += __shfl_xor(acc.w, 16, 64);
    acc.x += __shfl_xor(acc.x, 32, 64);
    acc.y += __shfl_xor(acc.y, 32, 64);
    acc.z += __shfl_xor(acc.z, 32, 64);
    acc.w += __shfl_xor(acc.w, 32, 64);
    if (g == 0) {
        float idv = inv_deg[wave];
        ushort4 o;
        o.x = f2h(acc.x * idv); o.y = f2h(acc.y * idv);
        o.z = f2h(acc.z * idv); o.w = f2h(acc.w * idv);
        *(ushort4*)&out[((unsigned)wave << 6) + ((unsigned)sub << 2)] = o;
    }
}

// ---- k_mm1 (MFMA): Hh = relu(x_f32 @ lin1_w + b), K=128 ----
// 64 rows/block, 4 waves; A frags direct from global; W^T fp16 in padded LDS.
__global__ __launch_bounds__(256) void k_mm1(
    const float* __restrict__ x, const unsigned short* __restrict__ Wtg,
    const float* __restrict__ bias, unsigned short* __restrict__ outh, int n) {
    __shared__ alignas(16) unsigned short sW[64 * 136];  // [64][17 chunks x 8]
    const int tid = threadIdx.x;
    const int row0 = blockIdx.x * 64;
    for (int i = tid; i < 64 * 16; i += 256) {
        int nn = i >> 4, c = i & 15;
        *(uint4*)&sW[(nn * 17 + c) * 8] = *(const uint4*)&Wtg[i * 8];
    }
    __syncthreads();
    const int lane = tid & 63, w = tid >> 6;
    const int m = lane & 15, q = lane >> 4;
    const int gr = min(row0 + 16 * w + m, n - 1);
    const float* ar = x + (size_t)gr * 128;
    f32x4 acc[4];
#pragma unroll
    for (int c = 0; c < 4; ++c) acc[c] = (f32x4){0.f, 0.f, 0.f, 0.f};
#pragma unroll
    for (int kk = 0; kk < 4; ++kk) {
        float4 a0 = *(const float4*)(ar + kk * 32 + q * 8);
        float4 a1 = *(const float4*)(ar + kk * 32 + q * 8 + 4);
        f16x8 af;
        af[0] = (f16)a0.x; af[1] = (f16)a0.y; af[2] = (f16)a0.z; af[3] = (f16)a0.w;
        af[4] = (f16)a1.x; af[5] = (f16)a1.y; af[6] = (f16)a1.z; af[7] = (f16)a1.w;
#pragma unroll
        for (int c = 0; c < 4; ++c) {
            f16x8 bf = *(const f16x8*)&sW[((16 * c + m) * 17 + (kk * 4 + q)) * 8];
            acc[c] = __builtin_amdgcn_mfma_f32_16x16x32_f16(af, bf, acc[c], 0, 0, 0);
        }
    }
#pragma unroll
    for (int c = 0; c < 4; ++c) {
        int col = 16 * c + m;
        float bv = bias[col];
#pragma unroll
        for (int i = 0; i < 4; ++i) {
            int r = row0 + 16 * w + q * 4 + i;
            if (r < n) outh[(size_t)r * 64 + col] = f2h(fmaxf(acc[c][i] + bv, 0.f));
        }
    }
}

// ---- k_mm23 (MFMA, 2-stage): h3 = relu(relu([agg|h1]@Wc+bl) @ lin2 + b2) ----
__global__ __launch_bounds__(256) void k_mm23(
    const unsigned short* __restrict__ aggH, const unsigned short* __restrict__ h1,
    const unsigned short* __restrict__ Wcg, const float* __restrict__ bl,
    const unsigned short* __restrict__ Wl2g, const float* __restrict__ b2,
    unsigned short* __restrict__ outh, int n) {
    __shared__ alignas(16) unsigned short sm[64 * 72 + 64 * 136];
    unsigned short* hA = sm;            // [64][72]
    unsigned short* sW = sm + 64 * 72;  // phase1 [64][136]; phase2 [64][72]
    const int tid = threadIdx.x;
    const int row0 = blockIdx.x * 64;
    for (int i = tid; i < 64 * 16; i += 256) {
        int nn = i >> 4, c = i & 15;
        *(uint4*)&sW[(nn * 17 + c) * 8] = *(const uint4*)&Wcg[i * 8];
    }
    __syncthreads();
    const int lane = tid & 63, w = tid >> 6;
    const int m = lane & 15, q = lane >> 4;
    const int gr = min(row0 + 16 * w + m, n - 1);
    f32x4 acc[4];
#pragma unroll
    for (int c = 0; c < 4; ++c) acc[c] = (f32x4){0.f, 0.f, 0.f, 0.f};
#pragma unroll
    for (int kk = 0; kk < 4; ++kk) {
        const unsigned short* ap = (kk < 2)
            ? (aggH + (size_t)gr * 64 + kk * 32 + q * 8)
            : (h1 + (size_t)gr * 64 + (kk - 2) * 32 + q * 8);
        f16x8 af = *(const f16x8*)ap;
#pragma unroll
        for (int c = 0; c < 4; ++c) {
            f16x8 bf = *(const f16x8*)&sW[((16 * c + m) * 17 + (kk * 4 + q)) * 8];
            acc[c] = __builtin_amdgcn_mfma_f32_16x16x32_f16(af, bf, acc[c], 0, 0, 0);
        }
    }
    // h2 = relu(acc + bl) -> hA (padded [64][72], plain col index)
#pragma unroll
    for (int c = 0; c < 4; ++c) {
        int col = 16 * c + m;
        float bv = bl[col];
#pragma unroll
        for (int i = 0; i < 4; ++i)
            hA[(16 * w + q * 4 + i) * 72 + col] = f2h(fmaxf(acc[c][i] + bv, 0.f));
    }
    __syncthreads();
    for (int i = tid; i < 64 * 8; i += 256) {
        int nn = i >> 3, c = i & 7;
        *(uint4*)&sW[(nn * 9 + c) * 8] = *(const uint4*)&Wl2g[i * 8];
    }
    __syncthreads();
    f32x4 acc2[4];
#pragma unroll
    for (int c = 0; c < 4; ++c) acc2[c] = (f32x4){0.f, 0.f, 0.f, 0.f};
#pragma unroll
    for (int kk = 0; kk < 2; ++kk) {
        f16x8 af = *(const f16x8*)&hA[(16 * w + m) * 72 + kk * 32 + q * 8];
#pragma unroll
        for (int c = 0; c < 4; ++c) {
            f16x8 bf = *(const f16x8*)&sW[((16 * c + m) * 9 + (kk * 4 + q)) * 8];
            acc2[c] = __builtin_amdgcn_mfma_f32_16x16x32_f16(af, bf, acc2[c], 0, 0, 0);
        }
    }
#pragma unroll
    for (int c = 0; c < 4; ++c) {
        int col = 16 * c + m;
        float bv = b2[col];
#pragma unroll
        for (int i = 0; i < 4; ++i) {
            int r = row0 + 16 * w + q * 4 + i;
            if (r < n) outh[(size_t)r * 64 + col] = f2h(fmaxf(acc2[c][i] + bv, 0.f));
        }
    }
}

// ---- k_mm456 (MFMA, 2-stage): h4=relu([agg2|h3]@Wc2+bl); P=h4@Wp+b1; Q=h4@Wq
__global__ __launch_bounds__(256) void k_mm456(
    const unsigned short* __restrict__ aggH, const unsigned short* __restrict__ h3,
    const unsigned short* __restrict__ Wcg, const float* __restrict__ bl,
    const unsigned short* __restrict__ Wpg, const unsigned short* __restrict__ Wqg,
    const float* __restrict__ b1, unsigned short* __restrict__ Ph,
    unsigned short* __restrict__ Qh, int n) {
    __shared__ alignas(16) unsigned short sm[64 * 72 + 2 * 64 * 72];
    unsigned short* hA = sm;            // [64][72]
    unsigned short* sW = sm + 64 * 72;  // phase1 [64][136] (8704<=9216); phase2 Wp|Wq
    const int tid = threadIdx.x;
    const int row0 = blockIdx.x * 64;
    for (int i = tid; i < 64 * 16; i += 256) {
        int nn = i >> 4, c = i & 15;
        *(uint4*)&sW[(nn * 17 + c) * 8] = *(const uint4*)&Wcg[i * 8];
    }
    __syncthreads();
    const int lane = tid & 63, w = tid >> 6;
    const int m = lane & 15, q = lane >> 4;
    const int gr = min(row0 + 16 * w + m, n - 1);
    f32x4 acc[4];
#pragma unroll
    for (int c = 0; c < 4; ++c) acc[c] = (f32x4){0.f, 0.f, 0.f, 0.f};
#pragma unroll
    for (int kk = 0; kk < 4; ++kk) {
        const unsigned short* ap = (kk < 2)
            ? (aggH + (size_t)gr * 64 + kk * 32 + q * 8)
            : (h3 + (size_t)gr * 64 + (kk - 2) * 32 + q * 8);
        f16x8 af = *(const f16x8*)ap;
#pragma unroll
        for (int c = 0; c < 4; ++c) {
            f16x8 bf = *(const f16x8*)&sW[((16 * c + m) * 17 + (kk * 4 + q)) * 8];
            acc[c] = __builtin_amdgcn_mfma_f32_16x16x32_f16(af, bf, acc[c], 0, 0, 0);
        }
    }
#pragma unroll
    for (int c = 0; c < 4; ++c) {
        int col = 16 * c + m;
        float bv = bl[col];
#pragma unroll
        for (int i = 0; i < 4; ++i)
            hA[(16 * w + q * 4 + i) * 72 + col] = f2h(fmaxf(acc[c][i] + bv, 0.f));
    }
    __syncthreads();
    for (int i = tid; i < 64 * 8; i += 256) {
        int nn = i >> 3, c = i & 7;
        *(uint4*)&sW[(nn * 9 + c) * 8] = *(const uint4*)&Wpg[i * 8];
        *(uint4*)&sW[4608 + (nn * 9 + c) * 8] = *(const uint4*)&Wqg[i * 8];
    }
    __syncthreads();
    f32x4 accP[4], accQ[4];
#pragma unroll
    for (int c = 0; c < 4; ++c) {
        accP[c] = (f32x4){0.f, 0.f, 0.f, 0.f};
        accQ[c] = (f32x4){0.f, 0.f, 0.f, 0.f};
    }
#pragma unroll
    for (int kk = 0; kk < 2; ++kk) {
        f16x8 af = *(const f16x8*)&hA[(16 * w + m) * 72 + kk * 32 + q * 8];
#pragma unroll
        for (int c = 0; c < 4; ++c) {
            f16x8 bp = *(const f16x8*)&sW[((16 * c + m) * 9 + (kk * 4 + q)) * 8];
            f16x8 bq = *(const f16x8*)&sW[4608 + ((16 * c + m) * 9 + (kk * 4 + q)) * 8];
            accP[c] = __builtin_amdgcn_mfma_f32_16x16x32_f16(af, bp, accP[c], 0, 0, 0);
            accQ[c] = __builtin_amdgcn_mfma_f32_16x16x32_f16(af, bq, accQ[c], 0, 0, 0);
        }
    }
#pragma unroll
    for (int c = 0; c < 4; ++c) {
        int col = 16 * c + m;
        float bv = b1[col];
#pragma unroll
        for (int i = 0; i < 4; ++i) {
            int r = row0 + 16 * w + q * 4 + i;
            if (r < n) {
                Ph[(size_t)r * 64 + col] = f2h(accP[c][i] + bv);
                Qh[(size_t)r * 64 + col] = f2h(accQ[c][i]);
            }
        }
    }
}

// ---- edge scorer: out[e] = tanh( relu(P[s]+Q[d]) . w2 + b2 ), fp16 P/Q ----
__global__ __launch_bounds__(256) void k_score_h(
    const unsigned short* __restrict__ P, const unsigned short* __restrict__ Q,
    const int* __restrict__ msrc, const int* __restrict__ mdst,
    const float* __restrict__ w2, const float* __restrict__ b2,
    float* __restrict__ out, int M) {
    int gid = blockIdx.x * 256 + threadIdx.x;
    int e = gid >> 4;
    if (e >= M) return;
    int l = gid & 15;
    int s = msrc[e], d = mdst[e];
    ushort4 up = *(const ushort4*)(P + (((unsigned)s << 6) + ((unsigned)l << 2)));
    ushort4 uq = *(const ushort4*)(Q + (((unsigned)d << 6) + ((unsigned)l << 2)));
    float4 w = *(const float4*)&w2[l * 4];
    float ux = fmaxf(h2f(up.x) + h2f(uq.x), 0.f);
    float uy = fmaxf(h2f(up.y) + h2f(uq.y), 0.f);
    float uz = fmaxf(h2f(up.z) + h2f(uq.z), 0.f);
    float uw = fmaxf(h2f(up.w) + h2f(uq.w), 0.f);
    float partial = ux * w.x + uy * w.y + uz * w.z + uw * w.w;
#pragma unroll
    for (int mm = 1; mm < 16; mm <<= 1) partial += __shfl_xor(partial, mm, 16);
    if (l == 0) out[e] = tanhf(partial + b2[0]);
}

extern "C" void kernel_launch(void* const* d_in, const int* in_sizes, int n_in,
                              void* d_out, int out_size, void* d_ws, size_t ws_size,
                              hipStream_t stream) {
    const float* x      = (const float*)d_in[0];
    const int*   ei     = (const int*)d_in[1];
    const int*   mei    = (const int*)d_in[2];
    const float* lin1_w = (const float*)d_in[3];
    const float* lin1_b = (const float*)d_in[4];
    const float* lin2_w = (const float*)d_in[5];
    const float* lin2_b = (const float*)d_in[6];
    const float* c1_wl  = (const float*)d_in[7];
    const float* c1_bl  = (const float*)d_in[8];
    const float* c1_wr  = (const float*)d_in[9];
    const float* c2_wl  = (const float*)d_in[10];
    const float* c2_bl  = (const float*)d_in[11];
    const float* c2_wr  = (const float*)d_in[12];
    const float* mlp_w1 = (const float*)d_in[13];
    const float* mlp_b1 = (const float*)d_in[14];
    const float* mlp_w2 = (const float*)d_in[15];
    const float* mlp_b2 = (const float*)d_in[16];

    const int N = in_sizes[0] / 128;
    const int E = in_sizes[1] / 2;
    const int M = in_sizes[2] / 2;
    const int* src  = ei;
    const int* dstE = ei + E;
    const int* msrc = mei;
    const int* mdst = mei + M;

    int shift = 8;
    while ((((N - 1) >> shift) + 1) > MAXB) ++shift;
    const int nbuckets = ((N - 1) >> shift) + 1;

    const size_t N64 = (size_t)N * 64;
    unsigned short* Hh   = (unsigned short*)d_ws;   // N*64 fp16: h1/h3/P
    unsigned short* aggH = Hh + N64;                // N*64 fp16 (bb aliases pre-gather)
    unsigned short* Qh   = aggH + N64;              // N*64 fp16
    float* inv_deg = (float*)(Qh + N64);            // N
    int*   row_ptr = (int*)(inv_deg + N);           // N+1
    int*   bcnt    = row_ptr + (N + 1);             // MAXB
    int*   boff    = bcnt + MAXB;                   // MAXB
    int*   bcur    = boff + MAXB;                   // MAXB
    unsigned short* Wt = (unsigned short*)(bcur + MAXB);  // 36864 halfs
    int*   csr     = (int*)(Wt + 36864 + 64);       // E
    unsigned* bb   = (unsigned*)aggH;               // E words == N*64 halfs
    float* outf = (float*)d_out;

    const int nbN = (N + 63) / 64;
    const int nbM = (int)(((long long)M * 16 + 255) / 256);
    const int nbG = (int)(((long long)N * 64 + 255) / 256);
    const int nbP = (E + PART_CH - 1) / PART_CH;

    // ---- CSR build + weight prep ----
    hipMemsetAsync(bcnt, 0, MAXB * sizeof(int), stream);
    k_prep<<<64, 256, 0, stream>>>(lin1_w, c1_wl, c1_wr, lin2_w, c2_wl, c2_wr,
                                   mlp_w1, Wt);
    k_bcount<<<512, 256, 0, stream>>>(dstE, bcnt, E, shift);
    k_bscan<<<1, MAXB, 0, stream>>>(bcnt, boff, bcur, nbuckets);
    k_part<<<nbP, PART_BS, 0, stream>>>(src, dstE, bcur, bb, E, shift);
    k_bfill<<<nbuckets, 512, 0, stream>>>(bb, boff, bcnt, row_ptr,
                                          inv_deg, csr, N, E, shift);

    // h1 = relu(x @ lin1_w + b)  (fp16 out)
    k_mm1<<<nbN, 256, 0, stream>>>(x, Wt + 0, lin1_b, Hh, N);

    // sage1 + lin2 fused
    k_gather_h<<<nbG, 256, 0, stream>>>(Hh, csr, row_ptr, inv_deg, aggH, N);
    k_mm23<<<nbN, 256, 0, stream>>>(aggH, Hh, Wt + 8192, c1_bl,
                                    Wt + 16384, lin2_b, Hh, N);

    // sage2 + P/Q fused
    k_gather_h<<<nbG, 256, 0, stream>>>(Hh, csr, row_ptr, inv_deg, aggH, N);
    k_mm456<<<nbN, 256, 0, stream>>>(aggH, Hh, Wt + 20480, c2_bl,
                                     Wt + 28672, Wt + 32768, mlp_b1,
                                     Hh, Qh, N);

    // edge scoring
    k_score_h<<<nbM, 256, 0, stream>>>(Hh, Qh, msrc, mdst, mlp_w2, mlp_b2,
                                       outf, M);
}

// Round 9
// 428.544 us; speedup vs baseline: 2.7061x; 1.0169x over previous
//
#include <hip/hip_runtime.h>
#include <math.h>

#define MAXB 512
#define PART_CH 8192
#define PART_BS 1024

typedef _Float16 f16;
typedef __attribute__((ext_vector_type(2))) _Float16 f16x2;
typedef __attribute__((ext_vector_type(4))) _Float16 f16x4;
typedef __attribute__((ext_vector_type(8))) _Float16 f16x8;
typedef __attribute__((ext_vector_type(4))) float f32x4;

static __device__ __forceinline__ float h2f(unsigned short s) {
    f16 h; *(unsigned short*)&h = s; return (float)h;
}
static __device__ __forceinline__ unsigned short f2h(float f) {
    f16 h = (f16)f; return *(unsigned short*)&h;
}

// ========== single-pass partition into fixed-capacity strided buckets ======
__global__ __launch_bounds__(PART_BS) void k_part(const int* __restrict__ src,
                                                  const int* __restrict__ dst,
                                                  int* __restrict__ bcur,
                                                  unsigned* __restrict__ bb,
                                                  int E, int shift, int CAP) {
    __shared__ int h[MAXB], base[MAXB];
    int b0 = blockIdx.x * PART_CH;
    int e1 = min(b0 + PART_CH, E);
    for (int i = threadIdx.x; i < MAXB; i += PART_BS) h[i] = 0;
    __syncthreads();
    for (int i = b0 + threadIdx.x; i < e1; i += PART_BS)
        atomicAdd(&h[dst[i] >> shift], 1);
    __syncthreads();
    for (int i = threadIdx.x; i < MAXB; i += PART_BS) {
        base[i] = h[i] ? atomicAdd(&bcur[i], h[i]) : 0;
        h[i] = 0;
    }
    __syncthreads();
    unsigned mask = (1u << shift) - 1u;
    for (int i = b0 + threadIdx.x; i < e1; i += PART_BS) {
        int d = dst[i];
        int b = d >> shift;
        int r = atomicAdd(&h[b], 1);
        unsigned p = (unsigned)base[b] + (unsigned)r;
        if (p < (unsigned)CAP)
            bb[(size_t)b * CAP + p] = ((unsigned)src[i] << shift) | ((unsigned)d & mask);
    }
}

// ========== per-bucket deg/row_st/row_en/csr fill (strided layout) =========
__global__ __launch_bounds__(512) void k_bfill(const unsigned* __restrict__ bb,
                                               const int* __restrict__ bcur,
                                               int* __restrict__ row_st,
                                               int* __restrict__ row_en,
                                               float* __restrict__ inv_deg,
                                               int* __restrict__ csr,
                                               int N, int shift, int CAP) {
    __shared__ int deg[512], cur[512], s[512];
    int b = blockIdx.x;
    int t = threadIdx.x;
    int lo = b << shift;
    int hi = min(N, (b + 1) << shift);
    int nn = hi - lo;
    unsigned off = (unsigned)b * CAP;
    int cnt = min(bcur[b], CAP);
    unsigned mask = (1u << shift) - 1u;

    deg[t] = 0;
    __syncthreads();
    for (int i = t; i < cnt; i += 512)
        atomicAdd(&deg[bb[off + i] & mask], 1);
    __syncthreads();
    int d = deg[t];
    s[t] = d;
    __syncthreads();
    for (int o = 1; o < 512; o <<= 1) {
        int u = (t >= o) ? s[t - o] : 0;
        __syncthreads();
        s[t] += u;
        __syncthreads();
    }
    int excl = s[t] - d;
    cur[t] = excl;
    if (t < nn) {
        row_st[lo + t] = (int)off + excl;
        row_en[lo + t] = (int)off + excl + d;
        inv_deg[lo + t] = d > 0 ? 1.0f / (float)d : 0.0f;
    }
    __syncthreads();
    for (int i = t; i < cnt; i += 512) {
        unsigned w = bb[off + i];
        int dl = (int)(w & mask);
        int pos = atomicAdd(&cur[dl], 1);
        csr[off + pos] = (int)(w >> shift);
    }
}

// ========== weight prep: fp16 W^T[n][k] + fp16 w2 ==========
// half offsets: Wt1 0 (64x128), Wc1 8192, Wl2 16384 (64x64), Wc2 20480,
//               Wp 28672, Wq 32768, w2h 36864 (64)
__global__ __launch_bounds__(256) void k_prep(
    const float* __restrict__ lin1_w, const float* __restrict__ c1_wl,
    const float* __restrict__ c1_wr, const float* __restrict__ lin2_w,
    const float* __restrict__ c2_wl, const float* __restrict__ c2_wr,
    const float* __restrict__ mlp_w1, const float* __restrict__ mlp_w2,
    unsigned short* __restrict__ Wt) {
    int i = blockIdx.x * 256 + threadIdx.x;
    for (; i < 36928; i += gridDim.x * 256) {
        float v;
        if (i < 8192)       { int j = i;         int n = j >> 7, k = j & 127; v = lin1_w[k * 64 + n]; }
        else if (i < 16384) { int j = i - 8192;  int n = j >> 7, k = j & 127;
                              v = (k < 64) ? c1_wl[k * 64 + n] : c1_wr[(k - 64) * 64 + n]; }
        else if (i < 20480) { int j = i - 16384; int n = j >> 6, k = j & 63;  v = lin2_w[k * 64 + n]; }
        else if (i < 28672) { int j = i - 20480; int n = j >> 7, k = j & 127;
                              v = (k < 64) ? c2_wl[k * 64 + n] : c2_wr[(k - 64) * 64 + n]; }
        else if (i < 32768) { int j = i - 28672; int n = j >> 6, k = j & 63;  v = mlp_w1[k * 64 + n]; }
        else if (i < 36864) { int j = i - 32768; int n = j >> 6, k = j & 63;  v = mlp_w1[(k + 64) * 64 + n]; }
        else                { v = mlp_w2[i - 36864]; }
        Wt[i] = f2h(v);
    }
}

// ====== mean aggregation v2: fp16 rows, fma_mix, 8 rows in flight ======
// lane: g = lane>>4 (row slot 0..3), sub = lane&15 (channel quad)
__global__ __launch_bounds__(256) void k_gather_h(
    const _Float16* __restrict__ hh, const int* __restrict__ csr,
    const int* __restrict__ row_st, const int* __restrict__ row_en,
    const float* __restrict__ inv_deg, _Float16* __restrict__ out, int n) {
    int node = (blockIdx.x * 256 + (int)threadIdx.x) >> 6;
    if (node >= n) return;
    int lane = threadIdx.x & 63;
    int g = lane >> 4, sub = lane & 15;
    int base = row_st[node], end = row_en[node];
    float idv = inv_deg[node];
    float a0 = 0.f, a1 = 0.f, a2 = 0.f, a3 = 0.f;
    // main: 8 full rows per iter (2 groups of 4), no masks
    for (; base + 8 <= end; base += 8) {
        int s0 = csr[base + g];
        int s1 = csr[base + 4 + g];
        f16x4 u0 = *(const f16x4*)(hh + (((unsigned)s0 << 6) + ((unsigned)sub << 2)));
        f16x4 u1 = *(const f16x4*)(hh + (((unsigned)s1 << 6) + ((unsigned)sub << 2)));
        a0 = fmaf((float)u0[0], idv, a0);
        a1 = fmaf((float)u0[1], idv, a1);
        a2 = fmaf((float)u0[2], idv, a2);
        a3 = fmaf((float)u0[3], idv, a3);
        a0 = fmaf((float)u1[0], idv, a0);
        a1 = fmaf((float)u1[1], idv, a1);
        a2 = fmaf((float)u1[2], idv, a2);
        a3 = fmaf((float)u1[3], idv, a3);
    }
    // tail: up to 7 rows, masked
    if (base < end) {
        int last = end - 1;
        int j0 = base + g, j1 = base + 4 + g;
        int s0 = csr[min(j0, last)];
        int s1 = csr[min(j1, last)];
        f16x4 u0 = *(const f16x4*)(hh + (((unsigned)s0 << 6) + ((unsigned)sub << 2)));
        f16x4 u1 = *(const f16x4*)(hh + (((unsigned)s1 << 6) + ((unsigned)sub << 2)));
        float m0 = (j0 < end) ? idv : 0.f;
        float m1 = (j1 < end) ? idv : 0.f;
        a0 = fmaf((float)u0[0], m0, a0);
        a1 = fmaf((float)u0[1], m0, a1);
        a2 = fmaf((float)u0[2], m0, a2);
        a3 = fmaf((float)u0[3], m0, a3);
        a0 = fmaf((float)u1[0], m1, a0);
        a1 = fmaf((float)u1[1], m1, a1);
        a2 = fmaf((float)u1[2], m1, a2);
        a3 = fmaf((float)u1[3], m1, a3);
    }
    // fold the 4 row slots (g occupies lane bits 4,5)
    a0 += __shfl_xor(a0, 16, 64); a1 += __shfl_xor(a1, 16, 64);
    a2 += __shfl_xor(a2, 16, 64); a3 += __shfl_xor(a3, 16, 64);
    a0 += __shfl_xor(a0, 32, 64); a1 += __shfl_xor(a1, 32, 64);
    a2 += __shfl_xor(a2, 32, 64); a3 += __shfl_xor(a3, 32, 64);
    if (g == 0) {
        f16x4 o;
        o[0] = (f16)a0; o[1] = (f16)a1; o[2] = (f16)a2; o[3] = (f16)a3;
        *(f16x4*)(out + (((unsigned)node << 6) + ((unsigned)sub << 2))) = o;
    }
}

// ---- k_mm1 (MFMA): Hh = relu(x_f32 @ lin1_w + b), K=128 ----
__global__ __launch_bounds__(256) void k_mm1(
    const float* __restrict__ x, const unsigned short* __restrict__ Wtg,
    const float* __restrict__ bias, unsigned short* __restrict__ outh, int n) {
    __shared__ alignas(16) unsigned short sW[64 * 136];
    const int tid = threadIdx.x;
    const int row0 = blockIdx.x * 64;
    for (int i = tid; i < 64 * 16; i += 256) {
        int nn = i >> 4, c = i & 15;
        *(uint4*)&sW[(nn * 17 + c) * 8] = *(const uint4*)&Wtg[i * 8];
    }
    __syncthreads();
    const int lane = tid & 63, w = tid >> 6;
    const int m = lane & 15, q = lane >> 4;
    const int gr = min(row0 + 16 * w + m, n - 1);
    const float* ar = x + (size_t)gr * 128;
    f32x4 acc[4];
#pragma unroll
    for (int c = 0; c < 4; ++c) acc[c] = (f32x4){0.f, 0.f, 0.f, 0.f};
#pragma unroll
    for (int kk = 0; kk < 4; ++kk) {
        float4 a0 = *(const float4*)(ar + kk * 32 + q * 8);
        float4 a1 = *(const float4*)(ar + kk * 32 + q * 8 + 4);
        f16x8 af;
        af[0] = (f16)a0.x; af[1] = (f16)a0.y; af[2] = (f16)a0.z; af[3] = (f16)a0.w;
        af[4] = (f16)a1.x; af[5] = (f16)a1.y; af[6] = (f16)a1.z; af[7] = (f16)a1.w;
#pragma unroll
        for (int c = 0; c < 4; ++c) {
            f16x8 bf = *(const f16x8*)&sW[((16 * c + m) * 17 + (kk * 4 + q)) * 8];
            acc[c] = __builtin_amdgcn_mfma_f32_16x16x32_f16(af, bf, acc[c], 0, 0, 0);
        }
    }
#pragma unroll
    for (int c = 0; c < 4; ++c) {
        int col = 16 * c + m;
        float bv = bias[col];
#pragma unroll
        for (int i = 0; i < 4; ++i) {
            int r = row0 + 16 * w + q * 4 + i;
            if (r < n) outh[(size_t)r * 64 + col] = f2h(fmaxf(acc[c][i] + bv, 0.f));
        }
    }
}

// ---- k_mm23 (MFMA, 2-stage): h3 = relu(relu([agg|h1]@Wc+bl) @ lin2 + b2) ----
__global__ __launch_bounds__(256) void k_mm23(
    const unsigned short* __restrict__ aggH, const unsigned short* __restrict__ h1,
    const unsigned short* __restrict__ Wcg, const float* __restrict__ bl,
    const unsigned short* __restrict__ Wl2g, const float* __restrict__ b2,
    unsigned short* __restrict__ outh, int n) {
    __shared__ alignas(16) unsigned short sm[64 * 72 + 64 * 136];
    unsigned short* hA = sm;
    unsigned short* sW = sm + 64 * 72;
    const int tid = threadIdx.x;
    const int row0 = blockIdx.x * 64;
    for (int i = tid; i < 64 * 16; i += 256) {
        int nn = i >> 4, c = i & 15;
        *(uint4*)&sW[(nn * 17 + c) * 8] = *(const uint4*)&Wcg[i * 8];
    }
    __syncthreads();
    const int lane = tid & 63, w = tid >> 6;
    const int m = lane & 15, q = lane >> 4;
    const int gr = min(row0 + 16 * w + m, n - 1);
    f32x4 acc[4];
#pragma unroll
    for (int c = 0; c < 4; ++c) acc[c] = (f32x4){0.f, 0.f, 0.f, 0.f};
#pragma unroll
    for (int kk = 0; kk < 4; ++kk) {
        const unsigned short* ap = (kk < 2)
            ? (aggH + (size_t)gr * 64 + kk * 32 + q * 8)
            : (h1 + (size_t)gr * 64 + (kk - 2) * 32 + q * 8);
        f16x8 af = *(const f16x8*)ap;
#pragma unroll
        for (int c = 0; c < 4; ++c) {
            f16x8 bf = *(const f16x8*)&sW[((16 * c + m) * 17 + (kk * 4 + q)) * 8];
            acc[c] = __builtin_amdgcn_mfma_f32_16x16x32_f16(af, bf, acc[c], 0, 0, 0);
        }
    }
#pragma unroll
    for (int c = 0; c < 4; ++c) {
        int col = 16 * c + m;
        float bv = bl[col];
#pragma unroll
        for (int i = 0; i < 4; ++i)
            hA[(16 * w + q * 4 + i) * 72 + col] = f2h(fmaxf(acc[c][i] + bv, 0.f));
    }
    __syncthreads();
    for (int i = tid; i < 64 * 8; i += 256) {
        int nn = i >> 3, c = i & 7;
        *(uint4*)&sW[(nn * 9 + c) * 8] = *(const uint4*)&Wl2g[i * 8];
    }
    __syncthreads();
    f32x4 acc2[4];
#pragma unroll
    for (int c = 0; c < 4; ++c) acc2[c] = (f32x4){0.f, 0.f, 0.f, 0.f};
#pragma unroll
    for (int kk = 0; kk < 2; ++kk) {
        f16x8 af = *(const f16x8*)&hA[(16 * w + m) * 72 + kk * 32 + q * 8];
#pragma unroll
        for (int c = 0; c < 4; ++c) {
            f16x8 bf = *(const f16x8*)&sW[((16 * c + m) * 9 + (kk * 4 + q)) * 8];
            acc2[c] = __builtin_amdgcn_mfma_f32_16x16x32_f16(af, bf, acc2[c], 0, 0, 0);
        }
    }
#pragma unroll
    for (int c = 0; c < 4; ++c) {
        int col = 16 * c + m;
        float bv = b2[col];
#pragma unroll
        for (int i = 0; i < 4; ++i) {
            int r = row0 + 16 * w + q * 4 + i;
            if (r < n) outh[(size_t)r * 64 + col] = f2h(fmaxf(acc2[c][i] + bv, 0.f));
        }
    }
}

// ---- k_mm456 (MFMA, 2-stage): h4=relu([agg2|h3]@Wc2+bl); P=h4@Wp+b1; Q=h4@Wq
__global__ __launch_bounds__(256) void k_mm456(
    const unsigned short* __restrict__ aggH, const unsigned short* __restrict__ h3,
    const unsigned short* __restrict__ Wcg, const float* __restrict__ bl,
    const unsigned short* __restrict__ Wpg, const unsigned short* __restrict__ Wqg,
    const float* __restrict__ b1, unsigned short* __restrict__ Ph,
    unsigned short* __restrict__ Qh, int n) {
    __shared__ alignas(16) unsigned short sm[64 * 72 + 2 * 64 * 72];
    unsigned short* hA = sm;
    unsigned short* sW = sm + 64 * 72;
    const int tid = threadIdx.x;
    const int row0 = blockIdx.x * 64;
    for (int i = tid; i < 64 * 16; i += 256) {
        int nn = i >> 4, c = i & 15;
        *(uint4*)&sW[(nn * 17 + c) * 8] = *(const uint4*)&Wcg[i * 8];
    }
    __syncthreads();
    const int lane = tid & 63, w = tid >> 6;
    const int m = lane & 15, q = lane >> 4;
    const int gr = min(row0 + 16 * w + m, n - 1);
    f32x4 acc[4];
#pragma unroll
    for (int c = 0; c < 4; ++c) acc[c] = (f32x4){0.f, 0.f, 0.f, 0.f};
#pragma unroll
    for (int kk = 0; kk < 4; ++kk) {
        const unsigned short* ap = (kk < 2)
            ? (aggH + (size_t)gr * 64 + kk * 32 + q * 8)
            : (h3 + (size_t)gr * 64 + (kk - 2) * 32 + q * 8);
        f16x8 af = *(const f16x8*)ap;
#pragma unroll
        for (int c = 0; c < 4; ++c) {
            f16x8 bf = *(const f16x8*)&sW[((16 * c + m) * 17 + (kk * 4 + q)) * 8];
            acc[c] = __builtin_amdgcn_mfma_f32_16x16x32_f16(af, bf, acc[c], 0, 0, 0);
        }
    }
#pragma unroll
    for (int c = 0; c < 4; ++c) {
        int col = 16 * c + m;
        float bv = bl[col];
#pragma unroll
        for (int i = 0; i < 4; ++i)
            hA[(16 * w + q * 4 + i) * 72 + col] = f2h(fmaxf(acc[c][i] + bv, 0.f));
    }
    __syncthreads();
    for (int i = tid; i < 64 * 8; i += 256) {
        int nn = i >> 3, c = i & 7;
        *(uint4*)&sW[(nn * 9 + c) * 8] = *(const uint4*)&Wpg[i * 8];
        *(uint4*)&sW[4608 + (nn * 9 + c) * 8] = *(const uint4*)&Wqg[i * 8];
    }
    __syncthreads();
    f32x4 accP[4], accQ[4];
#pragma unroll
    for (int c = 0; c < 4; ++c) {
        accP[c] = (f32x4){0.f, 0.f, 0.f, 0.f};
        accQ[c] = (f32x4){0.f, 0.f, 0.f, 0.f};
    }
#pragma unroll
    for (int kk = 0; kk < 2; ++kk) {
        f16x8 af = *(const f16x8*)&hA[(16 * w + m) * 72 + kk * 32 + q * 8];
#pragma unroll
        for (int c = 0; c < 4; ++c) {
            f16x8 bp = *(const f16x8*)&sW[((16 * c + m) * 9 + (kk * 4 + q)) * 8];
            f16x8 bq = *(const f16x8*)&sW[4608 + ((16 * c + m) * 9 + (kk * 4 + q)) * 8];
            accP[c] = __builtin_amdgcn_mfma_f32_16x16x32_f16(af, bp, accP[c], 0, 0, 0);
            accQ[c] = __builtin_amdgcn_mfma_f32_16x16x32_f16(af, bq, accQ[c], 0, 0, 0);
        }
    }
#pragma unroll
    for (int c = 0; c < 4; ++c) {
        int col = 16 * c + m;
        float bv = b1[col];
#pragma unroll
        for (int i = 0; i < 4; ++i) {
            int r = row0 + 16 * w + q * 4 + i;
            if (r < n) {
                Ph[(size_t)r * 64 + col] = f2h(accP[c][i] + bv);
                Qh[(size_t)r * 64 + col] = f2h(accQ[c][i]);
            }
        }
    }
}

// ---- edge scorer v2: pk_add/pk_max + dot2, fp16 P/Q/w2, fast tanh ----
__global__ __launch_bounds__(256) void k_score_h(
    const _Float16* __restrict__ P, const _Float16* __restrict__ Q,
    const int* __restrict__ msrc, const int* __restrict__ mdst,
    const _Float16* __restrict__ w2h, const float* __restrict__ b2,
    float* __restrict__ out, int M) {
    int gid = blockIdx.x * 256 + threadIdx.x;
    int e = gid >> 4;
    if (e >= M) return;
    int l = gid & 15;
    int s = msrc[e], d = mdst[e];
    f16x4 p = *(const f16x4*)(P + (((unsigned)s << 6) + ((unsigned)l << 2)));
    f16x4 q = *(const f16x4*)(Q + (((unsigned)d << 6) + ((unsigned)l << 2)));
    f16x4 w = *(const f16x4*)(w2h + ((unsigned)l << 2));
    f16x4 u = p + q;                       // v_pk_add_f16 x2
    f16x4 z = {(f16)0, (f16)0, (f16)0, (f16)0};
    u = __builtin_elementwise_max(u, z);   // v_pk_max_f16 x2
    float partial;
#if __has_builtin(__builtin_amdgcn_fdot2)
    f16x2 u01 = {u[0], u[1]}, u23 = {u[2], u[3]};
    f16x2 w01 = {w[0], w[1]}, w23 = {w[2], w[3]};
    partial = __builtin_amdgcn_fdot2(u01, w01,
              __builtin_amdgcn_fdot2(u23, w23, 0.f, false), false);
#else
    partial = (float)u[0] * (float)w[0] + (float)u[1] * (float)w[1]
            + (float)u[2] * (float)w[2] + (float)u[3] * (float)w[3];
#endif
#pragma unroll
    for (int mm = 1; mm < 16; mm <<= 1) partial += __shfl_xor(partial, mm, 16);
    if (l == 0) {
        float xx = partial + b2[0];
        float t = __expf(2.f * xx);
        out[e] = (t - 1.f) / (t + 1.f);
    }
}

extern "C" void kernel_launch(void* const* d_in, const int* in_sizes, int n_in,
                              void* d_out, int out_size, void* d_ws, size_t ws_size,
                              hipStream_t stream) {
    const float* x      = (const float*)d_in[0];
    const int*   ei     = (const int*)d_in[1];
    const int*   mei    = (const int*)d_in[2];
    const float* lin1_w = (const float*)d_in[3];
    const float* lin1_b = (const float*)d_in[4];
    const float* lin2_w = (const float*)d_in[5];
    const float* lin2_b = (const float*)d_in[6];
    const float* c1_wl  = (const float*)d_in[7];
    const float* c1_bl  = (const float*)d_in[8];
    const float* c1_wr  = (const float*)d_in[9];
    const float* c2_wl  = (const float*)d_in[10];
    const float* c2_bl  = (const float*)d_in[11];
    const float* c2_wr  = (const float*)d_in[12];
    const float* mlp_w1 = (const float*)d_in[13];
    const float* mlp_b1 = (const float*)d_in[14];
    const float* mlp_w2 = (const float*)d_in[15];
    const float* mlp_b2 = (const float*)d_in[16];

    const int N = in_sizes[0] / 128;
    const int E = in_sizes[1] / 2;
    const int M = in_sizes[2] / 2;
    const int* src  = ei;
    const int* dstE = ei + E;
    const int* msrc = mei;
    const int* mdst = mei + M;

    int shift = 8;
    while ((((N - 1) >> shift) + 1) > MAXB) ++shift;
    const int nbuckets = ((N - 1) >> shift) + 1;
    // fixed bucket capacity: 2x expected + slack, 1K-aligned
    long long avg = (((long long)E << shift) / N) + 1;
    int CAP = (int)((2 * avg + 2047) & ~1023LL);

    const size_t N64 = (size_t)N * 64;
    unsigned short* Hh   = (unsigned short*)d_ws;   // N*64 fp16: h1/h3/P
    unsigned short* aggH = Hh + N64;                // N*64 fp16
    unsigned short* Qh   = aggH + N64;              // N*64 fp16
    float* inv_deg = (float*)(Qh + N64);            // N
    int*   row_st  = (int*)(inv_deg + N);           // N
    int*   row_en  = row_st + N;                    // N
    int*   bcur    = row_en + N;                    // MAXB
    unsigned short* Wt = (unsigned short*)(bcur + MAXB);  // 36928 halfs
    int*   csr     = (int*)(Wt + 36928 + 32);       // nbuckets*CAP ints
    unsigned* bb   = (unsigned*)Hh;                 // nbuckets*CAP ints (pre-mm1)
    float* outf = (float*)d_out;

    const int nbN = (N + 63) / 64;
    const int nbM = (int)(((long long)M * 16 + 255) / 256);
    const int nbG = (int)(((long long)N * 64 + 255) / 256);
    const int nbP = (E + PART_CH - 1) / PART_CH;

    // ---- CSR build (single-pass) + weight prep ----
    hipMemsetAsync(bcur, 0, MAXB * sizeof(int), stream);
    k_prep<<<64, 256, 0, stream>>>(lin1_w, c1_wl, c1_wr, lin2_w, c2_wl, c2_wr,
                                   mlp_w1, mlp_w2, Wt);
    k_part<<<nbP, PART_BS, 0, stream>>>(src, dstE, bcur, bb, E, shift, CAP);
    k_bfill<<<nbuckets, 512, 0, stream>>>(bb, bcur, row_st, row_en,
                                          inv_deg, csr, N, shift, CAP);

    // h1 = relu(x @ lin1_w + b)  (fp16 out)
    k_mm1<<<nbN, 256, 0, stream>>>(x, Wt + 0, lin1_b, Hh, N);

    // sage1 + lin2 fused
    k_gather_h<<<nbG, 256, 0, stream>>>((const _Float16*)Hh, csr, row_st, row_en,
                                        inv_deg, (_Float16*)aggH, N);
    k_mm23<<<nbN, 256, 0, stream>>>(aggH, Hh, Wt + 8192, c1_bl,
                                    Wt + 16384, lin2_b, Hh, N);

    // sage2 + P/Q fused
    k_gather_h<<<nbG, 256, 0, stream>>>((const _Float16*)Hh, csr, row_st, row_en,
                                        inv_deg, (_Float16*)aggH, N);
    k_mm456<<<nbN, 256, 0, stream>>>(aggH, Hh, Wt + 20480, c2_bl,
                                     Wt + 28672, Wt + 32768, mlp_b1,
                                     Hh, Qh, N);

    // edge scoring
    k_score_h<<<nbM, 256, 0, stream>>>((const _Float16*)Hh, (const _Float16*)Qh,
                                       msrc, mdst, (const _Float16*)(Wt + 36864),
                                       mlp_b2, outf, M);
}

// Round 10
// 416.298 us; speedup vs baseline: 2.7857x; 1.0294x over previous
//
#include <hip/hip_runtime.h>
#include <math.h>

#define MAXB 512
#define PART_CH 8192
#define PART_BS 1024

typedef _Float16 f16;
typedef __attribute__((ext_vector_type(2))) _Float16 f16x2;
typedef __attribute__((ext_vector_type(4))) _Float16 f16x4;
typedef __attribute__((ext_vector_type(8))) _Float16 f16x8;
typedef __attribute__((ext_vector_type(4))) float f32x4;

static __device__ __forceinline__ unsigned short f2h(float f) {
    f16 h = (f16)f; return *(unsigned short*)&h;
}

// ========== single-pass partition into fixed-capacity strided buckets ======
__global__ __launch_bounds__(PART_BS) void k_part(const int* __restrict__ src,
                                                  const int* __restrict__ dst,
                                                  int* __restrict__ bcur,
                                                  unsigned* __restrict__ bb,
                                                  int E, int shift, int CAP) {
    __shared__ int h[MAXB], base[MAXB];
    int b0 = blockIdx.x * PART_CH;
    int e1 = min(b0 + PART_CH, E);
    for (int i = threadIdx.x; i < MAXB; i += PART_BS) h[i] = 0;
    __syncthreads();
    for (int i = b0 + threadIdx.x; i < e1; i += PART_BS)
        atomicAdd(&h[dst[i] >> shift], 1);
    __syncthreads();
    for (int i = threadIdx.x; i < MAXB; i += PART_BS) {
        base[i] = h[i] ? atomicAdd(&bcur[i], h[i]) : 0;
        h[i] = 0;
    }
    __syncthreads();
    unsigned mask = (1u << shift) - 1u;
    for (int i = b0 + threadIdx.x; i < e1; i += PART_BS) {
        int d = dst[i];
        int b = d >> shift;
        int r = atomicAdd(&h[b], 1);
        unsigned p = (unsigned)base[b] + (unsigned)r;
        if (p < (unsigned)CAP)
            bb[(size_t)b * CAP + p] = ((unsigned)src[i] << shift) | ((unsigned)d & mask);
    }
}

// ========== per-bucket deg/row_st/row_en/csr fill (strided layout) =========
__global__ __launch_bounds__(512) void k_bfill(const unsigned* __restrict__ bb,
                                               const int* __restrict__ bcur,
                                               int* __restrict__ row_st,
                                               int* __restrict__ row_en,
                                               float* __restrict__ inv_deg,
                                               int* __restrict__ csr,
                                               int N, int shift, int CAP) {
    __shared__ int deg[512], cur[512], s[512];
    int b = blockIdx.x;
    int t = threadIdx.x;
    int lo = b << shift;
    int hi = min(N, (b + 1) << shift);
    int nn = hi - lo;
    unsigned off = (unsigned)b * CAP;
    int cnt = min(bcur[b], CAP);
    unsigned mask = (1u << shift) - 1u;

    deg[t] = 0;
    __syncthreads();
    for (int i = t; i < cnt; i += 512)
        atomicAdd(&deg[bb[off + i] & mask], 1);
    __syncthreads();
    int d = deg[t];
    s[t] = d;
    __syncthreads();
    for (int o = 1; o < 512; o <<= 1) {
        int u = (t >= o) ? s[t - o] : 0;
        __syncthreads();
        s[t] += u;
        __syncthreads();
    }
    int excl = s[t] - d;
    cur[t] = excl;
    if (t < nn) {
        row_st[lo + t] = (int)off + excl;
        row_en[lo + t] = (int)off + excl + d;
        inv_deg[lo + t] = d > 0 ? 1.0f / (float)d : 0.0f;
    }
    __syncthreads();
    for (int i = t; i < cnt; i += 512) {
        unsigned w = bb[off + i];
        int dl = (int)(w & mask);
        int pos = atomicAdd(&cur[dl], 1);
        csr[off + pos] = (int)(w >> shift);
    }
}

// ========== weight prep: fp16 W^T[n][k] + fp16 w2 ==========
__global__ __launch_bounds__(256) void k_prep(
    const float* __restrict__ lin1_w, const float* __restrict__ c1_wl,
    const float* __restrict__ c1_wr, const float* __restrict__ lin2_w,
    const float* __restrict__ c2_wl, const float* __restrict__ c2_wr,
    const float* __restrict__ mlp_w1, const float* __restrict__ mlp_w2,
    unsigned short* __restrict__ Wt) {
    int i = blockIdx.x * 256 + threadIdx.x;
    for (; i < 36928; i += gridDim.x * 256) {
        float v;
        if (i < 8192)       { int j = i;         int n = j >> 7, k = j & 127; v = lin1_w[k * 64 + n]; }
        else if (i < 16384) { int j = i - 8192;  int n = j >> 7, k = j & 127;
                              v = (k < 64) ? c1_wl[k * 64 + n] : c1_wr[(k - 64) * 64 + n]; }
        else if (i < 20480) { int j = i - 16384; int n = j >> 6, k = j & 63;  v = lin2_w[k * 64 + n]; }
        else if (i < 28672) { int j = i - 20480; int n = j >> 7, k = j & 127;
                              v = (k < 64) ? c2_wl[k * 64 + n] : c2_wr[(k - 64) * 64 + n]; }
        else if (i < 32768) { int j = i - 28672; int n = j >> 6, k = j & 63;  v = mlp_w1[k * 64 + n]; }
        else if (i < 36864) { int j = i - 32768; int n = j >> 6, k = j & 63;  v = mlp_w1[(k + 64) * 64 + n]; }
        else                { v = mlp_w2[i - 36864]; }
        Wt[i] = f2h(v);
    }
}

// ====== mean aggregation v3: 16 row-loads in flight, fma_mix accum ======
// lane: g = lane>>4 (row slot 0..3), sub = lane&15 (channel quad)
__global__ __launch_bounds__(256) void k_gather_h(
    const _Float16* __restrict__ hh, const int* __restrict__ csr,
    const int* __restrict__ row_st, const int* __restrict__ row_en,
    const float* __restrict__ inv_deg, _Float16* __restrict__ out, int n) {
    int node = (blockIdx.x * 256 + (int)threadIdx.x) >> 6;
    if (node >= n) return;
    int lane = threadIdx.x & 63;
    int g = lane >> 4, sub = lane & 15;
    int base = row_st[node], end = row_en[node];
    float idv = inv_deg[node];
    float a0 = 0.f, a1 = 0.f, a2 = 0.f, a3 = 0.f;
    for (; base < end; base += 64) {
        int last = end - 1;
        int jj[16], sidx[16];
#pragma unroll
        for (int t = 0; t < 16; ++t) {
            jj[t] = base + g + 4 * t;
            sidx[t] = csr[min(jj[t], last)];
        }
        f16x4 u[16];
#pragma unroll
        for (int t = 0; t < 16; ++t)
            u[t] = *(const f16x4*)(hh + (((unsigned)sidx[t] << 6) + ((unsigned)sub << 2)));
#pragma unroll
        for (int t = 0; t < 16; ++t) {
            float m = (jj[t] < end) ? idv : 0.f;
            a0 = fmaf((float)u[t][0], m, a0);
            a1 = fmaf((float)u[t][1], m, a1);
            a2 = fmaf((float)u[t][2], m, a2);
            a3 = fmaf((float)u[t][3], m, a3);
        }
    }
    a0 += __shfl_xor(a0, 16, 64); a1 += __shfl_xor(a1, 16, 64);
    a2 += __shfl_xor(a2, 16, 64); a3 += __shfl_xor(a3, 16, 64);
    a0 += __shfl_xor(a0, 32, 64); a1 += __shfl_xor(a1, 32, 64);
    a2 += __shfl_xor(a2, 32, 64); a3 += __shfl_xor(a3, 32, 64);
    if (g == 0) {
        f16x4 o;
        o[0] = (f16)a0; o[1] = (f16)a1; o[2] = (f16)a2; o[3] = (f16)a3;
        *(f16x4*)(out + (((unsigned)node << 6) + ((unsigned)sub << 2))) = o;
    }
}

// ---- k_mm1 (MFMA): Hh = relu(x_f32 @ lin1_w + b), K=128 ----
__global__ __launch_bounds__(256) void k_mm1(
    const float* __restrict__ x, const unsigned short* __restrict__ Wtg,
    const float* __restrict__ bias, unsigned short* __restrict__ outh, int n) {
    __shared__ alignas(16) unsigned short sW[64 * 136];
    const int tid = threadIdx.x;
    const int row0 = blockIdx.x * 64;
    for (int i = tid; i < 64 * 16; i += 256) {
        int nn = i >> 4, c = i & 15;
        *(uint4*)&sW[(nn * 17 + c) * 8] = *(const uint4*)&Wtg[i * 8];
    }
    __syncthreads();
    const int lane = tid & 63, w = tid >> 6;
    const int m = lane & 15, q = lane >> 4;
    const int gr = min(row0 + 16 * w + m, n - 1);
    const float* ar = x + (size_t)gr * 128;
    f32x4 acc[4];
#pragma unroll
    for (int c = 0; c < 4; ++c) acc[c] = (f32x4){0.f, 0.f, 0.f, 0.f};
#pragma unroll
    for (int kk = 0; kk < 4; ++kk) {
        float4 a0 = *(const float4*)(ar + kk * 32 + q * 8);
        float4 a1 = *(const float4*)(ar + kk * 32 + q * 8 + 4);
        f16x8 af;
        af[0] = (f16)a0.x; af[1] = (f16)a0.y; af[2] = (f16)a0.z; af[3] = (f16)a0.w;
        af[4] = (f16)a1.x; af[5] = (f16)a1.y; af[6] = (f16)a1.z; af[7] = (f16)a1.w;
#pragma unroll
        for (int c = 0; c < 4; ++c) {
            f16x8 bf = *(const f16x8*)&sW[((16 * c + m) * 17 + (kk * 4 + q)) * 8];
            acc[c] = __builtin_amdgcn_mfma_f32_16x16x32_f16(af, bf, acc[c], 0, 0, 0);
        }
    }
#pragma unroll
    for (int c = 0; c < 4; ++c) {
        int col = 16 * c + m;
        float bv = bias[col];
#pragma unroll
        for (int i = 0; i < 4; ++i) {
            int r = row0 + 16 * w + q * 4 + i;
            if (r < n) outh[(size_t)r * 64 + col] = f2h(fmaxf(acc[c][i] + bv, 0.f));
        }
    }
}

// ---- k_mm23 (MFMA, 2-stage): h3 = relu(relu([agg|h1]@Wc+bl) @ lin2 + b2) ----
__global__ __launch_bounds__(256) void k_mm23(
    const unsigned short* __restrict__ aggH, const unsigned short* __restrict__ h1,
    const unsigned short* __restrict__ Wcg, const float* __restrict__ bl,
    const unsigned short* __restrict__ Wl2g, const float* __restrict__ b2,
    unsigned short* __restrict__ outh, int n) {
    __shared__ alignas(16) unsigned short sm[64 * 72 + 64 * 136];
    unsigned short* hA = sm;
    unsigned short* sW = sm + 64 * 72;
    const int tid = threadIdx.x;
    const int row0 = blockIdx.x * 64;
    for (int i = tid; i < 64 * 16; i += 256) {
        int nn = i >> 4, c = i & 15;
        *(uint4*)&sW[(nn * 17 + c) * 8] = *(const uint4*)&Wcg[i * 8];
    }
    __syncthreads();
    const int lane = tid & 63, w = tid >> 6;
    const int m = lane & 15, q = lane >> 4;
    const int gr = min(row0 + 16 * w + m, n - 1);
    f32x4 acc[4];
#pragma unroll
    for (int c = 0; c < 4; ++c) acc[c] = (f32x4){0.f, 0.f, 0.f, 0.f};
#pragma unroll
    for (int kk = 0; kk < 4; ++kk) {
        const unsigned short* ap = (kk < 2)
            ? (aggH + (size_t)gr * 64 + kk * 32 + q * 8)
            : (h1 + (size_t)gr * 64 + (kk - 2) * 32 + q * 8);
        f16x8 af = *(const f16x8*)ap;
#pragma unroll
        for (int c = 0; c < 4; ++c) {
            f16x8 bf = *(const f16x8*)&sW[((16 * c + m) * 17 + (kk * 4 + q)) * 8];
            acc[c] = __builtin_amdgcn_mfma_f32_16x16x32_f16(af, bf, acc[c], 0, 0, 0);
        }
    }
#pragma unroll
    for (int c = 0; c < 4; ++c) {
        int col = 16 * c + m;
        float bv = bl[col];
#pragma unroll
        for (int i = 0; i < 4; ++i)
            hA[(16 * w + q * 4 + i) * 72 + col] = f2h(fmaxf(acc[c][i] + bv, 0.f));
    }
    __syncthreads();
    for (int i = tid; i < 64 * 8; i += 256) {
        int nn = i >> 3, c = i & 7;
        *(uint4*)&sW[(nn * 9 + c) * 8] = *(const uint4*)&Wl2g[i * 8];
    }
    __syncthreads();
    f32x4 acc2[4];
#pragma unroll
    for (int c = 0; c < 4; ++c) acc2[c] = (f32x4){0.f, 0.f, 0.f, 0.f};
#pragma unroll
    for (int kk = 0; kk < 2; ++kk) {
        f16x8 af = *(const f16x8*)&hA[(16 * w + m) * 72 + kk * 32 + q * 8];
#pragma unroll
        for (int c = 0; c < 4; ++c) {
            f16x8 bf = *(const f16x8*)&sW[((16 * c + m) * 9 + (kk * 4 + q)) * 8];
            acc2[c] = __builtin_amdgcn_mfma_f32_16x16x32_f16(af, bf, acc2[c], 0, 0, 0);
        }
    }
#pragma unroll
    for (int c = 0; c < 4; ++c) {
        int col = 16 * c + m;
        float bv = b2[col];
#pragma unroll
        for (int i = 0; i < 4; ++i) {
            int r = row0 + 16 * w + q * 4 + i;
            if (r < n) outh[(size_t)r * 64 + col] = f2h(fmaxf(acc2[c][i] + bv, 0.f));
        }
    }
}

// ---- k_mm456 (MFMA, 2-stage): h4=relu([agg2|h3]@Wc2+bl); P=h4@Wp+b1; Q=h4@Wq
__global__ __launch_bounds__(256) void k_mm456(
    const unsigned short* __restrict__ aggH, const unsigned short* __restrict__ h3,
    const unsigned short* __restrict__ Wcg, const float* __restrict__ bl,
    const unsigned short* __restrict__ Wpg, const unsigned short* __restrict__ Wqg,
    const float* __restrict__ b1, unsigned short* __restrict__ Ph,
    unsigned short* __restrict__ Qh, int n) {
    __shared__ alignas(16) unsigned short sm[64 * 72 + 2 * 64 * 72];
    unsigned short* hA = sm;
    unsigned short* sW = sm + 64 * 72;
    const int tid = threadIdx.x;
    const int row0 = blockIdx.x * 64;
    for (int i = tid; i < 64 * 16; i += 256) {
        int nn = i >> 4, c = i & 15;
        *(uint4*)&sW[(nn * 17 + c) * 8] = *(const uint4*)&Wcg[i * 8];
    }
    __syncthreads();
    const int lane = tid & 63, w = tid >> 6;
    const int m = lane & 15, q = lane >> 4;
    const int gr = min(row0 + 16 * w + m, n - 1);
    f32x4 acc[4];
#pragma unroll
    for (int c = 0; c < 4; ++c) acc[c] = (f32x4){0.f, 0.f, 0.f, 0.f};
#pragma unroll
    for (int kk = 0; kk < 4; ++kk) {
        const unsigned short* ap = (kk < 2)
            ? (aggH + (size_t)gr * 64 + kk * 32 + q * 8)
            : (h3 + (size_t)gr * 64 + (kk - 2) * 32 + q * 8);
        f16x8 af = *(const f16x8*)ap;
#pragma unroll
        for (int c = 0; c < 4; ++c) {
            f16x8 bf = *(const f16x8*)&sW[((16 * c + m) * 17 + (kk * 4 + q)) * 8];
            acc[c] = __builtin_amdgcn_mfma_f32_16x16x32_f16(af, bf, acc[c], 0, 0, 0);
        }
    }
#pragma unroll
    for (int c = 0; c < 4; ++c) {
        int col = 16 * c + m;
        float bv = bl[col];
#pragma unroll
        for (int i = 0; i < 4; ++i)
            hA[(16 * w + q * 4 + i) * 72 + col] = f2h(fmaxf(acc[c][i] + bv, 0.f));
    }
    __syncthreads();
    for (int i = tid; i < 64 * 8; i += 256) {
        int nn = i >> 3, c = i & 7;
        *(uint4*)&sW[(nn * 9 + c) * 8] = *(const uint4*)&Wpg[i * 8];
        *(uint4*)&sW[4608 + (nn * 9 + c) * 8] = *(const uint4*)&Wqg[i * 8];
    }
    __syncthreads();
    f32x4 accP[4], accQ[4];
#pragma unroll
    for (int c = 0; c < 4; ++c) {
        accP[c] = (f32x4){0.f, 0.f, 0.f, 0.f};
        accQ[c] = (f32x4){0.f, 0.f, 0.f, 0.f};
    }
#pragma unroll
    for (int kk = 0; kk < 2; ++kk) {
        f16x8 af = *(const f16x8*)&hA[(16 * w + m) * 72 + kk * 32 + q * 8];
#pragma unroll
        for (int c = 0; c < 4; ++c) {
            f16x8 bp = *(const f16x8*)&sW[((16 * c + m) * 9 + (kk * 4 + q)) * 8];
            f16x8 bq = *(const f16x8*)&sW[4608 + ((16 * c + m) * 9 + (kk * 4 + q)) * 8];
            accP[c] = __builtin_amdgcn_mfma_f32_16x16x32_f16(af, bp, accP[c], 0, 0, 0);
            accQ[c] = __builtin_amdgcn_mfma_f32_16x16x32_f16(af, bq, accQ[c], 0, 0, 0);
        }
    }
#pragma unroll
    for (int c = 0; c < 4; ++c) {
        int col = 16 * c + m;
        float bv = b1[col];
#pragma unroll
        for (int i = 0; i < 4; ++i) {
            int r = row0 + 16 * w + q * 4 + i;
            if (r < n) {
                Ph[(size_t)r * 64 + col] = f2h(accP[c][i] + bv);
                Qh[(size_t)r * 64 + col] = f2h(accQ[c][i]);
            }
        }
    }
}

// ---- edge scorer v3: 8 lanes/edge, f16x8, 16 loads in flight per wave ----
__global__ __launch_bounds__(256) void k_score_h(
    const _Float16* __restrict__ P, const _Float16* __restrict__ Q,
    const int* __restrict__ msrc, const int* __restrict__ mdst,
    const _Float16* __restrict__ w2h, const float* __restrict__ b2,
    float* __restrict__ out, int M) {
    int gid = blockIdx.x * 256 + threadIdx.x;
    int e = gid >> 3;
    if (e >= M) return;
    int l = gid & 7;
    int s = msrc[e], d = mdst[e];
    f16x8 p = *(const f16x8*)(P + (((unsigned)s << 6) + ((unsigned)l << 3)));
    f16x8 q = *(const f16x8*)(Q + (((unsigned)d << 6) + ((unsigned)l << 3)));
    f16x8 w = *(const f16x8*)(w2h + ((unsigned)l << 3));
    f16x8 u = p + q;                       // v_pk_add_f16 x4
    f16x8 z = {(f16)0, (f16)0, (f16)0, (f16)0, (f16)0, (f16)0, (f16)0, (f16)0};
    u = __builtin_elementwise_max(u, z);   // v_pk_max_f16 x4
    float partial;
#if __has_builtin(__builtin_amdgcn_fdot2)
    f16x2 u01 = {u[0], u[1]}, u23 = {u[2], u[3]}, u45 = {u[4], u[5]}, u67 = {u[6], u[7]};
    f16x2 w01 = {w[0], w[1]}, w23 = {w[2], w[3]}, w45 = {w[4], w[5]}, w67 = {w[6], w[7]};
    partial = __builtin_amdgcn_fdot2(u01, w01,
              __builtin_amdgcn_fdot2(u23, w23,
              __builtin_amdgcn_fdot2(u45, w45,
              __builtin_amdgcn_fdot2(u67, w67, 0.f, false), false), false), false);
#else
    partial = 0.f;
#pragma unroll
    for (int i = 0; i < 8; ++i) partial += (float)u[i] * (float)w[i];
#endif
    partial += __shfl_xor(partial, 1, 8);
    partial += __shfl_xor(partial, 2, 8);
    partial += __shfl_xor(partial, 4, 8);
    if (l == 0) {
        float xx = partial + b2[0];
        float t = __expf(2.f * xx);
        out[e] = (t - 1.f) / (t + 1.f);
    }
}

extern "C" void kernel_launch(void* const* d_in, const int* in_sizes, int n_in,
                              void* d_out, int out_size, void* d_ws, size_t ws_size,
                              hipStream_t stream) {
    const float* x      = (const float*)d_in[0];
    const int*   ei     = (const int*)d_in[1];
    const int*   mei    = (const int*)d_in[2];
    const float* lin1_w = (const float*)d_in[3];
    const float* lin1_b = (const float*)d_in[4];
    const float* lin2_w = (const float*)d_in[5];
    const float* lin2_b = (const float*)d_in[6];
    const float* c1_wl  = (const float*)d_in[7];
    const float* c1_bl  = (const float*)d_in[8];
    const float* c1_wr  = (const float*)d_in[9];
    const float* c2_wl  = (const float*)d_in[10];
    const float* c2_bl  = (const float*)d_in[11];
    const float* c2_wr  = (const float*)d_in[12];
    const float* mlp_w1 = (const float*)d_in[13];
    const float* mlp_b1 = (const float*)d_in[14];
    const float* mlp_w2 = (const float*)d_in[15];
    const float* mlp_b2 = (const float*)d_in[16];

    const int N = in_sizes[0] / 128;
    const int E = in_sizes[1] / 2;
    const int M = in_sizes[2] / 2;
    const int* src  = ei;
    const int* dstE = ei + E;
    const int* msrc = mei;
    const int* mdst = mei + M;

    int shift = 8;
    while ((((N - 1) >> shift) + 1) > MAXB) ++shift;
    const int nbuckets = ((N - 1) >> shift) + 1;
    long long avg = (((long long)E << shift) / N) + 1;
    int CAP = (int)((2 * avg + 2047) & ~1023LL);

    const size_t N64 = (size_t)N * 64;
    unsigned short* Hh   = (unsigned short*)d_ws;   // N*64 fp16: h1/h3/P
    unsigned short* aggH = Hh + N64;                // N*64 fp16
    unsigned short* Qh   = aggH + N64;              // N*64 fp16
    float* inv_deg = (float*)(Qh + N64);            // N
    int*   row_st  = (int*)(inv_deg + N);           // N
    int*   row_en  = row_st + N;                    // N
    int*   bcur    = row_en + N;                    // MAXB
    unsigned short* Wt = (unsigned short*)(bcur + MAXB);  // 36928 halfs
    int*   csr     = (int*)(Wt + 36928 + 32);       // nbuckets*CAP ints
    unsigned* bb   = (unsigned*)Hh;                 // nbuckets*CAP ints (pre-mm1)
    float* outf = (float*)d_out;

    const int nbN = (N + 63) / 64;
    const int nbM = (int)(((long long)M * 8 + 255) / 256);
    const int nbG = (int)(((long long)N * 64 + 255) / 256);
    const int nbP = (E + PART_CH - 1) / PART_CH;

    // ---- CSR build (single-pass) + weight prep ----
    hipMemsetAsync(bcur, 0, MAXB * sizeof(int), stream);
    k_prep<<<64, 256, 0, stream>>>(lin1_w, c1_wl, c1_wr, lin2_w, c2_wl, c2_wr,
                                   mlp_w1, mlp_w2, Wt);
    k_part<<<nbP, PART_BS, 0, stream>>>(src, dstE, bcur, bb, E, shift, CAP);
    k_bfill<<<nbuckets, 512, 0, stream>>>(bb, bcur, row_st, row_en,
                                          inv_deg, csr, N, shift, CAP);

    // h1 = relu(x @ lin1_w + b)  (fp16 out)
    k_mm1<<<nbN, 256, 0, stream>>>(x, Wt + 0, lin1_b, Hh, N);

    // sage1 + lin2 fused
    k_gather_h<<<nbG, 256, 0, stream>>>((const _Float16*)Hh, csr, row_st, row_en,
                                        inv_deg, (_Float16*)aggH, N);
    k_mm23<<<nbN, 256, 0, stream>>>(aggH, Hh, Wt + 8192, c1_bl,
                                    Wt + 16384, lin2_b, Hh, N);

    // sage2 + P/Q fused
    k_gather_h<<<nbG, 256, 0, stream>>>((const _Float16*)Hh, csr, row_st, row_en,
                                        inv_deg, (_Float16*)aggH, N);
    k_mm456<<<nbN, 256, 0, stream>>>(aggH, Hh, Wt + 20480, c2_bl,
                                     Wt + 28672, Wt + 32768, mlp_b1,
                                     Hh, Qh, N);

    // edge scoring
    k_score_h<<<nbM, 256, 0, stream>>>((const _Float16*)Hh, (const _Float16*)Qh,
                                       msrc, mdst, (const _Float16*)(Wt + 36864),
                                       mlp_b2, outf, M);
}

// Round 11
// 386.615 us; speedup vs baseline: 2.9996x; 1.0768x over previous
//
#include <hip/hip_runtime.h>
#include <math.h>

#define MAXB 512
#define PART_CH 8192
#define PART_BS 1024

typedef _Float16 f16;
typedef __attribute__((ext_vector_type(2))) _Float16 f16x2;
typedef __attribute__((ext_vector_type(4))) _Float16 f16x4;
typedef __attribute__((ext_vector_type(8))) _Float16 f16x8;
typedef __attribute__((ext_vector_type(4))) float f32x4;

static __device__ __forceinline__ unsigned short f2h(float f) {
    f16 h = (f16)f; return *(unsigned short*)&h;
}

// ========== single-pass partition into fixed-capacity strided buckets ======
__global__ __launch_bounds__(PART_BS) void k_part(const int* __restrict__ src,
                                                  const int* __restrict__ dst,
                                                  int* __restrict__ bcur,
                                                  unsigned* __restrict__ bb,
                                                  int E, int shift, int CAP) {
    __shared__ int h[MAXB], base[MAXB];
    int b0 = blockIdx.x * PART_CH;
    int e1 = min(b0 + PART_CH, E);
    for (int i = threadIdx.x; i < MAXB; i += PART_BS) h[i] = 0;
    __syncthreads();
    for (int i = b0 + threadIdx.x; i < e1; i += PART_BS)
        atomicAdd(&h[dst[i] >> shift], 1);
    __syncthreads();
    for (int i = threadIdx.x; i < MAXB; i += PART_BS) {
        base[i] = h[i] ? atomicAdd(&bcur[i], h[i]) : 0;
        h[i] = 0;
    }
    __syncthreads();
    unsigned mask = (1u << shift) - 1u;
    for (int i = b0 + threadIdx.x; i < e1; i += PART_BS) {
        int d = dst[i];
        int b = d >> shift;
        int r = atomicAdd(&h[b], 1);
        unsigned p = (unsigned)base[b] + (unsigned)r;
        if (p < (unsigned)CAP)
            bb[(size_t)b * CAP + p] = ((unsigned)src[i] << shift) | ((unsigned)d & mask);
    }
}

// ========== per-bucket deg/row_st/row_en/csr fill (strided layout) =========
__global__ __launch_bounds__(512) void k_bfill(const unsigned* __restrict__ bb,
                                               const int* __restrict__ bcur,
                                               int* __restrict__ row_st,
                                               int* __restrict__ row_en,
                                               float* __restrict__ inv_deg,
                                               int* __restrict__ csr,
                                               int N, int shift, int CAP) {
    __shared__ int deg[512], cur[512], s[512];
    int b = blockIdx.x;
    int t = threadIdx.x;
    int lo = b << shift;
    int hi = min(N, (b + 1) << shift);
    int nn = hi - lo;
    unsigned off = (unsigned)b * CAP;
    int cnt = min(bcur[b], CAP);
    unsigned mask = (1u << shift) - 1u;

    deg[t] = 0;
    __syncthreads();
    for (int i = t; i < cnt; i += 512)
        atomicAdd(&deg[bb[off + i] & mask], 1);
    __syncthreads();
    int d = deg[t];
    s[t] = d;
    __syncthreads();
    for (int o = 1; o < 512; o <<= 1) {
        int u = (t >= o) ? s[t - o] : 0;
        __syncthreads();
        s[t] += u;
        __syncthreads();
    }
    int excl = s[t] - d;
    cur[t] = excl;
    if (t < nn) {
        row_st[lo + t] = (int)off + excl;
        row_en[lo + t] = (int)off + excl + d;
        inv_deg[lo + t] = d > 0 ? 1.0f / (float)d : 0.0f;
    }
    __syncthreads();
    for (int i = t; i < cnt; i += 512) {
        unsigned w = bb[off + i];
        int dl = (int)(w & mask);
        int pos = atomicAdd(&cur[dl], 1);
        csr[off + pos] = (int)(w >> shift);
    }
}

// ========== weight prep: fp16 W^T[n][k] + fp16 w2 ==========
__global__ __launch_bounds__(256) void k_prep(
    const float* __restrict__ lin1_w, const float* __restrict__ c1_wl,
    const float* __restrict__ c1_wr, const float* __restrict__ lin2_w,
    const float* __restrict__ c2_wl, const float* __restrict__ c2_wr,
    const float* __restrict__ mlp_w1, const float* __restrict__ mlp_w2,
    unsigned short* __restrict__ Wt) {
    int i = blockIdx.x * 256 + threadIdx.x;
    for (; i < 36928; i += gridDim.x * 256) {
        float v;
        if (i < 8192)       { int j = i;         int n = j >> 7, k = j & 127; v = lin1_w[k * 64 + n]; }
        else if (i < 16384) { int j = i - 8192;  int n = j >> 7, k = j & 127;
                              v = (k < 64) ? c1_wl[k * 64 + n] : c1_wr[(k - 64) * 64 + n]; }
        else if (i < 20480) { int j = i - 16384; int n = j >> 6, k = j & 63;  v = lin2_w[k * 64 + n]; }
        else if (i < 28672) { int j = i - 20480; int n = j >> 7, k = j & 127;
                              v = (k < 64) ? c2_wl[k * 64 + n] : c2_wr[(k - 64) * 64 + n]; }
        else if (i < 32768) { int j = i - 28672; int n = j >> 6, k = j & 63;  v = mlp_w1[k * 64 + n]; }
        else if (i < 36864) { int j = i - 32768; int n = j >> 6, k = j & 63;  v = mlp_w1[(k + 64) * 64 + n]; }
        else                { v = mlp_w2[i - 36864]; }
        Wt[i] = f2h(v);
    }
}

// ====== mean aggregation v4: 32-row chunks, 8 loads in flight (r8 ILP),
//        idv folded into mask multiplier (r10 VALU) ======
// lane: g = lane>>4 (row slot 0..3), sub = lane&15 (channel quad)
__global__ __launch_bounds__(256) void k_gather_h(
    const _Float16* __restrict__ hh, const int* __restrict__ csr,
    const int* __restrict__ row_st, const int* __restrict__ row_en,
    const float* __restrict__ inv_deg, _Float16* __restrict__ out, int n) {
    int node = (blockIdx.x * 256 + (int)threadIdx.x) >> 6;
    if (node >= n) return;
    int lane = threadIdx.x & 63;
    int g = lane >> 4, sub = lane & 15;
    int base = row_st[node], end = row_en[node];
    float idv = inv_deg[node];
    float a0 = 0.f, a1 = 0.f, a2 = 0.f, a3 = 0.f;
    for (; base < end; base += 32) {
        int last = end - 1;
        int jj[8], sidx[8];
#pragma unroll
        for (int t = 0; t < 8; ++t) {
            jj[t] = base + g + 4 * t;
            sidx[t] = csr[min(jj[t], last)];
        }
        f16x4 u[8];
#pragma unroll
        for (int t = 0; t < 8; ++t)
            u[t] = *(const f16x4*)(hh + (((unsigned)sidx[t] << 6) + ((unsigned)sub << 2)));
#pragma unroll
        for (int t = 0; t < 8; ++t) {
            float m = (jj[t] < end) ? idv : 0.f;
            a0 = fmaf((float)u[t][0], m, a0);
            a1 = fmaf((float)u[t][1], m, a1);
            a2 = fmaf((float)u[t][2], m, a2);
            a3 = fmaf((float)u[t][3], m, a3);
        }
    }
    a0 += __shfl_xor(a0, 16, 64); a1 += __shfl_xor(a1, 16, 64);
    a2 += __shfl_xor(a2, 16, 64); a3 += __shfl_xor(a3, 16, 64);
    a0 += __shfl_xor(a0, 32, 64); a1 += __shfl_xor(a1, 32, 64);
    a2 += __shfl_xor(a2, 32, 64); a3 += __shfl_xor(a3, 32, 64);
    if (g == 0) {
        f16x4 o;
        o[0] = (f16)a0; o[1] = (f16)a1; o[2] = (f16)a2; o[3] = (f16)a3;
        *(f16x4*)(out + (((unsigned)node << 6) + ((unsigned)sub << 2))) = o;
    }
}

// ---- k_mm1 (MFMA): Hh = relu(x_f32 @ lin1_w + b), K=128 ----
__global__ __launch_bounds__(256) void k_mm1(
    const float* __restrict__ x, const unsigned short* __restrict__ Wtg,
    const float* __restrict__ bias, unsigned short* __restrict__ outh, int n) {
    __shared__ alignas(16) unsigned short sW[64 * 136];
    const int tid = threadIdx.x;
    const int row0 = blockIdx.x * 64;
    for (int i = tid; i < 64 * 16; i += 256) {
        int nn = i >> 4, c = i & 15;
        *(uint4*)&sW[(nn * 17 + c) * 8] = *(const uint4*)&Wtg[i * 8];
    }
    __syncthreads();
    const int lane = tid & 63, w = tid >> 6;
    const int m = lane & 15, q = lane >> 4;
    const int gr = min(row0 + 16 * w + m, n - 1);
    const float* ar = x + (size_t)gr * 128;
    f32x4 acc[4];
#pragma unroll
    for (int c = 0; c < 4; ++c) acc[c] = (f32x4){0.f, 0.f, 0.f, 0.f};
#pragma unroll
    for (int kk = 0; kk < 4; ++kk) {
        float4 a0 = *(const float4*)(ar + kk * 32 + q * 8);
        float4 a1 = *(const float4*)(ar + kk * 32 + q * 8 + 4);
        f16x8 af;
        af[0] = (f16)a0.x; af[1] = (f16)a0.y; af[2] = (f16)a0.z; af[3] = (f16)a0.w;
        af[4] = (f16)a1.x; af[5] = (f16)a1.y; af[6] = (f16)a1.z; af[7] = (f16)a1.w;
#pragma unroll
        for (int c = 0; c < 4; ++c) {
            f16x8 bf = *(const f16x8*)&sW[((16 * c + m) * 17 + (kk * 4 + q)) * 8];
            acc[c] = __builtin_amdgcn_mfma_f32_16x16x32_f16(af, bf, acc[c], 0, 0, 0);
        }
    }
#pragma unroll
    for (int c = 0; c < 4; ++c) {
        int col = 16 * c + m;
        float bv = bias[col];
#pragma unroll
        for (int i = 0; i < 4; ++i) {
            int r = row0 + 16 * w + q * 4 + i;
            if (r < n) outh[(size_t)r * 64 + col] = f2h(fmaxf(acc[c][i] + bv, 0.f));
        }
    }
}

// ---- k_mm23 (MFMA, 2-stage): h3 = relu(relu([agg|h1]@Wc+bl) @ lin2 + b2) ----
__global__ __launch_bounds__(256) void k_mm23(
    const unsigned short* __restrict__ aggH, const unsigned short* __restrict__ h1,
    const unsigned short* __restrict__ Wcg, const float* __restrict__ bl,
    const unsigned short* __restrict__ Wl2g, const float* __restrict__ b2,
    unsigned short* __restrict__ outh, int n) {
    __shared__ alignas(16) unsigned short sm[64 * 72 + 64 * 136];
    unsigned short* hA = sm;
    unsigned short* sW = sm + 64 * 72;
    const int tid = threadIdx.x;
    const int row0 = blockIdx.x * 64;
    for (int i = tid; i < 64 * 16; i += 256) {
        int nn = i >> 4, c = i & 15;
        *(uint4*)&sW[(nn * 17 + c) * 8] = *(const uint4*)&Wcg[i * 8];
    }
    __syncthreads();
    const int lane = tid & 63, w = tid >> 6;
    const int m = lane & 15, q = lane >> 4;
    const int gr = min(row0 + 16 * w + m, n - 1);
    f32x4 acc[4];
#pragma unroll
    for (int c = 0; c < 4; ++c) acc[c] = (f32x4){0.f, 0.f, 0.f, 0.f};
#pragma unroll
    for (int kk = 0; kk < 4; ++kk) {
        const unsigned short* ap = (kk < 2)
            ? (aggH + (size_t)gr * 64 + kk * 32 + q * 8)
            : (h1 + (size_t)gr * 64 + (kk - 2) * 32 + q * 8);
        f16x8 af = *(const f16x8*)ap;
#pragma unroll
        for (int c = 0; c < 4; ++c) {
            f16x8 bf = *(const f16x8*)&sW[((16 * c + m) * 17 + (kk * 4 + q)) * 8];
            acc[c] = __builtin_amdgcn_mfma_f32_16x16x32_f16(af, bf, acc[c], 0, 0, 0);
        }
    }
#pragma unroll
    for (int c = 0; c < 4; ++c) {
        int col = 16 * c + m;
        float bv = bl[col];
#pragma unroll
        for (int i = 0; i < 4; ++i)
            hA[(16 * w + q * 4 + i) * 72 + col] = f2h(fmaxf(acc[c][i] + bv, 0.f));
    }
    __syncthreads();
    for (int i = tid; i < 64 * 8; i += 256) {
        int nn = i >> 3, c = i & 7;
        *(uint4*)&sW[(nn * 9 + c) * 8] = *(const uint4*)&Wl2g[i * 8];
    }
    __syncthreads();
    f32x4 acc2[4];
#pragma unroll
    for (int c = 0; c < 4; ++c) acc2[c] = (f32x4){0.f, 0.f, 0.f, 0.f};
#pragma unroll
    for (int kk = 0; kk < 2; ++kk) {
        f16x8 af = *(const f16x8*)&hA[(16 * w + m) * 72 + kk * 32 + q * 8];
#pragma unroll
        for (int c = 0; c < 4; ++c) {
            f16x8 bf = *(const f16x8*)&sW[((16 * c + m) * 9 + (kk * 4 + q)) * 8];
            acc2[c] = __builtin_amdgcn_mfma_f32_16x16x32_f16(af, bf, acc2[c], 0, 0, 0);
        }
    }
#pragma unroll
    for (int c = 0; c < 4; ++c) {
        int col = 16 * c + m;
        float bv = b2[col];
#pragma unroll
        for (int i = 0; i < 4; ++i) {
            int r = row0 + 16 * w + q * 4 + i;
            if (r < n) outh[(size_t)r * 64 + col] = f2h(fmaxf(acc2[c][i] + bv, 0.f));
        }
    }
}

// ---- k_mm456 (MFMA, 2-stage): h4=relu([agg2|h3]@Wc2+bl); P=h4@Wp+b1; Q=h4@Wq
__global__ __launch_bounds__(256) void k_mm456(
    const unsigned short* __restrict__ aggH, const unsigned short* __restrict__ h3,
    const unsigned short* __restrict__ Wcg, const float* __restrict__ bl,
    const unsigned short* __restrict__ Wpg, const unsigned short* __restrict__ Wqg,
    const float* __restrict__ b1, unsigned short* __restrict__ Ph,
    unsigned short* __restrict__ Qh, int n) {
    __shared__ alignas(16) unsigned short sm[64 * 72 + 2 * 64 * 72];
    unsigned short* hA = sm;
    unsigned short* sW = sm + 64 * 72;
    const int tid = threadIdx.x;
    const int row0 = blockIdx.x * 64;
    for (int i = tid; i < 64 * 16; i += 256) {
        int nn = i >> 4, c = i & 15;
        *(uint4*)&sW[(nn * 17 + c) * 8] = *(const uint4*)&Wcg[i * 8];
    }
    __syncthreads();
    const int lane = tid & 63, w = tid >> 6;
    const int m = lane & 15, q = lane >> 4;
    const int gr = min(row0 + 16 * w + m, n - 1);
    f32x4 acc[4];
#pragma unroll
    for (int c = 0; c < 4; ++c) acc[c] = (f32x4){0.f, 0.f, 0.f, 0.f};
#pragma unroll
    for (int kk = 0; kk < 4; ++kk) {
        const unsigned short* ap = (kk < 2)
            ? (aggH + (size_t)gr * 64 + kk * 32 + q * 8)
            : (h3 + (size_t)gr * 64 + (kk - 2) * 32 + q * 8);
        f16x8 af = *(const f16x8*)ap;
#pragma unroll
        for (int c = 0; c < 4; ++c) {
            f16x8 bf = *(const f16x8*)&sW[((16 * c + m) * 17 + (kk * 4 + q)) * 8];
            acc[c] = __builtin_amdgcn_mfma_f32_16x16x32_f16(af, bf, acc[c], 0, 0, 0);
        }
    }
#pragma unroll
    for (int c = 0; c < 4; ++c) {
        int col = 16 * c + m;
        float bv = bl[col];
#pragma unroll
        for (int i = 0; i < 4; ++i)
            hA[(16 * w + q * 4 + i) * 72 + col] = f2h(fmaxf(acc[c][i] + bv, 0.f));
    }
    __syncthreads();
    for (int i = tid; i < 64 * 8; i += 256) {
        int nn = i >> 3, c = i & 7;
        *(uint4*)&sW[(nn * 9 + c) * 8] = *(const uint4*)&Wpg[i * 8];
        *(uint4*)&sW[4608 + (nn * 9 + c) * 8] = *(const uint4*)&Wqg[i * 8];
    }
    __syncthreads();
    f32x4 accP[4], accQ[4];
#pragma unroll
    for (int c = 0; c < 4; ++c) {
        accP[c] = (f32x4){0.f, 0.f, 0.f, 0.f};
        accQ[c] = (f32x4){0.f, 0.f, 0.f, 0.f};
    }
#pragma unroll
    for (int kk = 0; kk < 2; ++kk) {
        f16x8 af = *(const f16x8*)&hA[(16 * w + m) * 72 + kk * 32 + q * 8];
#pragma unroll
        for (int c = 0; c < 4; ++c) {
            f16x8 bp = *(const f16x8*)&sW[((16 * c + m) * 9 + (kk * 4 + q)) * 8];
            f16x8 bq = *(const f16x8*)&sW[4608 + ((16 * c + m) * 9 + (kk * 4 + q)) * 8];
            accP[c] = __builtin_amdgcn_mfma_f32_16x16x32_f16(af, bp, accP[c], 0, 0, 0);
            accQ[c] = __builtin_amdgcn_mfma_f32_16x16x32_f16(af, bq, accQ[c], 0, 0, 0);
        }
    }
#pragma unroll
    for (int c = 0; c < 4; ++c) {
        int col = 16 * c + m;
        float bv = b1[col];
#pragma unroll
        for (int i = 0; i < 4; ++i) {
            int r = row0 + 16 * w + q * 4 + i;
            if (r < n) {
                Ph[(size_t)r * 64 + col] = f2h(accP[c][i] + bv);
                Qh[(size_t)r * 64 + col] = f2h(accQ[c][i]);
            }
        }
    }
}

// ---- edge scorer v3: 8 lanes/edge, f16x8, 16 loads in flight per wave ----
__global__ __launch_bounds__(256) void k_score_h(
    const _Float16* __restrict__ P, const _Float16* __restrict__ Q,
    const int* __restrict__ msrc, const int* __restrict__ mdst,
    const _Float16* __restrict__ w2h, const float* __restrict__ b2,
    float* __restrict__ out, int M) {
    int gid = blockIdx.x * 256 + threadIdx.x;
    int e = gid >> 3;
    if (e >= M) return;
    int l = gid & 7;
    int s = msrc[e], d = mdst[e];
    f16x8 p = *(const f16x8*)(P + (((unsigned)s << 6) + ((unsigned)l << 3)));
    f16x8 q = *(const f16x8*)(Q + (((unsigned)d << 6) + ((unsigned)l << 3)));
    f16x8 w = *(const f16x8*)(w2h + ((unsigned)l << 3));
    f16x8 u = p + q;
    f16x8 z = {(f16)0, (f16)0, (f16)0, (f16)0, (f16)0, (f16)0, (f16)0, (f16)0};
    u = __builtin_elementwise_max(u, z);
    float partial;
#if __has_builtin(__builtin_amdgcn_fdot2)
    f16x2 u01 = {u[0], u[1]}, u23 = {u[2], u[3]}, u45 = {u[4], u[5]}, u67 = {u[6], u[7]};
    f16x2 w01 = {w[0], w[1]}, w23 = {w[2], w[3]}, w45 = {w[4], w[5]}, w67 = {w[6], w[7]};
    partial = __builtin_amdgcn_fdot2(u01, w01,
              __builtin_amdgcn_fdot2(u23, w23,
              __builtin_amdgcn_fdot2(u45, w45,
              __builtin_amdgcn_fdot2(u67, w67, 0.f, false), false), false), false);
#else
    partial = 0.f;
#pragma unroll
    for (int i = 0; i < 8; ++i) partial += (float)u[i] * (float)w[i];
#endif
    partial += __shfl_xor(partial, 1, 8);
    partial += __shfl_xor(partial, 2, 8);
    partial += __shfl_xor(partial, 4, 8);
    if (l == 0) {
        float xx = partial + b2[0];
        float t = __expf(2.f * xx);
        out[e] = (t - 1.f) / (t + 1.f);
    }
}

extern "C" void kernel_launch(void* const* d_in, const int* in_sizes, int n_in,
                              void* d_out, int out_size, void* d_ws, size_t ws_size,
                              hipStream_t stream) {
    const float* x      = (const float*)d_in[0];
    const int*   ei     = (const int*)d_in[1];
    const int*   mei    = (const int*)d_in[2];
    const float* lin1_w = (const float*)d_in[3];
    const float* lin1_b = (const float*)d_in[4];
    const float* lin2_w = (const float*)d_in[5];
    const float* lin2_b = (const float*)d_in[6];
    const float* c1_wl  = (const float*)d_in[7];
    const float* c1_bl  = (const float*)d_in[8];
    const float* c1_wr  = (const float*)d_in[9];
    const float* c2_wl  = (const float*)d_in[10];
    const float* c2_bl  = (const float*)d_in[11];
    const float* c2_wr  = (const float*)d_in[12];
    const float* mlp_w1 = (const float*)d_in[13];
    const float* mlp_b1 = (const float*)d_in[14];
    const float* mlp_w2 = (const float*)d_in[15];
    const float* mlp_b2 = (const float*)d_in[16];

    const int N = in_sizes[0] / 128;
    const int E = in_sizes[1] / 2;
    const int M = in_sizes[2] / 2;
    const int* src  = ei;
    const int* dstE = ei + E;
    const int* msrc = mei;
    const int* mdst = mei + M;

    int shift = 8;
    while ((((N - 1) >> shift) + 1) > MAXB) ++shift;
    const int nbuckets = ((N - 1) >> shift) + 1;
    long long avg = (((long long)E << shift) / N) + 1;
    int CAP = (int)((2 * avg + 2047) & ~1023LL);

    const size_t N64 = (size_t)N * 64;
    unsigned short* Hh   = (unsigned short*)d_ws;   // N*64 fp16: h1/h3/P
    unsigned short* aggH = Hh + N64;                // N*64 fp16
    unsigned short* Qh   = aggH + N64;              // N*64 fp16
    float* inv_deg = (float*)(Qh + N64);            // N
    int*   row_st  = (int*)(inv_deg + N);           // N
    int*   row_en  = row_st + N;                    // N
    int*   bcur    = row_en + N;                    // MAXB
    unsigned short* Wt = (unsigned short*)(bcur + MAXB);  // 36928 halfs
    int*   csr     = (int*)(Wt + 36928 + 32);       // nbuckets*CAP ints
    unsigned* bb   = (unsigned*)Hh;                 // nbuckets*CAP ints (pre-mm1)
    float* outf = (float*)d_out;

    const int nbN = (N + 63) / 64;
    const int nbM = (int)(((long long)M * 8 + 255) / 256);
    const int nbG = (int)(((long long)N * 64 + 255) / 256);
    const int nbP = (E + PART_CH - 1) / PART_CH;

    // ---- CSR build (single-pass) + weight prep ----
    hipMemsetAsync(bcur, 0, MAXB * sizeof(int), stream);
    k_prep<<<64, 256, 0, stream>>>(lin1_w, c1_wl, c1_wr, lin2_w, c2_wl, c2_wr,
                                   mlp_w1, mlp_w2, Wt);
    k_part<<<nbP, PART_BS, 0, stream>>>(src, dstE, bcur, bb, E, shift, CAP);
    k_bfill<<<nbuckets, 512, 0, stream>>>(bb, bcur, row_st, row_en,
                                          inv_deg, csr, N, shift, CAP);

    // h1 = relu(x @ lin1_w + b)  (fp16 out)
    k_mm1<<<nbN, 256, 0, stream>>>(x, Wt + 0, lin1_b, Hh, N);

    // sage1 + lin2 fused
    k_gather_h<<<nbG, 256, 0, stream>>>((const _Float16*)Hh, csr, row_st, row_en,
                                        inv_deg, (_Float16*)aggH, N);
    k_mm23<<<nbN, 256, 0, stream>>>(aggH, Hh, Wt + 8192, c1_bl,
                                    Wt + 16384, lin2_b, Hh, N);

    // sage2 + P/Q fused
    k_gather_h<<<nbG, 256, 0, stream>>>((const _Float16*)Hh, csr, row_st, row_en,
                                        inv_deg, (_Float16*)aggH, N);
    k_mm456<<<nbN, 256, 0, stream>>>(aggH, Hh, Wt + 20480, c2_bl,
                                     Wt + 28672, Wt + 32768, mlp_b1,
                                     Hh, Qh, N);

    // edge scoring
    k_score_h<<<nbM, 256, 0, stream>>>((const _Float16*)Hh, (const _Float16*)Qh,
                                       msrc, mdst, (const _Float16*)(Wt + 36864),
                                       mlp_b2, outf, M);
}